// Round 4
// baseline (274.902 us; speedup 1.0000x reference)
//
#include <hip/hip_runtime.h>
#include <math.h>

#define S 4096
#define QK_SCALE 0.17677669529663687f  // 1/sqrt(32)
#define LOG2E    1.44269504088896f
#define SPLIT 8
#define KS (S / SPLIT)                 // 512 keys per split

typedef _Float16 f16x8 __attribute__((ext_vector_type(8)));
typedef _Float16 f16x4 __attribute__((ext_vector_type(4)));
typedef _Float16 f16x2 __attribute__((ext_vector_type(2)));
typedef float f32x4 __attribute__((ext_vector_type(4)));

// ---------------------------------------------------------------------------
// MFMA lane map (HW-verified R4): A-frag m=l&15, k=(l>>4)*8+j; B-frag n=l&15;
// C reg r: row=(l>>4)*4+r, col=l&15.  For 16x16x16: k=(l>>4)*4+j (4-granular).
// R13: revert R3's layer_tail + SPLIT=4 (regressed, -9us; both cut TLP).
// Base = R2 (263us). ONE change: attn PV via 16x16x16 MFMA — QK^T's swapped
// C-layout (lane holds P[key=t*16+lr*4+r][q=lc]) IS the 16x16x16 A-frag, so
// P never touches LDS: no Ps buffer (9.2KB freed -> ~8 blocks/CU), no
// ds_write/lgkmcnt(0)/ds_read round-trip per tile.
// LDS stride 136 f16 = 68 dw == 4 mod 32 banks -> balanced b128 access.
// ---------------------------------------------------------------------------
template<int R>
__device__ __forceinline__ void stageT(_Float16 (*dst)[136], const _Float16* __restrict__ src,
                                       int ld, int row0, int col0, int tid) {
    int r = tid >> 4, cb = (tid & 15) * 8;   // 16 rows x 128 cols per pass, coalesced
#pragma unroll
    for (int v = 0; v < R / 16; v++)
        *(f16x8*)&dst[v * 16 + r][cb] =
            *(const f16x8*)(src + (size_t)(row0 + v * 16 + r) * ld + col0 + cb);
}

// ---------------------------------------------------------------------------
// setup: weight fp32->fp16 conversion (blocks 0..991) + x/xh copy (992..1503).
// ---------------------------------------------------------------------------
__global__ __launch_bounds__(256) void setup_cvt(const float* __restrict__ q,
                                                 const float* __restrict__ wo,
                                                 const float* __restrict__ w1,
                                                 const float* __restrict__ w2,
                                                 const float* __restrict__ f1,
                                                 const float* __restrict__ f2,
                                                 _Float16* __restrict__ dst,
                                                 const float* __restrict__ a,
                                                 float* __restrict__ x,
                                                 _Float16* __restrict__ xh)
{
    int bb = blockIdx.x;
    if (bb < 992) {
        const float* src; size_t dof; int lb;
        if (bb < 144)      { src = q;  dof = 0;      lb = bb; }
        else if (bb < 192) { src = wo; dof = 147456; lb = bb - 144; }
        else if (bb < 576) { src = w1; dof = 196608; lb = bb - 192; }
        else if (bb < 960) { src = w2; dof = 589824; lb = bb - 576; }
        else if (bb < 976) { src = f1; dof = 983040; lb = bb - 960; }
        else               { src = f2; dof = 999424; lb = bb - 976; }
        int i = lb * 1024 + threadIdx.x * 4;
        float4 v = *(const float4*)(src + i);
        f16x4 h = {(_Float16)v.x, (_Float16)v.y, (_Float16)v.z, (_Float16)v.w};
        *(f16x4*)(dst + dof + i) = h;
    } else {
        int i = (bb - 992) * 256 + threadIdx.x;
        float4 v = ((const float4*)a)[i];
        ((float4*)x)[i] = v;
        f16x4 h = {(_Float16)v.x, (_Float16)v.y, (_Float16)v.z, (_Float16)v.w};
        ((f16x4*)xh)[i] = h;
    }
}

// ---------------------------------------------------------------------------
// QKV GEMM, 16-row tiles, full-K single barrier. grid (256, 3).
// ---------------------------------------------------------------------------
__global__ __launch_bounds__(256) void gemm_qkv(const _Float16* __restrict__ xh,
                                                const _Float16* __restrict__ Wh,
                                                const float* __restrict__ bias,
                                                _Float16* __restrict__ qh,
                                                _Float16* __restrict__ kh,
                                                _Float16* __restrict__ vt)
{
    __shared__ _Float16 Ah[16][136], Bh[128][136];
    int tid = threadIdx.x, w = tid >> 6, l = tid & 63, lc = l & 15, lr = l >> 4;
    int m0 = blockIdx.x * 16, by = blockIdx.y;

    stageT<16>(Ah, xh, 128, m0, 0, tid);
    stageT<128>(Bh, Wh, 128, by * 128, 0, tid);
    __syncthreads();

    f32x4 acc[2];
#pragma unroll
    for (int j = 0; j < 2; j++) acc[j] = {0.f, 0.f, 0.f, 0.f};
#pragma unroll
    for (int ks = 0; ks < 4; ks++) {
        f16x8 af = *(const f16x8*)&Ah[lc][ks * 32 + lr * 8];
#pragma unroll
        for (int j = 0; j < 2; j++) {
            f16x8 bf = *(const f16x8*)&Bh[w * 32 + j * 16 + lc][ks * 32 + lr * 8];
            acc[j] = __builtin_amdgcn_mfma_f32_16x16x32_f16(af, bf, acc[j], 0, 0, 0);
        }
    }

    int mb = m0 + lr * 4;
#pragma unroll
    for (int j = 0; j < 2; j++) {
        int n = w * 32 + j * 16 + lc;
        float bb = bias[by * 128 + n];
        if (by == 0) {
#pragma unroll
            for (int r = 0; r < 4; r++)
                qh[(size_t)(mb + r) * 128 + n] =
                    (_Float16)((acc[j][r] + bb) * (QK_SCALE * LOG2E));
        } else if (by == 1) {
            int hh = n >> 5, d = n & 31;
#pragma unroll
            for (int r = 0; r < 4; r++)
                kh[((size_t)hh * S + mb + r) * 32 + d] = (_Float16)(acc[j][r] + bb);
        } else {
            f16x4 pk;
#pragma unroll
            for (int r = 0; r < 4; r++) pk[r] = (_Float16)(acc[j][r] + bb);
            *(f16x4*)&vt[(size_t)n * S + mb] = pk;
        }
    }
}

// ---------------------------------------------------------------------------
// MFMA flash attention: K/V double-buffer, async-split staging, one barrier
// per tile; swapped QK^T (C[k][q]); PV via 16x16x16 MFMA directly from QK^T
// output registers (P never staged to LDS).
// ---------------------------------------------------------------------------
__global__ __launch_bounds__(256) void attn_mfma(const _Float16* __restrict__ qh,
                                                 const _Float16* __restrict__ kh,
                                                 const _Float16* __restrict__ vt,
                                                 _Float16* __restrict__ part,
                                                 float* __restrict__ mll)
{
    __shared__ _Float16 Ks[2][64][32];
    __shared__ _Float16 Vt[2][32][72];
    int h = blockIdx.y, q0 = blockIdx.x * 64, z = blockIdx.z;
    int tid = threadIdx.x;
    int w = tid >> 6, l = tid & 63;
    int lc = l & 15, lr = l >> 4;

    f16x8 qf = *(const f16x8*)&qh[(size_t)(q0 + w * 16 + lc) * 128 + h * 32 + lr * 8];

    const _Float16* khh = kh + (size_t)h * S * 32;
    const _Float16* vth = vt + (size_t)h * 32 * S;

    int krow = tid >> 2, kcol = (tid & 3) * 8;
    int vrow = tid >> 3, vcol = (tid & 7) * 8;

    f32x4 o0 = {0.f, 0.f, 0.f, 0.f}, o1 = {0.f, 0.f, 0.f, 0.f};
    float lp = 0.f;

    int k0 = z * KS;
    {   // prologue: stage tile 0
        f16x8 kr = *(const f16x8*)&khh[(size_t)(k0 + krow) * 32 + kcol];
        f16x8 vr = *(const f16x8*)&vth[(size_t)vrow * S + k0 + vcol];
        *(f16x8*)&Ks[0][krow][kcol] = kr;
        *(f16x8*)&Vt[0][vrow][vcol] = vr;
    }
    __syncthreads();

    int cur = 0;
#pragma unroll 1
    for (int t8 = 0; t8 < KS / 64; t8++) {
        bool more = (t8 + 1 < KS / 64);
        f16x8 kr, vr;
        if (more) {   // issue next tile's loads early; latency hides under compute
            int kn = k0 + (t8 + 1) * 64;
            kr = *(const f16x8*)&khh[(size_t)(kn + krow) * 32 + kcol];
            vr = *(const f16x8*)&vth[(size_t)vrow * S + kn + vcol];
        }

        // QK^T (swapped): st[t] holds P[key=t*16+lr*4+r][q=lc]
        f32x4 st[4];
#pragma unroll
        for (int t = 0; t < 4; t++) {
            f16x8 kf = *(const f16x8*)&Ks[cur][t * 16 + lc][lr * 8];
            f32x4 zz = {0.f, 0.f, 0.f, 0.f};
            st[t] = __builtin_amdgcn_mfma_f32_16x16x32_f16(kf, qf, zz, 0, 0, 0);
        }

        // exp2 + f16 pack: pa[t] IS the 16x16x16 PV A-frag (k=(l>>4)*4+j)
        f16x4 pa[4];
#pragma unroll
        for (int t = 0; t < 4; t++) {
            float p0 = exp2f(st[t][0]), p1 = exp2f(st[t][1]);
            float p2 = exp2f(st[t][2]), p3 = exp2f(st[t][3]);
            lp += (p0 + p1) + (p2 + p3);
            f16x4 pk = {(_Float16)p0, (_Float16)p1, (_Float16)p2, (_Float16)p3};
            pa[t] = pk;
        }

        // PV: o[q][d] += P[q][k] * V[k][d], K=16 per MFMA, B from Vt rows
#pragma unroll
        for (int t = 0; t < 4; t++) {
            f16x4 vb0 = *(const f16x4*)&Vt[cur][lc][t * 16 + lr * 4];
            f16x4 vb1 = *(const f16x4*)&Vt[cur][16 + lc][t * 16 + lr * 4];
            o0 = __builtin_amdgcn_mfma_f32_16x16x16f16(pa[t], vb0, o0, 0, 0, 0);
            o1 = __builtin_amdgcn_mfma_f32_16x16x16f16(pa[t], vb1, o1, 0, 0, 0);
        }

        if (more) {
            *(f16x8*)&Ks[cur ^ 1][krow][kcol] = kr;
            *(f16x8*)&Vt[cur ^ 1][vrow][vcol] = vr;
            __syncthreads();
        }
        cur ^= 1;
    }

    lp += __shfl_xor(lp, 16);
    lp += __shfl_xor(lp, 32);

    _Float16* pz = part + (size_t)z * 524288;
#pragma unroll
    for (int i = 0; i < 4; i++) {
        int q = q0 + w * 16 + lr * 4 + i;
        pz[(size_t)q * 128 + h * 32 + lc]      = (_Float16)o0[i];
        pz[(size_t)q * 128 + h * 32 + 16 + lc] = (_Float16)o1[i];
    }
    if (l < 16) mll[((size_t)z * 4 + h) * 4096 + q0 + w * 16 + lc] = lp;
}

// ---------------------------------------------------------------------------
// Wo GEMM + split-attention merge + residual + LayerNorm. 16-row tiles.
// ---------------------------------------------------------------------------
__global__ __launch_bounds__(256) void wo_ln_merge(const _Float16* __restrict__ part,
                                                   const float* __restrict__ mll,
                                                   const _Float16* __restrict__ Wh,
                                                   const float* __restrict__ bias,
                                                   float* __restrict__ x,
                                                   _Float16* __restrict__ xh,
                                                   const float* __restrict__ g,
                                                   const float* __restrict__ b)
{
    __shared__ _Float16 Ah[16][136], Bh[128][136];
    __shared__ float Red[16][4][2];
    int tid = threadIdx.x, w = tid >> 6, l = tid & 63, lc = l & 15, lr = l >> 4;
    int m0 = blockIdx.x * 16;

    {   // merge-stage A: 16 rows x 128 cols, 8 cols/thread
        int row = tid >> 4, col0 = (tid & 15) * 8;
        int q = m0 + row, hh = col0 >> 5;
        float lsum = 0.f;
#pragma unroll
        for (int s = 0; s < SPLIT; s++) lsum += mll[((size_t)s * 4 + hh) * 4096 + q];
        float am[8];
#pragma unroll
        for (int e = 0; e < 8; e++) am[e] = 0.f;
#pragma unroll
        for (int s = 0; s < SPLIT; s++) {
            f16x8 t = *(const f16x8*)&part[(size_t)s * 524288 + (size_t)q * 128 + col0];
#pragma unroll
            for (int e = 0; e < 8; e++) am[e] += (float)t[e];
        }
        float inv = 1.f / lsum;
        f16x8 hv;
#pragma unroll
        for (int e = 0; e < 8; e++) hv[e] = (_Float16)(am[e] * inv);
        *(f16x8*)&Ah[row][col0] = hv;
    }
    stageT<128>(Bh, Wh, 128, 0, 0, tid);
    __syncthreads();

    f32x4 acc[2];
#pragma unroll
    for (int j = 0; j < 2; j++) acc[j] = {0.f, 0.f, 0.f, 0.f};
#pragma unroll
    for (int ks = 0; ks < 4; ks++) {
        f16x8 af = *(const f16x8*)&Ah[lc][ks * 32 + lr * 8];
#pragma unroll
        for (int j = 0; j < 2; j++) {
            f16x8 bf = *(const f16x8*)&Bh[w * 32 + j * 16 + lc][ks * 32 + lr * 8];
            acc[j] = __builtin_amdgcn_mfma_f32_16x16x32_f16(af, bf, acc[j], 0, 0, 0);
        }
    }

#pragma unroll
    for (int j = 0; j < 2; j++) {
        int n = w * 32 + j * 16 + lc;
        float bb = bias[n];
#pragma unroll
        for (int r = 0; r < 4; r++)
            acc[j][r] += bb + x[(size_t)(m0 + lr * 4 + r) * 128 + n];
    }
#pragma unroll
    for (int r = 0; r < 4; r++) {
        float s1 = acc[0][r] + acc[1][r];
        float s2 = acc[0][r] * acc[0][r] + acc[1][r] * acc[1][r];
#pragma unroll
        for (int off = 1; off < 16; off <<= 1) {
            s1 += __shfl_xor(s1, off);
            s2 += __shfl_xor(s2, off);
        }
        if (lc == 0) { Red[lr * 4 + r][w][0] = s1; Red[lr * 4 + r][w][1] = s2; }
    }
    __syncthreads();
#pragma unroll
    for (int r = 0; r < 4; r++) {
        int rl = lr * 4 + r;
        float S1 = (Red[rl][0][0] + Red[rl][1][0]) + (Red[rl][2][0] + Red[rl][3][0]);
        float S2 = (Red[rl][0][1] + Red[rl][1][1]) + (Red[rl][2][1] + Red[rl][3][1]);
        float mean = S1 * (1.0f / 128.0f);
        float var = S2 * (1.0f / 128.0f) - mean * mean;
        float inv = rsqrtf(var + 1e-5f);
        int m = m0 + rl;
#pragma unroll
        for (int j = 0; j < 2; j++) {
            int n = w * 32 + j * 16 + lc;
            float o = (acc[j][r] - mean) * inv * g[n] + b[n];
            x[(size_t)m * 128 + n] = o;
            xh[(size_t)m * 128 + n] = (_Float16)o;
        }
    }
}

// ---------------------------------------------------------------------------
// Fused W1+W2 pair, 64-row tiles, grid (64, 8) = 512 blocks.
// ---------------------------------------------------------------------------
__global__ __launch_bounds__(256) void ffn_pair(const _Float16* __restrict__ xh,
                                                const _Float16* __restrict__ W1h,
                                                const float* __restrict__ b1,
                                                const _Float16* __restrict__ W2h,
                                                _Float16* __restrict__ wpart)
{
    __shared__ _Float16 Ah[64][136], Bh[128][136];
    int tid = threadIdx.x, w = tid >> 6, l = tid & 63, lc = l & 15, lr = l >> 4;
    int wr = w >> 1, wc = w & 1;
    int m0 = blockIdx.x * 64, c = blockIdx.y;

    stageT<64>(Ah, xh, 128, m0, 0, tid);
    stageT<128>(Bh, W1h, 128, c * 128, 0, tid);
    __syncthreads();

    f32x4 acc[2][4];
#pragma unroll
    for (int i = 0; i < 2; i++)
#pragma unroll
        for (int j = 0; j < 4; j++) acc[i][j] = {0.f, 0.f, 0.f, 0.f};
#pragma unroll
    for (int ks = 0; ks < 4; ks++) {
        f16x8 af0 = *(const f16x8*)&Ah[wr * 32 + lc][ks * 32 + lr * 8];
        f16x8 af1 = *(const f16x8*)&Ah[wr * 32 + 16 + lc][ks * 32 + lr * 8];
#pragma unroll
        for (int j = 0; j < 4; j++) {
            f16x8 bf = *(const f16x8*)&Bh[wc * 64 + j * 16 + lc][ks * 32 + lr * 8];
            acc[0][j] = __builtin_amdgcn_mfma_f32_16x16x32_f16(af0, bf, acc[0][j], 0, 0, 0);
            acc[1][j] = __builtin_amdgcn_mfma_f32_16x16x32_f16(af1, bf, acc[1][j], 0, 0, 0);
        }
    }
    __syncthreads();

#pragma unroll
    for (int i = 0; i < 2; i++)
#pragma unroll
        for (int j = 0; j < 4; j++) {
            int n = wc * 64 + j * 16 + lc;
            float bb = b1[c * 128 + n];
#pragma unroll
            for (int r = 0; r < 4; r++)
                Ah[wr * 32 + i * 16 + lr * 4 + r][n] =
                    (_Float16)fmaxf(acc[i][j][r] + bb, 0.f);
        }
    stageT<128>(Bh, W2h, 1024, 0, c * 128, tid);
    __syncthreads();

    f32x4 oacc[2][4];
#pragma unroll
    for (int i = 0; i < 2; i++)
#pragma unroll
        for (int j = 0; j < 4; j++) oacc[i][j] = {0.f, 0.f, 0.f, 0.f};
#pragma unroll
    for (int ks = 0; ks < 4; ks++) {
        f16x8 af0 = *(const f16x8*)&Ah[wr * 32 + lc][ks * 32 + lr * 8];
        f16x8 af1 = *(const f16x8*)&Ah[wr * 32 + 16 + lc][ks * 32 + lr * 8];
#pragma unroll
        for (int j = 0; j < 4; j++) {
            f16x8 bf = *(const f16x8*)&Bh[wc * 64 + j * 16 + lc][ks * 32 + lr * 8];
            oacc[0][j] = __builtin_amdgcn_mfma_f32_16x16x32_f16(af0, bf, oacc[0][j], 0, 0, 0);
            oacc[1][j] = __builtin_amdgcn_mfma_f32_16x16x32_f16(af1, bf, oacc[1][j], 0, 0, 0);
        }
    }

    _Float16* pz = wpart + (size_t)c * 524288;
#pragma unroll
    for (int i = 0; i < 2; i++) {
        int mb = m0 + wr * 32 + i * 16 + lr * 4;
#pragma unroll
        for (int j = 0; j < 4; j++) {
            int n = wc * 64 + j * 16 + lc;
#pragma unroll
            for (int r = 0; r < 4; r++)
                pz[(size_t)(mb + r) * 128 + n] = (_Float16)oacc[i][j][r];
        }
    }
}

// ---------------------------------------------------------------------------
// reduce 8 fp16 W2 partials + bias + residual + LayerNorm -> x, xh.
// ---------------------------------------------------------------------------
__global__ __launch_bounds__(256) void reduce8_ln(const _Float16* __restrict__ part,
                                                  const float* __restrict__ bias,
                                                  float* __restrict__ x,
                                                  _Float16* __restrict__ xh,
                                                  const float* __restrict__ g,
                                                  const float* __restrict__ b)
{
    int row  = blockIdx.x * 4 + (threadIdx.x >> 6);
    int lane = threadIdx.x & 63;
    size_t base = (size_t)row * 128;
    int c = lane * 2;
    float a0 = 0.f, a1 = 0.f;
#pragma unroll
    for (int s = 0; s < 8; s++) {
        f16x2 p = *(const f16x2*)&part[(size_t)s * 524288 + base + c];
        a0 += (float)p[0]; a1 += (float)p[1];
    }
    float2 bv = *(const float2*)&bias[c];
    float2 xv = *(const float2*)&x[base + c];
    a0 += bv.x + xv.x; a1 += bv.y + xv.y;
    float s = a0 + a1;
#pragma unroll
    for (int off = 32; off; off >>= 1) s += __shfl_xor(s, off);
    float mean = s * (1.0f / 128.0f);
    float d0 = a0 - mean, d1 = a1 - mean;
    float v = d0 * d0 + d1 * d1;
#pragma unroll
    for (int off = 32; off; off >>= 1) v += __shfl_xor(v, off);
    float inv = rsqrtf(v * (1.0f / 128.0f) + 1e-5f);
    float2 gv = *(const float2*)&g[c];
    float2 bb = *(const float2*)&b[c];
    float o0 = d0 * inv * gv.x + bb.x, o1 = d1 * inv * gv.y + bb.y;
    float2 r; r.x = o0; r.y = o1;
    *(float2*)&x[base + c] = r;
    f16x2 rh = {(_Float16)o0, (_Float16)o1};
    *(f16x2*)&xh[base + c] = rh;
}

// ---------------------------------------------------------------------------
// fc1 + relu + fc2 + rownorm fused. 16-row tiles, grid 256.
// ---------------------------------------------------------------------------
__global__ __launch_bounds__(256) void fc_fused(const _Float16* __restrict__ xh,
                                                const _Float16* __restrict__ W1h,
                                                const float* __restrict__ b1f,
                                                const _Float16* __restrict__ W2h,
                                                const float* __restrict__ b2f,
                                                _Float16* __restrict__ aoh)
{
    __shared__ _Float16 Ah[16][136], Bh[128][136];
    __shared__ float Red[16][4];
    int tid = threadIdx.x, w = tid >> 6, l = tid & 63, lc = l & 15, lr = l >> 4;
    int m0 = blockIdx.x * 16;

    stageT<16>(Ah, xh, 128, m0, 0, tid);
    stageT<128>(Bh, W1h, 128, 0, 0, tid);
    __syncthreads();

    f32x4 acc[2];
#pragma unroll
    for (int j = 0; j < 2; j++) acc[j] = {0.f, 0.f, 0.f, 0.f};
#pragma unroll
    for (int ks = 0; ks < 4; ks++) {
        f16x8 af = *(const f16x8*)&Ah[lc][ks * 32 + lr * 8];
#pragma unroll
        for (int j = 0; j < 2; j++) {
            f16x8 bf = *(const f16x8*)&Bh[w * 32 + j * 16 + lc][ks * 32 + lr * 8];
            acc[j] = __builtin_amdgcn_mfma_f32_16x16x32_f16(af, bf, acc[j], 0, 0, 0);
        }
    }
    __syncthreads();
#pragma unroll
    for (int j = 0; j < 2; j++) {
        int n = w * 32 + j * 16 + lc;
        float bb = b1f[n];
#pragma unroll
        for (int r = 0; r < 4; r++)
            Ah[lr * 4 + r][n] = (_Float16)fmaxf(acc[j][r] + bb, 0.f);
    }
    stageT<128>(Bh, W2h, 128, 0, 0, tid);
    __syncthreads();

    f32x4 o[2];
#pragma unroll
    for (int j = 0; j < 2; j++) o[j] = {0.f, 0.f, 0.f, 0.f};
#pragma unroll
    for (int ks = 0; ks < 4; ks++) {
        f16x8 af = *(const f16x8*)&Ah[lc][ks * 32 + lr * 8];
#pragma unroll
        for (int j = 0; j < 2; j++) {
            f16x8 bf = *(const f16x8*)&Bh[w * 32 + j * 16 + lc][ks * 32 + lr * 8];
            o[j] = __builtin_amdgcn_mfma_f32_16x16x32_f16(af, bf, o[j], 0, 0, 0);
        }
    }
#pragma unroll
    for (int j = 0; j < 2; j++) {
        float bb = b2f[w * 32 + j * 16 + lc];
#pragma unroll
        for (int r = 0; r < 4; r++) o[j][r] += bb;
    }
#pragma unroll
    for (int r = 0; r < 4; r++) {
        float s2 = o[0][r] * o[0][r] + o[1][r] * o[1][r];
#pragma unroll
        for (int off = 1; off < 16; off <<= 1) s2 += __shfl_xor(s2, off);
        if (lc == 0) Red[lr * 4 + r][w] = s2;
    }
    __syncthreads();
#pragma unroll
    for (int r = 0; r < 4; r++) {
        int rl = lr * 4 + r;
        float inv = rsqrtf((Red[rl][0] + Red[rl][1]) + (Red[rl][2] + Red[rl][3]));
        int m = m0 + rl;
#pragma unroll
        for (int j = 0; j < 2; j++) {
            int n = w * 32 + j * 16 + lc;
            aoh[(size_t)m * 128 + n] = (_Float16)(o[j][r] * inv);
        }
    }
}

// ---------------------------------------------------------------------------
// Gram: C = max(aoh @ aoh^T, 1e-6). 64x128 tiles, full-K single barrier,
// grid (64, 32) = 2048 blocks.
// ---------------------------------------------------------------------------
__global__ __launch_bounds__(256) void gram_f16(const _Float16* __restrict__ aoh,
                                                float* __restrict__ C)
{
    __shared__ _Float16 Ah[64][136], Bh[128][136];
    int tid = threadIdx.x, w = tid >> 6, l = tid & 63, lc = l & 15, lr = l >> 4;
    int wr = w >> 1, wc = w & 1;
    int m0 = blockIdx.x * 64, n0 = blockIdx.y * 128;

    stageT<64>(Ah, aoh, 128, m0, 0, tid);
    stageT<128>(Bh, aoh, 128, n0, 0, tid);
    __syncthreads();

    f32x4 acc[2][4];
#pragma unroll
    for (int i = 0; i < 2; i++)
#pragma unroll
        for (int j = 0; j < 4; j++) acc[i][j] = {0.f, 0.f, 0.f, 0.f};
#pragma unroll
    for (int ks = 0; ks < 4; ks++) {
        f16x8 af0 = *(const f16x8*)&Ah[wr * 32 + lc][ks * 32 + lr * 8];
        f16x8 af1 = *(const f16x8*)&Ah[wr * 32 + 16 + lc][ks * 32 + lr * 8];
#pragma unroll
        for (int j = 0; j < 4; j++) {
            f16x8 bf = *(const f16x8*)&Bh[wc * 64 + j * 16 + lc][ks * 32 + lr * 8];
            acc[0][j] = __builtin_amdgcn_mfma_f32_16x16x32_f16(af0, bf, acc[0][j], 0, 0, 0);
            acc[1][j] = __builtin_amdgcn_mfma_f32_16x16x32_f16(af1, bf, acc[1][j], 0, 0, 0);
        }
    }

#pragma unroll
    for (int i = 0; i < 2; i++) {
        int mb = m0 + wr * 32 + i * 16 + lr * 4;
#pragma unroll
        for (int j = 0; j < 4; j++) {
            int n = n0 + wc * 64 + j * 16 + lc;
#pragma unroll
            for (int r = 0; r < 4; r++)
                C[(size_t)(mb + r) * 4096 + n] = fmaxf(acc[i][j][r], 1e-6f);
        }
    }
}

// ---------------------------------------------------------------------------
extern "C" void kernel_launch(void* const* d_in, const int* in_sizes, int n_in,
                              void* d_out, int out_size, void* d_ws, size_t ws_size,
                              hipStream_t stream)
{
    const float* src  = (const float*)d_in[0];
    const float* Wqkv = (const float*)d_in[1];
    const float* bqkv = (const float*)d_in[2];
    const float* Wo   = (const float*)d_in[3];
    const float* bo   = (const float*)d_in[4];
    const float* ln1g = (const float*)d_in[5];
    const float* ln1b = (const float*)d_in[6];
    const float* W1   = (const float*)d_in[7];
    const float* b1   = (const float*)d_in[8];
    const float* W2   = (const float*)d_in[9];
    const float* b2   = (const float*)d_in[10];
    const float* ln2g = (const float*)d_in[11];
    const float* ln2b = (const float*)d_in[12];
    const float* fc1W = (const float*)d_in[13];
    const float* fc1b = (const float*)d_in[14];
    const float* fc2W = (const float*)d_in[15];
    const float* fc2b = (const float*)d_in[16];

    float* ws = (float*)d_ws;
    float*    x   = ws;                                   // 524288 f32
    _Float16* xh  = (_Float16*)(ws + 524288);             // 524288 f16
    _Float16* aoh = (_Float16*)(ws + 786432);             // 524288 f16
    _Float16* qh  = (_Float16*)(ws + 1048576);            // 524288 f16
    _Float16* kh  = (_Float16*)(ws + 1310720);            // 524288 f16
    _Float16* vt  = (_Float16*)(ws + 1572864);            // 524288 f16
    float*    mll = ws + 1835008;                         // 131072 f32

    // d_out scratch (all dead before gram writes):
    _Float16* wpart = (_Float16*)d_out + 4194304;         // bytes [ 8MiB,16MiB)
    _Float16* apart = (_Float16*)d_out + 12582912;        // bytes [24MiB,32MiB)
    _Float16* wh    = (_Float16*)d_out + 16777216;        // bytes [32MiB,~34MiB)
    float*    out   = (float*)d_out;

    _Float16* qkvh = wh;                  // 3 x 384 x 128
    _Float16* woh  = wh + 147456;         // 3 x 128 x 128
    _Float16* w1h  = wh + 196608;         // 3 x 1024 x 128
    _Float16* w2h  = wh + 589824;         // 3 x 128 x 1024
    _Float16* fc1h = wh + 983040;         // 128 x 128
    _Float16* fc2h = wh + 999424;         // 128 x 128

    setup_cvt<<<1504, 256, 0, stream>>>(Wqkv, Wo, W1, W2, fc1W, fc2W, wh,
                                        src, x, xh);
    for (int l = 0; l < 3; l++) {
        gemm_qkv<<<dim3(256, 3), 256, 0, stream>>>(xh, qkvh + l * 49152,
                                                   bqkv + l * 384, qh, kh, vt);
        attn_mfma<<<dim3(64, 4, SPLIT), 256, 0, stream>>>(qh, kh, vt, apart, mll);
        wo_ln_merge<<<256, 256, 0, stream>>>(apart, mll, woh + l * 16384, bo + l * 128,
                                             x, xh, ln1g + l * 128, ln1b + l * 128);
        ffn_pair<<<dim3(64, 8), 256, 0, stream>>>(xh, w1h + l * 131072, b1 + l * 1024,
                                                  w2h + l * 131072, wpart);
        reduce8_ln<<<1024, 256, 0, stream>>>(wpart, b2 + l * 128, x, xh,
                                             ln2g + l * 128, ln2b + l * 128);
    }
    fc_fused<<<256, 256, 0, stream>>>(xh, fc1h, fc1b, fc2h, fc2b, aoh);
    gram_f16<<<dim3(64, 32), 256, 0, stream>>>(aoh, out);
}

// Round 5
// 271.053 us; speedup vs baseline: 1.0142x; 1.0142x over previous
//
#include <hip/hip_runtime.h>
#include <math.h>

#define S 4096
#define QK_SCALE 0.17677669529663687f  // 1/sqrt(32)
#define LOG2E    1.44269504088896f
#define SPLIT 8
#define KS (S / SPLIT)                 // 512 keys per split

typedef _Float16 f16x8 __attribute__((ext_vector_type(8)));
typedef _Float16 f16x4 __attribute__((ext_vector_type(4)));
typedef _Float16 f16x2 __attribute__((ext_vector_type(2)));
typedef float f32x4 __attribute__((ext_vector_type(4)));

// ---------------------------------------------------------------------------
// MFMA lane map (HW-verified R4): A-frag m=l&15, k=(l>>4)*8+j; B-frag n=l&15;
// C reg r: row=(l>>4)*4+r, col=l&15.
// R14: R4's 16x16x16 PV regressed (half FLOPs/inst -> PV MFMA time doubled).
// Base = R2 (263us, best). ONE change: attn Q-tile 64->128, grid (32,4,8)
// = 1024 blocks (exactly 4/CU, tail-free). Two q-halves share staged K/V
// tile, barrier, staging loads, and reg-hoisted V B-frags -> K/V L2 traffic
// and per-work barrier cost halved; MFMA/barrier section doubled at the
// SAME 16x16x32 shape. Ps (9.2KB) serialized between halves (per-wave DS
// order + lgkmcnt(0)). LDS stays 26.4KB; launch_bounds(256,4) caps VGPR 128.
// LDS stride 136 f16 = 68 dw == 4 mod 32 banks -> balanced b128 access.
// ---------------------------------------------------------------------------
template<int R>
__device__ __forceinline__ void stageT(_Float16 (*dst)[136], const _Float16* __restrict__ src,
                                       int ld, int row0, int col0, int tid) {
    int r = tid >> 4, cb = (tid & 15) * 8;   // 16 rows x 128 cols per pass, coalesced
#pragma unroll
    for (int v = 0; v < R / 16; v++)
        *(f16x8*)&dst[v * 16 + r][cb] =
            *(const f16x8*)(src + (size_t)(row0 + v * 16 + r) * ld + col0 + cb);
}

// ---------------------------------------------------------------------------
// setup: weight fp32->fp16 conversion (blocks 0..991) + x/xh copy (992..1503).
// ---------------------------------------------------------------------------
__global__ __launch_bounds__(256) void setup_cvt(const float* __restrict__ q,
                                                 const float* __restrict__ wo,
                                                 const float* __restrict__ w1,
                                                 const float* __restrict__ w2,
                                                 const float* __restrict__ f1,
                                                 const float* __restrict__ f2,
                                                 _Float16* __restrict__ dst,
                                                 const float* __restrict__ a,
                                                 float* __restrict__ x,
                                                 _Float16* __restrict__ xh)
{
    int bb = blockIdx.x;
    if (bb < 992) {
        const float* src; size_t dof; int lb;
        if (bb < 144)      { src = q;  dof = 0;      lb = bb; }
        else if (bb < 192) { src = wo; dof = 147456; lb = bb - 144; }
        else if (bb < 576) { src = w1; dof = 196608; lb = bb - 192; }
        else if (bb < 960) { src = w2; dof = 589824; lb = bb - 576; }
        else if (bb < 976) { src = f1; dof = 983040; lb = bb - 960; }
        else               { src = f2; dof = 999424; lb = bb - 976; }
        int i = lb * 1024 + threadIdx.x * 4;
        float4 v = *(const float4*)(src + i);
        f16x4 h = {(_Float16)v.x, (_Float16)v.y, (_Float16)v.z, (_Float16)v.w};
        *(f16x4*)(dst + dof + i) = h;
    } else {
        int i = (bb - 992) * 256 + threadIdx.x;
        float4 v = ((const float4*)a)[i];
        ((float4*)x)[i] = v;
        f16x4 h = {(_Float16)v.x, (_Float16)v.y, (_Float16)v.z, (_Float16)v.w};
        ((f16x4*)xh)[i] = h;
    }
}

// ---------------------------------------------------------------------------
// QKV GEMM, 16-row tiles, full-K single barrier. grid (256, 3).
// ---------------------------------------------------------------------------
__global__ __launch_bounds__(256) void gemm_qkv(const _Float16* __restrict__ xh,
                                                const _Float16* __restrict__ Wh,
                                                const float* __restrict__ bias,
                                                _Float16* __restrict__ qh,
                                                _Float16* __restrict__ kh,
                                                _Float16* __restrict__ vt)
{
    __shared__ _Float16 Ah[16][136], Bh[128][136];
    int tid = threadIdx.x, w = tid >> 6, l = tid & 63, lc = l & 15, lr = l >> 4;
    int m0 = blockIdx.x * 16, by = blockIdx.y;

    stageT<16>(Ah, xh, 128, m0, 0, tid);
    stageT<128>(Bh, Wh, 128, by * 128, 0, tid);
    __syncthreads();

    f32x4 acc[2];
#pragma unroll
    for (int j = 0; j < 2; j++) acc[j] = {0.f, 0.f, 0.f, 0.f};
#pragma unroll
    for (int ks = 0; ks < 4; ks++) {
        f16x8 af = *(const f16x8*)&Ah[lc][ks * 32 + lr * 8];
#pragma unroll
        for (int j = 0; j < 2; j++) {
            f16x8 bf = *(const f16x8*)&Bh[w * 32 + j * 16 + lc][ks * 32 + lr * 8];
            acc[j] = __builtin_amdgcn_mfma_f32_16x16x32_f16(af, bf, acc[j], 0, 0, 0);
        }
    }

    int mb = m0 + lr * 4;
#pragma unroll
    for (int j = 0; j < 2; j++) {
        int n = w * 32 + j * 16 + lc;
        float bb = bias[by * 128 + n];
        if (by == 0) {
#pragma unroll
            for (int r = 0; r < 4; r++)
                qh[(size_t)(mb + r) * 128 + n] =
                    (_Float16)((acc[j][r] + bb) * (QK_SCALE * LOG2E));
        } else if (by == 1) {
            int hh = n >> 5, d = n & 31;
#pragma unroll
            for (int r = 0; r < 4; r++)
                kh[((size_t)hh * S + mb + r) * 32 + d] = (_Float16)(acc[j][r] + bb);
        } else {
            f16x4 pk;
#pragma unroll
            for (int r = 0; r < 4; r++) pk[r] = (_Float16)(acc[j][r] + bb);
            *(f16x4*)&vt[(size_t)n * S + mb] = pk;
        }
    }
}

// ---------------------------------------------------------------------------
// MFMA flash attention: Q-tile 128 (two 16-q halves per wave), K/V dbuf,
// async-split staging, one barrier/tile; swapped QK^T (C[k][q]); halves
// serialized through one per-wave Ps buffer; V B-frags hoisted to regs and
// shared across halves.
// ---------------------------------------------------------------------------
__global__ __launch_bounds__(256, 4) void attn_mfma(const _Float16* __restrict__ qh,
                                                    const _Float16* __restrict__ kh,
                                                    const _Float16* __restrict__ vt,
                                                    _Float16* __restrict__ part,
                                                    float* __restrict__ mll)
{
    __shared__ _Float16 Ks[2][64][32];
    __shared__ _Float16 Vt[2][32][72];
    __shared__ _Float16 Ps[4][16][72];
    int h = blockIdx.y, q0 = blockIdx.x * 128, z = blockIdx.z;
    int tid = threadIdx.x;
    int w = tid >> 6, l = tid & 63;
    int lc = l & 15, lr = l >> 4;

    f16x8 qfa = *(const f16x8*)&qh[(size_t)(q0 + w * 16 + lc) * 128 + h * 32 + lr * 8];
    f16x8 qfb = *(const f16x8*)&qh[(size_t)(q0 + 64 + w * 16 + lc) * 128 + h * 32 + lr * 8];

    const _Float16* khh = kh + (size_t)h * S * 32;
    const _Float16* vth = vt + (size_t)h * 32 * S;

    int krow = tid >> 2, kcol = (tid & 3) * 8;
    int vrow = tid >> 3, vcol = (tid & 7) * 8;

    f32x4 oa0 = {0.f, 0.f, 0.f, 0.f}, oa1 = {0.f, 0.f, 0.f, 0.f};
    f32x4 ob0 = {0.f, 0.f, 0.f, 0.f}, ob1 = {0.f, 0.f, 0.f, 0.f};
    float lpa = 0.f, lpb = 0.f;

    int k0 = z * KS;
    {   // prologue: stage tile 0
        f16x8 kr = *(const f16x8*)&khh[(size_t)(k0 + krow) * 32 + kcol];
        f16x8 vr = *(const f16x8*)&vth[(size_t)vrow * S + k0 + vcol];
        *(f16x8*)&Ks[0][krow][kcol] = kr;
        *(f16x8*)&Vt[0][vrow][vcol] = vr;
    }
    __syncthreads();

    int cur = 0;
#pragma unroll 1
    for (int t8 = 0; t8 < KS / 64; t8++) {
        bool more = (t8 + 1 < KS / 64);
        f16x8 kr, vr;
        if (more) {   // issue next tile's loads early; latency hides under compute
            int kn = k0 + (t8 + 1) * 64;
            kr = *(const f16x8*)&khh[(size_t)(kn + krow) * 32 + kcol];
            vr = *(const f16x8*)&vth[(size_t)vrow * S + kn + vcol];
        }

        // ---- half a: QK^T (swapped), exp2, Ps, PV ----
        f32x4 st[4];
#pragma unroll
        for (int t = 0; t < 4; t++) {
            f16x8 kf = *(const f16x8*)&Ks[cur][t * 16 + lc][lr * 8];
            f32x4 zz = {0.f, 0.f, 0.f, 0.f};
            st[t] = __builtin_amdgcn_mfma_f32_16x16x32_f16(kf, qfa, zz, 0, 0, 0);
        }
#pragma unroll
        for (int t = 0; t < 4; t++) {
            float p0 = exp2f(st[t][0]), p1 = exp2f(st[t][1]);
            float p2 = exp2f(st[t][2]), p3 = exp2f(st[t][3]);
            lpa += (p0 + p1) + (p2 + p3);
            f16x2 h0 = {(_Float16)p0, (_Float16)p1};
            f16x2 h1 = {(_Float16)p2, (_Float16)p3};
            *(f16x2*)&Ps[w][lc][t * 16 + lr * 4]     = h0;
            *(f16x2*)&Ps[w][lc][t * 16 + lr * 4 + 2] = h1;
        }
        asm volatile("s_waitcnt lgkmcnt(0)" ::: "memory");
        // V B-frags hoisted once, shared by both halves
        f16x8 vg0 = *(const f16x8*)&Vt[cur][lc][lr * 8];
        f16x8 vg1 = *(const f16x8*)&Vt[cur][16 + lc][lr * 8];
        f16x8 vg2 = *(const f16x8*)&Vt[cur][lc][32 + lr * 8];
        f16x8 vg3 = *(const f16x8*)&Vt[cur][16 + lc][32 + lr * 8];
        {
            f16x8 pf0 = *(const f16x8*)&Ps[w][lc][lr * 8];
            f16x8 pf1 = *(const f16x8*)&Ps[w][lc][32 + lr * 8];
            oa0 = __builtin_amdgcn_mfma_f32_16x16x32_f16(pf0, vg0, oa0, 0, 0, 0);
            oa1 = __builtin_amdgcn_mfma_f32_16x16x32_f16(pf0, vg1, oa1, 0, 0, 0);
            oa0 = __builtin_amdgcn_mfma_f32_16x16x32_f16(pf1, vg2, oa0, 0, 0, 0);
            oa1 = __builtin_amdgcn_mfma_f32_16x16x32_f16(pf1, vg3, oa1, 0, 0, 0);
        }

        // ---- half b: QK^T, exp2, Ps (overwrite; per-wave DS order), PV ----
#pragma unroll
        for (int t = 0; t < 4; t++) {
            f16x8 kf = *(const f16x8*)&Ks[cur][t * 16 + lc][lr * 8];
            f32x4 zz = {0.f, 0.f, 0.f, 0.f};
            st[t] = __builtin_amdgcn_mfma_f32_16x16x32_f16(kf, qfb, zz, 0, 0, 0);
        }
#pragma unroll
        for (int t = 0; t < 4; t++) {
            float p0 = exp2f(st[t][0]), p1 = exp2f(st[t][1]);
            float p2 = exp2f(st[t][2]), p3 = exp2f(st[t][3]);
            lpb += (p0 + p1) + (p2 + p3);
            f16x2 h0 = {(_Float16)p0, (_Float16)p1};
            f16x2 h1 = {(_Float16)p2, (_Float16)p3};
            *(f16x2*)&Ps[w][lc][t * 16 + lr * 4]     = h0;
            *(f16x2*)&Ps[w][lc][t * 16 + lr * 4 + 2] = h1;
        }
        asm volatile("s_waitcnt lgkmcnt(0)" ::: "memory");
        {
            f16x8 pf0 = *(const f16x8*)&Ps[w][lc][lr * 8];
            f16x8 pf1 = *(const f16x8*)&Ps[w][lc][32 + lr * 8];
            ob0 = __builtin_amdgcn_mfma_f32_16x16x32_f16(pf0, vg0, ob0, 0, 0, 0);
            ob1 = __builtin_amdgcn_mfma_f32_16x16x32_f16(pf0, vg1, ob1, 0, 0, 0);
            ob0 = __builtin_amdgcn_mfma_f32_16x16x32_f16(pf1, vg2, ob0, 0, 0, 0);
            ob1 = __builtin_amdgcn_mfma_f32_16x16x32_f16(pf1, vg3, ob1, 0, 0, 0);
        }

        if (more) {
            *(f16x8*)&Ks[cur ^ 1][krow][kcol] = kr;
            *(f16x8*)&Vt[cur ^ 1][vrow][vcol] = vr;
            __syncthreads();
        }
        cur ^= 1;
    }

    lpa += __shfl_xor(lpa, 16);
    lpa += __shfl_xor(lpa, 32);
    lpb += __shfl_xor(lpb, 16);
    lpb += __shfl_xor(lpb, 32);

    _Float16* pz = part + (size_t)z * 524288;
#pragma unroll
    for (int i = 0; i < 4; i++) {
        int qa = q0 + w * 16 + lr * 4 + i;
        int qb = qa + 64;
        pz[(size_t)qa * 128 + h * 32 + lc]      = (_Float16)oa0[i];
        pz[(size_t)qa * 128 + h * 32 + 16 + lc] = (_Float16)oa1[i];
        pz[(size_t)qb * 128 + h * 32 + lc]      = (_Float16)ob0[i];
        pz[(size_t)qb * 128 + h * 32 + 16 + lc] = (_Float16)ob1[i];
    }
    if (l < 16) {
        mll[((size_t)z * 4 + h) * 4096 + q0 + w * 16 + lc]      = lpa;
        mll[((size_t)z * 4 + h) * 4096 + q0 + 64 + w * 16 + lc] = lpb;
    }
}

// ---------------------------------------------------------------------------
// Wo GEMM + split-attention merge + residual + LayerNorm. 16-row tiles.
// ---------------------------------------------------------------------------
__global__ __launch_bounds__(256) void wo_ln_merge(const _Float16* __restrict__ part,
                                                   const float* __restrict__ mll,
                                                   const _Float16* __restrict__ Wh,
                                                   const float* __restrict__ bias,
                                                   float* __restrict__ x,
                                                   _Float16* __restrict__ xh,
                                                   const float* __restrict__ g,
                                                   const float* __restrict__ b)
{
    __shared__ _Float16 Ah[16][136], Bh[128][136];
    __shared__ float Red[16][4][2];
    int tid = threadIdx.x, w = tid >> 6, l = tid & 63, lc = l & 15, lr = l >> 4;
    int m0 = blockIdx.x * 16;

    {   // merge-stage A: 16 rows x 128 cols, 8 cols/thread
        int row = tid >> 4, col0 = (tid & 15) * 8;
        int q = m0 + row, hh = col0 >> 5;
        float lsum = 0.f;
#pragma unroll
        for (int s = 0; s < SPLIT; s++) lsum += mll[((size_t)s * 4 + hh) * 4096 + q];
        float am[8];
#pragma unroll
        for (int e = 0; e < 8; e++) am[e] = 0.f;
#pragma unroll
        for (int s = 0; s < SPLIT; s++) {
            f16x8 t = *(const f16x8*)&part[(size_t)s * 524288 + (size_t)q * 128 + col0];
#pragma unroll
            for (int e = 0; e < 8; e++) am[e] += (float)t[e];
        }
        float inv = 1.f / lsum;
        f16x8 hv;
#pragma unroll
        for (int e = 0; e < 8; e++) hv[e] = (_Float16)(am[e] * inv);
        *(f16x8*)&Ah[row][col0] = hv;
    }
    stageT<128>(Bh, Wh, 128, 0, 0, tid);
    __syncthreads();

    f32x4 acc[2];
#pragma unroll
    for (int j = 0; j < 2; j++) acc[j] = {0.f, 0.f, 0.f, 0.f};
#pragma unroll
    for (int ks = 0; ks < 4; ks++) {
        f16x8 af = *(const f16x8*)&Ah[lc][ks * 32 + lr * 8];
#pragma unroll
        for (int j = 0; j < 2; j++) {
            f16x8 bf = *(const f16x8*)&Bh[w * 32 + j * 16 + lc][ks * 32 + lr * 8];
            acc[j] = __builtin_amdgcn_mfma_f32_16x16x32_f16(af, bf, acc[j], 0, 0, 0);
        }
    }

#pragma unroll
    for (int j = 0; j < 2; j++) {
        int n = w * 32 + j * 16 + lc;
        float bb = bias[n];
#pragma unroll
        for (int r = 0; r < 4; r++)
            acc[j][r] += bb + x[(size_t)(m0 + lr * 4 + r) * 128 + n];
    }
#pragma unroll
    for (int r = 0; r < 4; r++) {
        float s1 = acc[0][r] + acc[1][r];
        float s2 = acc[0][r] * acc[0][r] + acc[1][r] * acc[1][r];
#pragma unroll
        for (int off = 1; off < 16; off <<= 1) {
            s1 += __shfl_xor(s1, off);
            s2 += __shfl_xor(s2, off);
        }
        if (lc == 0) { Red[lr * 4 + r][w][0] = s1; Red[lr * 4 + r][w][1] = s2; }
    }
    __syncthreads();
#pragma unroll
    for (int r = 0; r < 4; r++) {
        int rl = lr * 4 + r;
        float S1 = (Red[rl][0][0] + Red[rl][1][0]) + (Red[rl][2][0] + Red[rl][3][0]);
        float S2 = (Red[rl][0][1] + Red[rl][1][1]) + (Red[rl][2][1] + Red[rl][3][1]);
        float mean = S1 * (1.0f / 128.0f);
        float var = S2 * (1.0f / 128.0f) - mean * mean;
        float inv = rsqrtf(var + 1e-5f);
        int m = m0 + rl;
#pragma unroll
        for (int j = 0; j < 2; j++) {
            int n = w * 32 + j * 16 + lc;
            float o = (acc[j][r] - mean) * inv * g[n] + b[n];
            x[(size_t)m * 128 + n] = o;
            xh[(size_t)m * 128 + n] = (_Float16)o;
        }
    }
}

// ---------------------------------------------------------------------------
// Fused W1+W2 pair, 64-row tiles, grid (64, 8) = 512 blocks.
// ---------------------------------------------------------------------------
__global__ __launch_bounds__(256) void ffn_pair(const _Float16* __restrict__ xh,
                                                const _Float16* __restrict__ W1h,
                                                const float* __restrict__ b1,
                                                const _Float16* __restrict__ W2h,
                                                _Float16* __restrict__ wpart)
{
    __shared__ _Float16 Ah[64][136], Bh[128][136];
    int tid = threadIdx.x, w = tid >> 6, l = tid & 63, lc = l & 15, lr = l >> 4;
    int wr = w >> 1, wc = w & 1;
    int m0 = blockIdx.x * 64, c = blockIdx.y;

    stageT<64>(Ah, xh, 128, m0, 0, tid);
    stageT<128>(Bh, W1h, 128, c * 128, 0, tid);
    __syncthreads();

    f32x4 acc[2][4];
#pragma unroll
    for (int i = 0; i < 2; i++)
#pragma unroll
        for (int j = 0; j < 4; j++) acc[i][j] = {0.f, 0.f, 0.f, 0.f};
#pragma unroll
    for (int ks = 0; ks < 4; ks++) {
        f16x8 af0 = *(const f16x8*)&Ah[wr * 32 + lc][ks * 32 + lr * 8];
        f16x8 af1 = *(const f16x8*)&Ah[wr * 32 + 16 + lc][ks * 32 + lr * 8];
#pragma unroll
        for (int j = 0; j < 4; j++) {
            f16x8 bf = *(const f16x8*)&Bh[wc * 64 + j * 16 + lc][ks * 32 + lr * 8];
            acc[0][j] = __builtin_amdgcn_mfma_f32_16x16x32_f16(af0, bf, acc[0][j], 0, 0, 0);
            acc[1][j] = __builtin_amdgcn_mfma_f32_16x16x32_f16(af1, bf, acc[1][j], 0, 0, 0);
        }
    }
    __syncthreads();

#pragma unroll
    for (int i = 0; i < 2; i++)
#pragma unroll
        for (int j = 0; j < 4; j++) {
            int n = wc * 64 + j * 16 + lc;
            float bb = b1[c * 128 + n];
#pragma unroll
            for (int r = 0; r < 4; r++)
                Ah[wr * 32 + i * 16 + lr * 4 + r][n] =
                    (_Float16)fmaxf(acc[i][j][r] + bb, 0.f);
        }
    stageT<128>(Bh, W2h, 1024, 0, c * 128, tid);
    __syncthreads();

    f32x4 oacc[2][4];
#pragma unroll
    for (int i = 0; i < 2; i++)
#pragma unroll
        for (int j = 0; j < 4; j++) oacc[i][j] = {0.f, 0.f, 0.f, 0.f};
#pragma unroll
    for (int ks = 0; ks < 4; ks++) {
        f16x8 af0 = *(const f16x8*)&Ah[wr * 32 + lc][ks * 32 + lr * 8];
        f16x8 af1 = *(const f16x8*)&Ah[wr * 32 + 16 + lc][ks * 32 + lr * 8];
#pragma unroll
        for (int j = 0; j < 4; j++) {
            f16x8 bf = *(const f16x8*)&Bh[wc * 64 + j * 16 + lc][ks * 32 + lr * 8];
            oacc[0][j] = __builtin_amdgcn_mfma_f32_16x16x32_f16(af0, bf, oacc[0][j], 0, 0, 0);
            oacc[1][j] = __builtin_amdgcn_mfma_f32_16x16x32_f16(af1, bf, oacc[1][j], 0, 0, 0);
        }
    }

    _Float16* pz = wpart + (size_t)c * 524288;
#pragma unroll
    for (int i = 0; i < 2; i++) {
        int mb = m0 + wr * 32 + i * 16 + lr * 4;
#pragma unroll
        for (int j = 0; j < 4; j++) {
            int n = wc * 64 + j * 16 + lc;
#pragma unroll
            for (int r = 0; r < 4; r++)
                pz[(size_t)(mb + r) * 128 + n] = (_Float16)oacc[i][j][r];
        }
    }
}

// ---------------------------------------------------------------------------
// reduce 8 fp16 W2 partials + bias + residual + LayerNorm -> x, xh.
// ---------------------------------------------------------------------------
__global__ __launch_bounds__(256) void reduce8_ln(const _Float16* __restrict__ part,
                                                  const float* __restrict__ bias,
                                                  float* __restrict__ x,
                                                  _Float16* __restrict__ xh,
                                                  const float* __restrict__ g,
                                                  const float* __restrict__ b)
{
    int row  = blockIdx.x * 4 + (threadIdx.x >> 6);
    int lane = threadIdx.x & 63;
    size_t base = (size_t)row * 128;
    int c = lane * 2;
    float a0 = 0.f, a1 = 0.f;
#pragma unroll
    for (int s = 0; s < 8; s++) {
        f16x2 p = *(const f16x2*)&part[(size_t)s * 524288 + base + c];
        a0 += (float)p[0]; a1 += (float)p[1];
    }
    float2 bv = *(const float2*)&bias[c];
    float2 xv = *(const float2*)&x[base + c];
    a0 += bv.x + xv.x; a1 += bv.y + xv.y;
    float s = a0 + a1;
#pragma unroll
    for (int off = 32; off; off >>= 1) s += __shfl_xor(s, off);
    float mean = s * (1.0f / 128.0f);
    float d0 = a0 - mean, d1 = a1 - mean;
    float v = d0 * d0 + d1 * d1;
#pragma unroll
    for (int off = 32; off; off >>= 1) v += __shfl_xor(v, off);
    float inv = rsqrtf(v * (1.0f / 128.0f) + 1e-5f);
    float2 gv = *(const float2*)&g[c];
    float2 bb = *(const float2*)&b[c];
    float o0 = d0 * inv * gv.x + bb.x, o1 = d1 * inv * gv.y + bb.y;
    float2 r; r.x = o0; r.y = o1;
    *(float2*)&x[base + c] = r;
    f16x2 rh = {(_Float16)o0, (_Float16)o1};
    *(f16x2*)&xh[base + c] = rh;
}

// ---------------------------------------------------------------------------
// fc1 + relu + fc2 + rownorm fused. 16-row tiles, grid 256.
// ---------------------------------------------------------------------------
__global__ __launch_bounds__(256) void fc_fused(const _Float16* __restrict__ xh,
                                                const _Float16* __restrict__ W1h,
                                                const float* __restrict__ b1f,
                                                const _Float16* __restrict__ W2h,
                                                const float* __restrict__ b2f,
                                                _Float16* __restrict__ aoh)
{
    __shared__ _Float16 Ah[16][136], Bh[128][136];
    __shared__ float Red[16][4];
    int tid = threadIdx.x, w = tid >> 6, l = tid & 63, lc = l & 15, lr = l >> 4;
    int m0 = blockIdx.x * 16;

    stageT<16>(Ah, xh, 128, m0, 0, tid);
    stageT<128>(Bh, W1h, 128, 0, 0, tid);
    __syncthreads();

    f32x4 acc[2];
#pragma unroll
    for (int j = 0; j < 2; j++) acc[j] = {0.f, 0.f, 0.f, 0.f};
#pragma unroll
    for (int ks = 0; ks < 4; ks++) {
        f16x8 af = *(const f16x8*)&Ah[lc][ks * 32 + lr * 8];
#pragma unroll
        for (int j = 0; j < 2; j++) {
            f16x8 bf = *(const f16x8*)&Bh[w * 32 + j * 16 + lc][ks * 32 + lr * 8];
            acc[j] = __builtin_amdgcn_mfma_f32_16x16x32_f16(af, bf, acc[j], 0, 0, 0);
        }
    }
    __syncthreads();
#pragma unroll
    for (int j = 0; j < 2; j++) {
        int n = w * 32 + j * 16 + lc;
        float bb = b1f[n];
#pragma unroll
        for (int r = 0; r < 4; r++)
            Ah[lr * 4 + r][n] = (_Float16)fmaxf(acc[j][r] + bb, 0.f);
    }
    stageT<128>(Bh, W2h, 128, 0, 0, tid);
    __syncthreads();

    f32x4 o[2];
#pragma unroll
    for (int j = 0; j < 2; j++) o[j] = {0.f, 0.f, 0.f, 0.f};
#pragma unroll
    for (int ks = 0; ks < 4; ks++) {
        f16x8 af = *(const f16x8*)&Ah[lc][ks * 32 + lr * 8];
#pragma unroll
        for (int j = 0; j < 2; j++) {
            f16x8 bf = *(const f16x8*)&Bh[w * 32 + j * 16 + lc][ks * 32 + lr * 8];
            o[j] = __builtin_amdgcn_mfma_f32_16x16x32_f16(af, bf, o[j], 0, 0, 0);
        }
    }
#pragma unroll
    for (int j = 0; j < 2; j++) {
        float bb = b2f[w * 32 + j * 16 + lc];
#pragma unroll
        for (int r = 0; r < 4; r++) o[j][r] += bb;
    }
#pragma unroll
    for (int r = 0; r < 4; r++) {
        float s2 = o[0][r] * o[0][r] + o[1][r] * o[1][r];
#pragma unroll
        for (int off = 1; off < 16; off <<= 1) s2 += __shfl_xor(s2, off);
        if (lc == 0) Red[lr * 4 + r][w] = s2;
    }
    __syncthreads();
#pragma unroll
    for (int r = 0; r < 4; r++) {
        int rl = lr * 4 + r;
        float inv = rsqrtf((Red[rl][0] + Red[rl][1]) + (Red[rl][2] + Red[rl][3]));
        int m = m0 + rl;
#pragma unroll
        for (int j = 0; j < 2; j++) {
            int n = w * 32 + j * 16 + lc;
            aoh[(size_t)m * 128 + n] = (_Float16)(o[j][r] * inv);
        }
    }
}

// ---------------------------------------------------------------------------
// Gram: C = max(aoh @ aoh^T, 1e-6). 64x128 tiles, full-K single barrier,
// grid (64, 32) = 2048 blocks.
// ---------------------------------------------------------------------------
__global__ __launch_bounds__(256) void gram_f16(const _Float16* __restrict__ aoh,
                                                float* __restrict__ C)
{
    __shared__ _Float16 Ah[64][136], Bh[128][136];
    int tid = threadIdx.x, w = tid >> 6, l = tid & 63, lc = l & 15, lr = l >> 4;
    int wr = w >> 1, wc = w & 1;
    int m0 = blockIdx.x * 64, n0 = blockIdx.y * 128;

    stageT<64>(Ah, aoh, 128, m0, 0, tid);
    stageT<128>(Bh, aoh, 128, n0, 0, tid);
    __syncthreads();

    f32x4 acc[2][4];
#pragma unroll
    for (int i = 0; i < 2; i++)
#pragma unroll
        for (int j = 0; j < 4; j++) acc[i][j] = {0.f, 0.f, 0.f, 0.f};
#pragma unroll
    for (int ks = 0; ks < 4; ks++) {
        f16x8 af0 = *(const f16x8*)&Ah[wr * 32 + lc][ks * 32 + lr * 8];
        f16x8 af1 = *(const f16x8*)&Ah[wr * 32 + 16 + lc][ks * 32 + lr * 8];
#pragma unroll
        for (int j = 0; j < 4; j++) {
            f16x8 bf = *(const f16x8*)&Bh[wc * 64 + j * 16 + lc][ks * 32 + lr * 8];
            acc[0][j] = __builtin_amdgcn_mfma_f32_16x16x32_f16(af0, bf, acc[0][j], 0, 0, 0);
            acc[1][j] = __builtin_amdgcn_mfma_f32_16x16x32_f16(af1, bf, acc[1][j], 0, 0, 0);
        }
    }

#pragma unroll
    for (int i = 0; i < 2; i++) {
        int mb = m0 + wr * 32 + i * 16 + lr * 4;
#pragma unroll
        for (int j = 0; j < 4; j++) {
            int n = n0 + wc * 64 + j * 16 + lc;
#pragma unroll
            for (int r = 0; r < 4; r++)
                C[(size_t)(mb + r) * 4096 + n] = fmaxf(acc[i][j][r], 1e-6f);
        }
    }
}

// ---------------------------------------------------------------------------
extern "C" void kernel_launch(void* const* d_in, const int* in_sizes, int n_in,
                              void* d_out, int out_size, void* d_ws, size_t ws_size,
                              hipStream_t stream)
{
    const float* src  = (const float*)d_in[0];
    const float* Wqkv = (const float*)d_in[1];
    const float* bqkv = (const float*)d_in[2];
    const float* Wo   = (const float*)d_in[3];
    const float* bo   = (const float*)d_in[4];
    const float* ln1g = (const float*)d_in[5];
    const float* ln1b = (const float*)d_in[6];
    const float* W1   = (const float*)d_in[7];
    const float* b1   = (const float*)d_in[8];
    const float* W2   = (const float*)d_in[9];
    const float* b2   = (const float*)d_in[10];
    const float* ln2g = (const float*)d_in[11];
    const float* ln2b = (const float*)d_in[12];
    const float* fc1W = (const float*)d_in[13];
    const float* fc1b = (const float*)d_in[14];
    const float* fc2W = (const float*)d_in[15];
    const float* fc2b = (const float*)d_in[16];

    float* ws = (float*)d_ws;
    float*    x   = ws;                                   // 524288 f32
    _Float16* xh  = (_Float16*)(ws + 524288);             // 524288 f16
    _Float16* aoh = (_Float16*)(ws + 786432);             // 524288 f16
    _Float16* qh  = (_Float16*)(ws + 1048576);            // 524288 f16
    _Float16* kh  = (_Float16*)(ws + 1310720);            // 524288 f16
    _Float16* vt  = (_Float16*)(ws + 1572864);            // 524288 f16
    float*    mll = ws + 1835008;                         // 131072 f32

    // d_out scratch (all dead before gram writes):
    _Float16* wpart = (_Float16*)d_out + 4194304;         // bytes [ 8MiB,16MiB)
    _Float16* apart = (_Float16*)d_out + 12582912;        // bytes [24MiB,32MiB)
    _Float16* wh    = (_Float16*)d_out + 16777216;        // bytes [32MiB,~34MiB)
    float*    out   = (float*)d_out;

    _Float16* qkvh = wh;                  // 3 x 384 x 128
    _Float16* woh  = wh + 147456;         // 3 x 128 x 128
    _Float16* w1h  = wh + 196608;         // 3 x 1024 x 128
    _Float16* w2h  = wh + 589824;         // 3 x 128 x 1024
    _Float16* fc1h = wh + 983040;         // 128 x 128
    _Float16* fc2h = wh + 999424;         // 128 x 128

    setup_cvt<<<1504, 256, 0, stream>>>(Wqkv, Wo, W1, W2, fc1W, fc2W, wh,
                                        src, x, xh);
    for (int l = 0; l < 3; l++) {
        gemm_qkv<<<dim3(256, 3), 256, 0, stream>>>(xh, qkvh + l * 49152,
                                                   bqkv + l * 384, qh, kh, vt);
        attn_mfma<<<dim3(32, 4, SPLIT), 256, 0, stream>>>(qh, kh, vt, apart, mll);
        wo_ln_merge<<<256, 256, 0, stream>>>(apart, mll, woh + l * 16384, bo + l * 128,
                                             x, xh, ln1g + l * 128, ln1b + l * 128);
        ffn_pair<<<dim3(64, 8), 256, 0, stream>>>(xh, w1h + l * 131072, b1 + l * 1024,
                                                  w2h + l * 131072, wpart);
        reduce8_ln<<<1024, 256, 0, stream>>>(wpart, b2 + l * 128, x, xh,
                                             ln2g + l * 128, ln2b + l * 128);
    }
    fc_fused<<<256, 256, 0, stream>>>(xh, fc1h, fc1b, fc2h, fc2b, aoh);
    gram_f16<<<dim3(64, 32), 256, 0, stream>>>(aoh, out);
}

// Round 6
// 264.011 us; speedup vs baseline: 1.0413x; 1.0267x over previous
//
#include <hip/hip_runtime.h>
#include <math.h>

#define S 4096
#define QK_SCALE 0.17677669529663687f  // 1/sqrt(32)
#define LOG2E    1.44269504088896f
#define SPLIT 8
#define KS (S / SPLIT)                 // 512 keys per split

typedef _Float16 f16x8 __attribute__((ext_vector_type(8)));
typedef _Float16 f16x4 __attribute__((ext_vector_type(4)));
typedef _Float16 f16x2 __attribute__((ext_vector_type(2)));
typedef float f32x4 __attribute__((ext_vector_type(4)));

// ---------------------------------------------------------------------------
// MFMA lane map (HW-verified R4): A-frag m=l&15, k=(l>>4)*8+j; B-frag n=l&15;
// C reg r: row=(l>>4)*4+r, col=l&15.
// R15: base = R2 (263us, best; R3/R4/R5 attn experiments all regressed ->
// attn untouched). ONE mechanism: GEMM staging via global_load_lds (16B,
// direct-to-LDS, no VGPR round trip). Linear LDS dest required -> XOR
// swizzle on the GLOBAL source granule (g ^= row&15) + same XOR on reads
// (both-sides involution). All fragment reads = one 16B granule; swizzled
// bank pattern = 2 lanes/bank (free). Computed tiles (merge-A, relu-F, X2)
// write with the same element swizzle.
// ---------------------------------------------------------------------------

// direct-to-LDS stage of ROWS x 128 f16 tile, linear [128] stride, source
// granule-swizzled so a swizzled read recovers logical layout.
template<int ROWS>
__device__ __forceinline__ void stageGL(_Float16 (*dst)[128], const _Float16* src,
                                        int ld, int row0, int col0, int tid) {
    int w = tid >> 6, l = tid & 63;
    constexpr int NISS = ROWS / 16;         // wave-issues per wave (4 waves)
#pragma unroll
    for (int v = 0; v < NISS; v++) {
        int G = (w * NISS + v) * 64 + l;    // linear granule id
        int row = G >> 4, g = G & 15;
        int gs = g ^ (row & 15);            // swizzled source granule
        const void* gp = src + (size_t)(row0 + row) * ld + col0 + gs * 8;
        void* lp = (char*)&dst[0][0] + (size_t)G * 16;
        __builtin_amdgcn_global_load_lds(
            (const __attribute__((address_space(1))) void*)gp,
            (__attribute__((address_space(3))) void*)lp, 16, 0, 0);
    }
}

// swizzled 16B fragment read: logical granule qg of row
__device__ __forceinline__ f16x8 rdS(const _Float16 (*B)[128], int row, int qg) {
    return *(const f16x8*)&B[row][(qg ^ (row & 15)) << 3];
}
// swizzled element write (for register-computed tiles)
__device__ __forceinline__ void wrS(_Float16 (*B)[128], int row, int col, _Float16 v) {
    B[row][((((col >> 3) ^ (row & 15))) << 3) | (col & 7)] = v;
}

// ---------------------------------------------------------------------------
// setup: weight fp32->fp16 conversion (blocks 0..991) + x/xh copy (992..1503).
// ---------------------------------------------------------------------------
__global__ __launch_bounds__(256) void setup_cvt(const float* __restrict__ q,
                                                 const float* __restrict__ wo,
                                                 const float* __restrict__ w1,
                                                 const float* __restrict__ w2,
                                                 const float* __restrict__ f1,
                                                 const float* __restrict__ f2,
                                                 _Float16* __restrict__ dst,
                                                 const float* __restrict__ a,
                                                 float* __restrict__ x,
                                                 _Float16* __restrict__ xh)
{
    int bb = blockIdx.x;
    if (bb < 992) {
        const float* src; size_t dof; int lb;
        if (bb < 144)      { src = q;  dof = 0;      lb = bb; }
        else if (bb < 192) { src = wo; dof = 147456; lb = bb - 144; }
        else if (bb < 576) { src = w1; dof = 196608; lb = bb - 192; }
        else if (bb < 960) { src = w2; dof = 589824; lb = bb - 576; }
        else if (bb < 976) { src = f1; dof = 983040; lb = bb - 960; }
        else               { src = f2; dof = 999424; lb = bb - 976; }
        int i = lb * 1024 + threadIdx.x * 4;
        float4 v = *(const float4*)(src + i);
        f16x4 h = {(_Float16)v.x, (_Float16)v.y, (_Float16)v.z, (_Float16)v.w};
        *(f16x4*)(dst + dof + i) = h;
    } else {
        int i = (bb - 992) * 256 + threadIdx.x;
        float4 v = ((const float4*)a)[i];
        ((float4*)x)[i] = v;
        f16x4 h = {(_Float16)v.x, (_Float16)v.y, (_Float16)v.z, (_Float16)v.w};
        ((f16x4*)xh)[i] = h;
    }
}

// ---------------------------------------------------------------------------
// QKV GEMM, 16-row tiles, full-K single barrier, glds staging. grid (256, 3).
// ---------------------------------------------------------------------------
__global__ __launch_bounds__(256) void gemm_qkv(const _Float16* __restrict__ xh,
                                                const _Float16* __restrict__ Wh,
                                                const float* __restrict__ bias,
                                                _Float16* __restrict__ qh,
                                                _Float16* __restrict__ kh,
                                                _Float16* __restrict__ vt)
{
    __shared__ _Float16 Ah[16][128], Bh[128][128];
    int tid = threadIdx.x, w = tid >> 6, l = tid & 63, lc = l & 15, lr = l >> 4;
    int m0 = blockIdx.x * 16, by = blockIdx.y;

    stageGL<16>(Ah, xh, 128, m0, 0, tid);
    stageGL<128>(Bh, Wh, 128, by * 128, 0, tid);
    __syncthreads();

    f32x4 acc[2];
#pragma unroll
    for (int j = 0; j < 2; j++) acc[j] = {0.f, 0.f, 0.f, 0.f};
#pragma unroll
    for (int ks = 0; ks < 4; ks++) {
        f16x8 af = rdS(Ah, lc, ks * 4 + lr);
#pragma unroll
        for (int j = 0; j < 2; j++) {
            f16x8 bf = rdS(Bh, w * 32 + j * 16 + lc, ks * 4 + lr);
            acc[j] = __builtin_amdgcn_mfma_f32_16x16x32_f16(af, bf, acc[j], 0, 0, 0);
        }
    }

    int mb = m0 + lr * 4;
#pragma unroll
    for (int j = 0; j < 2; j++) {
        int n = w * 32 + j * 16 + lc;
        float bb = bias[by * 128 + n];
        if (by == 0) {
#pragma unroll
            for (int r = 0; r < 4; r++)
                qh[(size_t)(mb + r) * 128 + n] =
                    (_Float16)((acc[j][r] + bb) * (QK_SCALE * LOG2E));
        } else if (by == 1) {
            int hh = n >> 5, d = n & 31;
#pragma unroll
            for (int r = 0; r < 4; r++)
                kh[((size_t)hh * S + mb + r) * 32 + d] = (_Float16)(acc[j][r] + bb);
        } else {
            f16x4 pk;
#pragma unroll
            for (int r = 0; r < 4; r++) pk[r] = (_Float16)(acc[j][r] + bb);
            *(f16x4*)&vt[(size_t)n * S + mb] = pk;
        }
    }
}

// ---------------------------------------------------------------------------
// MFMA flash attention (R2 version, untouched): K/V double-buffer,
// async-split staging, one barrier/tile; swapped QK^T, packed Ps.
// ---------------------------------------------------------------------------
__global__ __launch_bounds__(256) void attn_mfma(const _Float16* __restrict__ qh,
                                                 const _Float16* __restrict__ kh,
                                                 const _Float16* __restrict__ vt,
                                                 _Float16* __restrict__ part,
                                                 float* __restrict__ mll)
{
    __shared__ _Float16 Ks[2][64][32];
    __shared__ _Float16 Vt[2][32][72];
    __shared__ _Float16 Ps[4][16][72];
    int h = blockIdx.y, q0 = blockIdx.x * 64, z = blockIdx.z;
    int tid = threadIdx.x;
    int w = tid >> 6, l = tid & 63;
    int lc = l & 15, lr = l >> 4;

    f16x8 qf = *(const f16x8*)&qh[(size_t)(q0 + w * 16 + lc) * 128 + h * 32 + lr * 8];

    const _Float16* khh = kh + (size_t)h * S * 32;
    const _Float16* vth = vt + (size_t)h * 32 * S;

    int krow = tid >> 2, kcol = (tid & 3) * 8;
    int vrow = tid >> 3, vcol = (tid & 7) * 8;

    f32x4 o0 = {0.f, 0.f, 0.f, 0.f}, o1 = {0.f, 0.f, 0.f, 0.f};
    float lp = 0.f;

    int k0 = z * KS;
    {   // prologue: stage tile 0
        f16x8 kr = *(const f16x8*)&khh[(size_t)(k0 + krow) * 32 + kcol];
        f16x8 vr = *(const f16x8*)&vth[(size_t)vrow * S + k0 + vcol];
        *(f16x8*)&Ks[0][krow][kcol] = kr;
        *(f16x8*)&Vt[0][vrow][vcol] = vr;
    }
    __syncthreads();

    int cur = 0;
#pragma unroll 1
    for (int t8 = 0; t8 < KS / 64; t8++) {
        bool more = (t8 + 1 < KS / 64);
        f16x8 kr, vr;
        if (more) {   // issue next tile's loads early; latency hides under compute
            int kn = k0 + (t8 + 1) * 64;
            kr = *(const f16x8*)&khh[(size_t)(kn + krow) * 32 + kcol];
            vr = *(const f16x8*)&vth[(size_t)vrow * S + kn + vcol];
        }

        f32x4 st[4];
#pragma unroll
        for (int t = 0; t < 4; t++) {
            f16x8 kf = *(const f16x8*)&Ks[cur][t * 16 + lc][lr * 8];
            f32x4 zz = {0.f, 0.f, 0.f, 0.f};
            st[t] = __builtin_amdgcn_mfma_f32_16x16x32_f16(kf, qf, zz, 0, 0, 0);
        }
#pragma unroll
        for (int t = 0; t < 4; t++) {
            float p0 = exp2f(st[t][0]), p1 = exp2f(st[t][1]);
            float p2 = exp2f(st[t][2]), p3 = exp2f(st[t][3]);
            lp += (p0 + p1) + (p2 + p3);
            f16x2 h0 = {(_Float16)p0, (_Float16)p1};
            f16x2 h1 = {(_Float16)p2, (_Float16)p3};
            *(f16x2*)&Ps[w][lc][t * 16 + lr * 4]     = h0;
            *(f16x2*)&Ps[w][lc][t * 16 + lr * 4 + 2] = h1;
        }
        asm volatile("s_waitcnt lgkmcnt(0)" ::: "memory");
#pragma unroll
        for (int ch = 0; ch < 2; ch++) {
            f16x8 pf = *(const f16x8*)&Ps[w][lc][ch * 32 + lr * 8];
            f16x8 v0 = *(const f16x8*)&Vt[cur][lc][ch * 32 + lr * 8];
            f16x8 v1 = *(const f16x8*)&Vt[cur][16 + lc][ch * 32 + lr * 8];
            o0 = __builtin_amdgcn_mfma_f32_16x16x32_f16(pf, v0, o0, 0, 0, 0);
            o1 = __builtin_amdgcn_mfma_f32_16x16x32_f16(pf, v1, o1, 0, 0, 0);
        }
        if (more) {
            *(f16x8*)&Ks[cur ^ 1][krow][kcol] = kr;
            *(f16x8*)&Vt[cur ^ 1][vrow][vcol] = vr;
            __syncthreads();
        }
        cur ^= 1;
    }

    lp += __shfl_xor(lp, 16);
    lp += __shfl_xor(lp, 32);

    _Float16* pz = part + (size_t)z * 524288;
#pragma unroll
    for (int i = 0; i < 4; i++) {
        int q = q0 + w * 16 + lr * 4 + i;
        pz[(size_t)q * 128 + h * 32 + lc]      = (_Float16)o0[i];
        pz[(size_t)q * 128 + h * 32 + 16 + lc] = (_Float16)o1[i];
    }
    if (l < 16) mll[((size_t)z * 4 + h) * 4096 + q0 + w * 16 + lc] = lp;
}

// ---------------------------------------------------------------------------
// Wo GEMM + split-attention merge + residual + LayerNorm. 16-row tiles,
// glds B staging; merge-A written with element swizzle.
// ---------------------------------------------------------------------------
__global__ __launch_bounds__(256) void wo_ln_merge(const _Float16* __restrict__ part,
                                                   const float* __restrict__ mll,
                                                   const _Float16* __restrict__ Wh,
                                                   const float* __restrict__ bias,
                                                   float* __restrict__ x,
                                                   _Float16* __restrict__ xh,
                                                   const float* __restrict__ g,
                                                   const float* __restrict__ b)
{
    __shared__ _Float16 Ah[16][128], Bh[128][128];
    __shared__ float Red[16][4][2];
    int tid = threadIdx.x, w = tid >> 6, l = tid & 63, lc = l & 15, lr = l >> 4;
    int m0 = blockIdx.x * 16;

    stageGL<128>(Bh, Wh, 128, 0, 0, tid);
    {   // merge-stage A: 16 rows x 128 cols, 8 cols/thread (granule-aligned)
        int row = tid >> 4, qg = tid & 15;
        int col0 = qg * 8;
        int q = m0 + row, hh = col0 >> 5;
        float lsum = 0.f;
#pragma unroll
        for (int s = 0; s < SPLIT; s++) lsum += mll[((size_t)s * 4 + hh) * 4096 + q];
        float am[8];
#pragma unroll
        for (int e = 0; e < 8; e++) am[e] = 0.f;
#pragma unroll
        for (int s = 0; s < SPLIT; s++) {
            f16x8 t = *(const f16x8*)&part[(size_t)s * 524288 + (size_t)q * 128 + col0];
#pragma unroll
            for (int e = 0; e < 8; e++) am[e] += (float)t[e];
        }
        float inv = 1.f / lsum;
        f16x8 hv;
#pragma unroll
        for (int e = 0; e < 8; e++) hv[e] = (_Float16)(am[e] * inv);
        *(f16x8*)&Ah[row][(qg ^ (row & 15)) << 3] = hv;   // swizzled slot
    }
    __syncthreads();

    f32x4 acc[2];
#pragma unroll
    for (int j = 0; j < 2; j++) acc[j] = {0.f, 0.f, 0.f, 0.f};
#pragma unroll
    for (int ks = 0; ks < 4; ks++) {
        f16x8 af = rdS(Ah, lc, ks * 4 + lr);
#pragma unroll
        for (int j = 0; j < 2; j++) {
            f16x8 bf = rdS(Bh, w * 32 + j * 16 + lc, ks * 4 + lr);
            acc[j] = __builtin_amdgcn_mfma_f32_16x16x32_f16(af, bf, acc[j], 0, 0, 0);
        }
    }

#pragma unroll
    for (int j = 0; j < 2; j++) {
        int n = w * 32 + j * 16 + lc;
        float bb = bias[n];
#pragma unroll
        for (int r = 0; r < 4; r++)
            acc[j][r] += bb + x[(size_t)(m0 + lr * 4 + r) * 128 + n];
    }
#pragma unroll
    for (int r = 0; r < 4; r++) {
        float s1 = acc[0][r] + acc[1][r];
        float s2 = acc[0][r] * acc[0][r] + acc[1][r] * acc[1][r];
#pragma unroll
        for (int off = 1; off < 16; off <<= 1) {
            s1 += __shfl_xor(s1, off);
            s2 += __shfl_xor(s2, off);
        }
        if (lc == 0) { Red[lr * 4 + r][w][0] = s1; Red[lr * 4 + r][w][1] = s2; }
    }
    __syncthreads();
#pragma unroll
    for (int r = 0; r < 4; r++) {
        int rl = lr * 4 + r;
        float S1 = (Red[rl][0][0] + Red[rl][1][0]) + (Red[rl][2][0] + Red[rl][3][0]);
        float S2 = (Red[rl][0][1] + Red[rl][1][1]) + (Red[rl][2][1] + Red[rl][3][1]);
        float mean = S1 * (1.0f / 128.0f);
        float var = S2 * (1.0f / 128.0f) - mean * mean;
        float inv = rsqrtf(var + 1e-5f);
        int m = m0 + rl;
#pragma unroll
        for (int j = 0; j < 2; j++) {
            int n = w * 32 + j * 16 + lc;
            float o = (acc[j][r] - mean) * inv * g[n] + b[n];
            x[(size_t)m * 128 + n] = o;
            xh[(size_t)m * 128 + n] = (_Float16)o;
        }
    }
}

// ---------------------------------------------------------------------------
// Fused W1+W2 pair, 64-row tiles, grid (64, 8) = 512 blocks, glds staging.
// relu(F) written back into Ah with element swizzle.
// ---------------------------------------------------------------------------
__global__ __launch_bounds__(256) void ffn_pair(const _Float16* __restrict__ xh,
                                                const _Float16* __restrict__ W1h,
                                                const float* __restrict__ b1,
                                                const _Float16* __restrict__ W2h,
                                                _Float16* __restrict__ wpart)
{
    __shared__ _Float16 Ah[64][128], Bh[128][128];
    int tid = threadIdx.x, w = tid >> 6, l = tid & 63, lc = l & 15, lr = l >> 4;
    int wr = w >> 1, wc = w & 1;
    int m0 = blockIdx.x * 64, c = blockIdx.y;

    stageGL<64>(Ah, xh, 128, m0, 0, tid);
    stageGL<128>(Bh, W1h, 128, c * 128, 0, tid);
    __syncthreads();

    f32x4 acc[2][4];
#pragma unroll
    for (int i = 0; i < 2; i++)
#pragma unroll
        for (int j = 0; j < 4; j++) acc[i][j] = {0.f, 0.f, 0.f, 0.f};
#pragma unroll
    for (int ks = 0; ks < 4; ks++) {
        f16x8 af0 = rdS(Ah, wr * 32 + lc, ks * 4 + lr);
        f16x8 af1 = rdS(Ah, wr * 32 + 16 + lc, ks * 4 + lr);
#pragma unroll
        for (int j = 0; j < 4; j++) {
            f16x8 bf = rdS(Bh, wc * 64 + j * 16 + lc, ks * 4 + lr);
            acc[0][j] = __builtin_amdgcn_mfma_f32_16x16x32_f16(af0, bf, acc[0][j], 0, 0, 0);
            acc[1][j] = __builtin_amdgcn_mfma_f32_16x16x32_f16(af1, bf, acc[1][j], 0, 0, 0);
        }
    }
    __syncthreads();   // all pass-1 reads of Ah/Bh done

    // relu + bias -> F (into Ah, swizzled element writes)
#pragma unroll
    for (int i = 0; i < 2; i++)
#pragma unroll
        for (int j = 0; j < 4; j++) {
            int n = wc * 64 + j * 16 + lc;
            float bb = b1[c * 128 + n];
#pragma unroll
            for (int r = 0; r < 4; r++)
                wrS(Ah, wr * 32 + i * 16 + lr * 4 + r, n,
                    (_Float16)fmaxf(acc[i][j][r] + bb, 0.f));
        }
    stageGL<128>(Bh, W2h, 1024, 0, c * 128, tid);
    __syncthreads();

    f32x4 oacc[2][4];
#pragma unroll
    for (int i = 0; i < 2; i++)
#pragma unroll
        for (int j = 0; j < 4; j++) oacc[i][j] = {0.f, 0.f, 0.f, 0.f};
#pragma unroll
    for (int ks = 0; ks < 4; ks++) {
        f16x8 af0 = rdS(Ah, wr * 32 + lc, ks * 4 + lr);
        f16x8 af1 = rdS(Ah, wr * 32 + 16 + lc, ks * 4 + lr);
#pragma unroll
        for (int j = 0; j < 4; j++) {
            f16x8 bf = rdS(Bh, wc * 64 + j * 16 + lc, ks * 4 + lr);
            oacc[0][j] = __builtin_amdgcn_mfma_f32_16x16x32_f16(af0, bf, oacc[0][j], 0, 0, 0);
            oacc[1][j] = __builtin_amdgcn_mfma_f32_16x16x32_f16(af1, bf, oacc[1][j], 0, 0, 0);
        }
    }

    _Float16* pz = wpart + (size_t)c * 524288;
#pragma unroll
    for (int i = 0; i < 2; i++) {
        int mb = m0 + wr * 32 + i * 16 + lr * 4;
#pragma unroll
        for (int j = 0; j < 4; j++) {
            int n = wc * 64 + j * 16 + lc;
#pragma unroll
            for (int r = 0; r < 4; r++)
                pz[(size_t)(mb + r) * 128 + n] = (_Float16)oacc[i][j][r];
        }
    }
}

// ---------------------------------------------------------------------------
// reduce 8 fp16 W2 partials + bias + residual + LayerNorm -> x, xh.
// ---------------------------------------------------------------------------
__global__ __launch_bounds__(256) void reduce8_ln(const _Float16* __restrict__ part,
                                                  const float* __restrict__ bias,
                                                  float* __restrict__ x,
                                                  _Float16* __restrict__ xh,
                                                  const float* __restrict__ g,
                                                  const float* __restrict__ b)
{
    int row  = blockIdx.x * 4 + (threadIdx.x >> 6);
    int lane = threadIdx.x & 63;
    size_t base = (size_t)row * 128;
    int c = lane * 2;
    float a0 = 0.f, a1 = 0.f;
#pragma unroll
    for (int s = 0; s < 8; s++) {
        f16x2 p = *(const f16x2*)&part[(size_t)s * 524288 + base + c];
        a0 += (float)p[0]; a1 += (float)p[1];
    }
    float2 bv = *(const float2*)&bias[c];
    float2 xv = *(const float2*)&x[base + c];
    a0 += bv.x + xv.x; a1 += bv.y + xv.y;
    float s = a0 + a1;
#pragma unroll
    for (int off = 32; off; off >>= 1) s += __shfl_xor(s, off);
    float mean = s * (1.0f / 128.0f);
    float d0 = a0 - mean, d1 = a1 - mean;
    float v = d0 * d0 + d1 * d1;
#pragma unroll
    for (int off = 32; off; off >>= 1) v += __shfl_xor(v, off);
    float inv = rsqrtf(v * (1.0f / 128.0f) + 1e-5f);
    float2 gv = *(const float2*)&g[c];
    float2 bb = *(const float2*)&b[c];
    float o0 = d0 * inv * gv.x + bb.x, o1 = d1 * inv * gv.y + bb.y;
    float2 r; r.x = o0; r.y = o1;
    *(float2*)&x[base + c] = r;
    f16x2 rh = {(_Float16)o0, (_Float16)o1};
    *(f16x2*)&xh[base + c] = rh;
}

// ---------------------------------------------------------------------------
// fc1 + relu + fc2 + rownorm fused. 16-row tiles, grid 256, glds staging.
// X2 reuses Ah with swizzled element writes.
// ---------------------------------------------------------------------------
__global__ __launch_bounds__(256) void fc_fused(const _Float16* __restrict__ xh,
                                                const _Float16* __restrict__ W1h,
                                                const float* __restrict__ b1f,
                                                const _Float16* __restrict__ W2h,
                                                const float* __restrict__ b2f,
                                                _Float16* __restrict__ aoh)
{
    __shared__ _Float16 Ah[16][128], Bh[128][128];
    __shared__ float Red[16][4];
    int tid = threadIdx.x, w = tid >> 6, l = tid & 63, lc = l & 15, lr = l >> 4;
    int m0 = blockIdx.x * 16;

    stageGL<16>(Ah, xh, 128, m0, 0, tid);
    stageGL<128>(Bh, W1h, 128, 0, 0, tid);
    __syncthreads();

    f32x4 acc[2];
#pragma unroll
    for (int j = 0; j < 2; j++) acc[j] = {0.f, 0.f, 0.f, 0.f};
#pragma unroll
    for (int ks = 0; ks < 4; ks++) {
        f16x8 af = rdS(Ah, lc, ks * 4 + lr);
#pragma unroll
        for (int j = 0; j < 2; j++) {
            f16x8 bf = rdS(Bh, w * 32 + j * 16 + lc, ks * 4 + lr);
            acc[j] = __builtin_amdgcn_mfma_f32_16x16x32_f16(af, bf, acc[j], 0, 0, 0);
        }
    }
    __syncthreads();   // pass-1 reads done
#pragma unroll
    for (int j = 0; j < 2; j++) {
        int n = w * 32 + j * 16 + lc;
        float bb = b1f[n];
#pragma unroll
        for (int r = 0; r < 4; r++)
            wrS(Ah, lr * 4 + r, n, (_Float16)fmaxf(acc[j][r] + bb, 0.f));
    }
    stageGL<128>(Bh, W2h, 128, 0, 0, tid);
    __syncthreads();

    f32x4 o[2];
#pragma unroll
    for (int j = 0; j < 2; j++) o[j] = {0.f, 0.f, 0.f, 0.f};
#pragma unroll
    for (int ks = 0; ks < 4; ks++) {
        f16x8 af = rdS(Ah, lc, ks * 4 + lr);
#pragma unroll
        for (int j = 0; j < 2; j++) {
            f16x8 bf = rdS(Bh, w * 32 + j * 16 + lc, ks * 4 + lr);
            o[j] = __builtin_amdgcn_mfma_f32_16x16x32_f16(af, bf, o[j], 0, 0, 0);
        }
    }
#pragma unroll
    for (int j = 0; j < 2; j++) {
        float bb = b2f[w * 32 + j * 16 + lc];
#pragma unroll
        for (int r = 0; r < 4; r++) o[j][r] += bb;
    }
#pragma unroll
    for (int r = 0; r < 4; r++) {
        float s2 = o[0][r] * o[0][r] + o[1][r] * o[1][r];
#pragma unroll
        for (int off = 1; off < 16; off <<= 1) s2 += __shfl_xor(s2, off);
        if (lc == 0) Red[lr * 4 + r][w] = s2;
    }
    __syncthreads();
#pragma unroll
    for (int r = 0; r < 4; r++) {
        int rl = lr * 4 + r;
        float inv = rsqrtf((Red[rl][0] + Red[rl][1]) + (Red[rl][2] + Red[rl][3]));
        int m = m0 + rl;
#pragma unroll
        for (int j = 0; j < 2; j++) {
            int n = w * 32 + j * 16 + lc;
            aoh[(size_t)m * 128 + n] = (_Float16)(o[j][r] * inv);
        }
    }
}

// ---------------------------------------------------------------------------
// Gram: C = max(aoh @ aoh^T, 1e-6). 64x128 tiles, glds staging,
// grid (64, 32) = 2048 blocks.
// ---------------------------------------------------------------------------
__global__ __launch_bounds__(256) void gram_f16(const _Float16* __restrict__ aoh,
                                                float* __restrict__ C)
{
    __shared__ _Float16 Ah[64][128], Bh[128][128];
    int tid = threadIdx.x, w = tid >> 6, l = tid & 63, lc = l & 15, lr = l >> 4;
    int wr = w >> 1, wc = w & 1;
    int m0 = blockIdx.x * 64, n0 = blockIdx.y * 128;

    stageGL<64>(Ah, aoh, 128, m0, 0, tid);
    stageGL<128>(Bh, aoh, 128, n0, 0, tid);
    __syncthreads();

    f32x4 acc[2][4];
#pragma unroll
    for (int i = 0; i < 2; i++)
#pragma unroll
        for (int j = 0; j < 4; j++) acc[i][j] = {0.f, 0.f, 0.f, 0.f};
#pragma unroll
    for (int ks = 0; ks < 4; ks++) {
        f16x8 af0 = rdS(Ah, wr * 32 + lc, ks * 4 + lr);
        f16x8 af1 = rdS(Ah, wr * 32 + 16 + lc, ks * 4 + lr);
#pragma unroll
        for (int j = 0; j < 4; j++) {
            f16x8 bf = rdS(Bh, wc * 64 + j * 16 + lc, ks * 4 + lr);
            acc[0][j] = __builtin_amdgcn_mfma_f32_16x16x32_f16(af0, bf, acc[0][j], 0, 0, 0);
            acc[1][j] = __builtin_amdgcn_mfma_f32_16x16x32_f16(af1, bf, acc[1][j], 0, 0, 0);
        }
    }

#pragma unroll
    for (int i = 0; i < 2; i++) {
        int mb = m0 + wr * 32 + i * 16 + lr * 4;
#pragma unroll
        for (int j = 0; j < 4; j++) {
            int n = n0 + wc * 64 + j * 16 + lc;
#pragma unroll
            for (int r = 0; r < 4; r++)
                C[(size_t)(mb + r) * 4096 + n] = fmaxf(acc[i][j][r], 1e-6f);
        }
    }
}

// ---------------------------------------------------------------------------
extern "C" void kernel_launch(void* const* d_in, const int* in_sizes, int n_in,
                              void* d_out, int out_size, void* d_ws, size_t ws_size,
                              hipStream_t stream)
{
    const float* src  = (const float*)d_in[0];
    const float* Wqkv = (const float*)d_in[1];
    const float* bqkv = (const float*)d_in[2];
    const float* Wo   = (const float*)d_in[3];
    const float* bo   = (const float*)d_in[4];
    const float* ln1g = (const float*)d_in[5];
    const float* ln1b = (const float*)d_in[6];
    const float* W1   = (const float*)d_in[7];
    const float* b1   = (const float*)d_in[8];
    const float* W2   = (const float*)d_in[9];
    const float* b2   = (const float*)d_in[10];
    const float* ln2g = (const float*)d_in[11];
    const float* ln2b = (const float*)d_in[12];
    const float* fc1W = (const float*)d_in[13];
    const float* fc1b = (const float*)d_in[14];
    const float* fc2W = (const float*)d_in[15];
    const float* fc2b = (const float*)d_in[16];

    float* ws = (float*)d_ws;
    float*    x   = ws;                                   // 524288 f32
    _Float16* xh  = (_Float16*)(ws + 524288);             // 524288 f16
    _Float16* aoh = (_Float16*)(ws + 786432);             // 524288 f16
    _Float16* qh  = (_Float16*)(ws + 1048576);            // 524288 f16
    _Float16* kh  = (_Float16*)(ws + 1310720);            // 524288 f16
    _Float16* vt  = (_Float16*)(ws + 1572864);            // 524288 f16
    float*    mll = ws + 1835008;                         // 131072 f32

    // d_out scratch (all dead before gram writes):
    _Float16* wpart = (_Float16*)d_out + 4194304;         // bytes [ 8MiB,16MiB)
    _Float16* apart = (_Float16*)d_out + 12582912;        // bytes [24MiB,32MiB)
    _Float16* wh    = (_Float16*)d_out + 16777216;        // bytes [32MiB,~34MiB)
    float*    out   = (float*)d_out;

    _Float16* qkvh = wh;                  // 3 x 384 x 128
    _Float16* woh  = wh + 147456;         // 3 x 128 x 128
    _Float16* w1h  = wh + 196608;         // 3 x 1024 x 128
    _Float16* w2h  = wh + 589824;         // 3 x 128 x 1024
    _Float16* fc1h = wh + 983040;         // 128 x 128
    _Float16* fc2h = wh + 999424;         // 128 x 128

    setup_cvt<<<1504, 256, 0, stream>>>(Wqkv, Wo, W1, W2, fc1W, fc2W, wh,
                                        src, x, xh);
    for (int l = 0; l < 3; l++) {
        gemm_qkv<<<dim3(256, 3), 256, 0, stream>>>(xh, qkvh + l * 49152,
                                                   bqkv + l * 384, qh, kh, vt);
        attn_mfma<<<dim3(64, 4, SPLIT), 256, 0, stream>>>(qh, kh, vt, apart, mll);
        wo_ln_merge<<<256, 256, 0, stream>>>(apart, mll, woh + l * 16384, bo + l * 128,
                                             x, xh, ln1g + l * 128, ln1b + l * 128);
        ffn_pair<<<dim3(64, 8), 256, 0, stream>>>(xh, w1h + l * 131072, b1 + l * 1024,
                                                  w2h + l * 131072, wpart);
        reduce8_ln<<<1024, 256, 0, stream>>>(wpart, b2 + l * 128, x, xh,
                                             ln2g + l * 128, ln2b + l * 128);
    }
    fc_fused<<<256, 256, 0, stream>>>(xh, fc1h, fc1b, fc2h, fc2b, aoh);
    gram_f16<<<dim3(64, 32), 256, 0, stream>>>(aoh, out);
}

// Round 7
// 260.937 us; speedup vs baseline: 1.0535x; 1.0118x over previous
//
#include <hip/hip_runtime.h>
#include <math.h>

#define S 4096
#define QK_SCALE 0.17677669529663687f  // 1/sqrt(32)
#define LOG2E    1.44269504088896f
#define SPLIT 8
#define KS (S / SPLIT)                 // 512 keys per split

typedef _Float16 f16x8 __attribute__((ext_vector_type(8)));
typedef _Float16 f16x4 __attribute__((ext_vector_type(4)));
typedef _Float16 f16x2 __attribute__((ext_vector_type(2)));
typedef float f32x4 __attribute__((ext_vector_type(4)));

// ---------------------------------------------------------------------------
// MFMA lane map (HW-verified R4): A-frag m=l&15, k=(l>>4)*8+j; B-frag n=l&15;
// C reg r: row=(l>>4)*4+r, col=l&15.
// R16: base = R6 (264us ~ R2). ONE mechanism: kill reduce8_ln (3 dispatches)
// by fusing {8-partial merge + b2 + residual + LN2} into the A-stage of the
// next consumer (gemm_qkv_merge for layers 1,2; fc_fused for layer 2).
// Residual ping-pong: x0 = post-LN2 chain (qkv_merge by==0 writes),
// x1 = post-LN1 chain (wo_ln writes; ffn/qkv_merge read). 15 dispatches.
// Staging: global_load_lds 16B direct-to-LDS, source-granule XOR swizzle
// (g ^= row&15) + same XOR on reads (both-sides involution, 2 lanes/bank).
// ---------------------------------------------------------------------------

// direct-to-LDS stage of ROWS x 128 f16 tile, linear [128] stride, source
// granule-swizzled so a swizzled read recovers logical layout.
template<int ROWS>
__device__ __forceinline__ void stageGL(_Float16 (*dst)[128], const _Float16* src,
                                        int ld, int row0, int col0, int tid) {
    int w = tid >> 6, l = tid & 63;
    constexpr int NISS = ROWS / 16;         // wave-issues per wave (4 waves)
#pragma unroll
    for (int v = 0; v < NISS; v++) {
        int G = (w * NISS + v) * 64 + l;    // linear granule id
        int row = G >> 4, g = G & 15;
        int gs = g ^ (row & 15);            // swizzled source granule
        const void* gp = src + (size_t)(row0 + row) * ld + col0 + gs * 8;
        void* lp = (char*)&dst[0][0] + (size_t)G * 16;
        __builtin_amdgcn_global_load_lds(
            (const __attribute__((address_space(1))) void*)gp,
            (__attribute__((address_space(3))) void*)lp, 16, 0, 0);
    }
}

// swizzled 16B fragment read: logical granule qg of row
__device__ __forceinline__ f16x8 rdS(const _Float16 (*B)[128], int row, int qg) {
    return *(const f16x8*)&B[row][(qg ^ (row & 15)) << 3];
}
// swizzled element write (for register-computed tiles)
__device__ __forceinline__ void wrS(_Float16 (*B)[128], int row, int col, _Float16 v) {
    B[row][((((col >> 3) ^ (row & 15))) << 3) | (col & 7)] = v;
}

// ---------------------------------------------------------------------------
// setup: weight fp32->fp16 conversion (blocks 0..991) + x/xh copy (992..1503).
// ---------------------------------------------------------------------------
__global__ __launch_bounds__(256) void setup_cvt(const float* __restrict__ q,
                                                 const float* __restrict__ wo,
                                                 const float* __restrict__ w1,
                                                 const float* __restrict__ w2,
                                                 const float* __restrict__ f1,
                                                 const float* __restrict__ f2,
                                                 _Float16* __restrict__ dst,
                                                 const float* __restrict__ a,
                                                 float* __restrict__ x,
                                                 _Float16* __restrict__ xh)
{
    int bb = blockIdx.x;
    if (bb < 992) {
        const float* src; size_t dof; int lb;
        if (bb < 144)      { src = q;  dof = 0;      lb = bb; }
        else if (bb < 192) { src = wo; dof = 147456; lb = bb - 144; }
        else if (bb < 576) { src = w1; dof = 196608; lb = bb - 192; }
        else if (bb < 960) { src = w2; dof = 589824; lb = bb - 576; }
        else if (bb < 976) { src = f1; dof = 983040; lb = bb - 960; }
        else               { src = f2; dof = 999424; lb = bb - 976; }
        int i = lb * 1024 + threadIdx.x * 4;
        float4 v = *(const float4*)(src + i);
        f16x4 h = {(_Float16)v.x, (_Float16)v.y, (_Float16)v.z, (_Float16)v.w};
        *(f16x4*)(dst + dof + i) = h;
    } else {
        int i = (bb - 992) * 256 + threadIdx.x;
        float4 v = ((const float4*)a)[i];
        ((float4*)x)[i] = v;
        f16x4 h = {(_Float16)v.x, (_Float16)v.y, (_Float16)v.z, (_Float16)v.w};
        ((f16x4*)xh)[i] = h;
    }
}

// ---------------------------------------------------------------------------
// QKV GEMM (layer 0), 16-row tiles, full-K single barrier, glds staging.
// grid (256, 3): by=0 -> qh (scaled), by=1 -> kh, by=2 -> vt (transposed).
// ---------------------------------------------------------------------------
__global__ __launch_bounds__(256) void gemm_qkv(const _Float16* __restrict__ xh,
                                                const _Float16* __restrict__ Wh,
                                                const float* __restrict__ bias,
                                                _Float16* __restrict__ qh,
                                                _Float16* __restrict__ kh,
                                                _Float16* __restrict__ vt)
{
    __shared__ _Float16 Ah[16][128], Bh[128][128];
    int tid = threadIdx.x, w = tid >> 6, l = tid & 63, lc = l & 15, lr = l >> 4;
    int m0 = blockIdx.x * 16, by = blockIdx.y;

    stageGL<16>(Ah, xh, 128, m0, 0, tid);
    stageGL<128>(Bh, Wh, 128, by * 128, 0, tid);
    __syncthreads();

    f32x4 acc[2];
#pragma unroll
    for (int j = 0; j < 2; j++) acc[j] = {0.f, 0.f, 0.f, 0.f};
#pragma unroll
    for (int ks = 0; ks < 4; ks++) {
        f16x8 af = rdS(Ah, lc, ks * 4 + lr);
#pragma unroll
        for (int j = 0; j < 2; j++) {
            f16x8 bf = rdS(Bh, w * 32 + j * 16 + lc, ks * 4 + lr);
            acc[j] = __builtin_amdgcn_mfma_f32_16x16x32_f16(af, bf, acc[j], 0, 0, 0);
        }
    }

    int mb = m0 + lr * 4;
#pragma unroll
    for (int j = 0; j < 2; j++) {
        int n = w * 32 + j * 16 + lc;
        float bb = bias[by * 128 + n];
        if (by == 0) {
#pragma unroll
            for (int r = 0; r < 4; r++)
                qh[(size_t)(mb + r) * 128 + n] =
                    (_Float16)((acc[j][r] + bb) * (QK_SCALE * LOG2E));
        } else if (by == 1) {
            int hh = n >> 5, d = n & 31;
#pragma unroll
            for (int r = 0; r < 4; r++)
                kh[((size_t)hh * S + mb + r) * 32 + d] = (_Float16)(acc[j][r] + bb);
        } else {
            f16x4 pk;
#pragma unroll
            for (int r = 0; r < 4; r++) pk[r] = (_Float16)(acc[j][r] + bb);
            *(f16x4*)&vt[(size_t)n * S + mb] = pk;
        }
    }
}

// ---------------------------------------------------------------------------
// QKV GEMM with fused FFN-merge + LN2 A-stage (layers 1,2). A-tile built from
// 8 W2 partials + b2 + residual(x1, post-LN1) -> LN2 -> Ah. by==0 writes the
// fp32 post-LN2 to x0 (residual for this layer's wo_ln_merge).
// ---------------------------------------------------------------------------
__global__ __launch_bounds__(256) void gemm_qkv_merge(
    const _Float16* __restrict__ wpart, const float* __restrict__ x1,
    const float* __restrict__ b2, const float* __restrict__ g2,
    const float* __restrict__ bn2, float* __restrict__ x0,
    const _Float16* __restrict__ Wh, const float* __restrict__ bias,
    _Float16* __restrict__ qh, _Float16* __restrict__ kh,
    _Float16* __restrict__ vt)
{
    __shared__ _Float16 Ah[16][128], Bh[128][128];
    int tid = threadIdx.x, w = tid >> 6, l = tid & 63, lc = l & 15, lr = l >> 4;
    int m0 = blockIdx.x * 16, by = blockIdx.y;

    stageGL<128>(Bh, Wh, 128, by * 128, 0, tid);   // B in flight during merge
    {   // merge 8 W2-partials + b2 + residual + LN2 -> Ah (16 x 128)
        int row = tid >> 4, qg = tid & 15, col0 = qg * 8;
        int q = m0 + row;
        float am[8];
#pragma unroll
        for (int e = 0; e < 8; e++) am[e] = 0.f;
#pragma unroll
        for (int s = 0; s < 8; s++) {
            f16x8 t = *(const f16x8*)&wpart[(size_t)s * 524288 + (size_t)q * 128 + col0];
#pragma unroll
            for (int e = 0; e < 8; e++) am[e] += (float)t[e];
        }
#pragma unroll
        for (int e = 0; e < 8; e++)
            am[e] += b2[col0 + e] + x1[(size_t)q * 128 + col0 + e];
        float s1 = 0.f, s2 = 0.f;
#pragma unroll
        for (int e = 0; e < 8; e++) { s1 += am[e]; s2 += am[e] * am[e]; }
#pragma unroll
        for (int off = 1; off < 16; off <<= 1) {   // row = aligned 16-lane group
            s1 += __shfl_xor(s1, off);
            s2 += __shfl_xor(s2, off);
        }
        float mean = s1 * (1.0f / 128.0f);
        float var = s2 * (1.0f / 128.0f) - mean * mean;
        float inv = rsqrtf(var + 1e-5f);
        float o[8];
        f16x8 hv;
#pragma unroll
        for (int e = 0; e < 8; e++) {
            o[e] = (am[e] - mean) * inv * g2[col0 + e] + bn2[col0 + e];
            hv[e] = (_Float16)o[e];
        }
        *(f16x8*)&Ah[row][(qg ^ (row & 15)) << 3] = hv;
        if (by == 0) {
            float4 v0 = {o[0], o[1], o[2], o[3]};
            float4 v1 = {o[4], o[5], o[6], o[7]};
            *(float4*)&x0[(size_t)q * 128 + col0]     = v0;
            *(float4*)&x0[(size_t)q * 128 + col0 + 4] = v1;
        }
    }
    __syncthreads();

    f32x4 acc[2];
#pragma unroll
    for (int j = 0; j < 2; j++) acc[j] = {0.f, 0.f, 0.f, 0.f};
#pragma unroll
    for (int ks = 0; ks < 4; ks++) {
        f16x8 af = rdS(Ah, lc, ks * 4 + lr);
#pragma unroll
        for (int j = 0; j < 2; j++) {
            f16x8 bf = rdS(Bh, w * 32 + j * 16 + lc, ks * 4 + lr);
            acc[j] = __builtin_amdgcn_mfma_f32_16x16x32_f16(af, bf, acc[j], 0, 0, 0);
        }
    }

    int mb = m0 + lr * 4;
#pragma unroll
    for (int j = 0; j < 2; j++) {
        int n = w * 32 + j * 16 + lc;
        float bb = bias[by * 128 + n];
        if (by == 0) {
#pragma unroll
            for (int r = 0; r < 4; r++)
                qh[(size_t)(mb + r) * 128 + n] =
                    (_Float16)((acc[j][r] + bb) * (QK_SCALE * LOG2E));
        } else if (by == 1) {
            int hh = n >> 5, d = n & 31;
#pragma unroll
            for (int r = 0; r < 4; r++)
                kh[((size_t)hh * S + mb + r) * 32 + d] = (_Float16)(acc[j][r] + bb);
        } else {
            f16x4 pk;
#pragma unroll
            for (int r = 0; r < 4; r++) pk[r] = (_Float16)(acc[j][r] + bb);
            *(f16x4*)&vt[(size_t)n * S + mb] = pk;
        }
    }
}

// ---------------------------------------------------------------------------
// MFMA flash attention (R2 version, untouched): K/V double-buffer,
// async-split staging, one barrier/tile; swapped QK^T, packed Ps.
// ---------------------------------------------------------------------------
__global__ __launch_bounds__(256) void attn_mfma(const _Float16* __restrict__ qh,
                                                 const _Float16* __restrict__ kh,
                                                 const _Float16* __restrict__ vt,
                                                 _Float16* __restrict__ part,
                                                 float* __restrict__ mll)
{
    __shared__ _Float16 Ks[2][64][32];
    __shared__ _Float16 Vt[2][32][72];
    __shared__ _Float16 Ps[4][16][72];
    int h = blockIdx.y, q0 = blockIdx.x * 64, z = blockIdx.z;
    int tid = threadIdx.x;
    int w = tid >> 6, l = tid & 63;
    int lc = l & 15, lr = l >> 4;

    f16x8 qf = *(const f16x8*)&qh[(size_t)(q0 + w * 16 + lc) * 128 + h * 32 + lr * 8];

    const _Float16* khh = kh + (size_t)h * S * 32;
    const _Float16* vth = vt + (size_t)h * 32 * S;

    int krow = tid >> 2, kcol = (tid & 3) * 8;
    int vrow = tid >> 3, vcol = (tid & 7) * 8;

    f32x4 o0 = {0.f, 0.f, 0.f, 0.f}, o1 = {0.f, 0.f, 0.f, 0.f};
    float lp = 0.f;

    int k0 = z * KS;
    {   // prologue: stage tile 0
        f16x8 kr = *(const f16x8*)&khh[(size_t)(k0 + krow) * 32 + kcol];
        f16x8 vr = *(const f16x8*)&vth[(size_t)vrow * S + k0 + vcol];
        *(f16x8*)&Ks[0][krow][kcol] = kr;
        *(f16x8*)&Vt[0][vrow][vcol] = vr;
    }
    __syncthreads();

    int cur = 0;
#pragma unroll 1
    for (int t8 = 0; t8 < KS / 64; t8++) {
        bool more = (t8 + 1 < KS / 64);
        f16x8 kr, vr;
        if (more) {   // issue next tile's loads early; latency hides under compute
            int kn = k0 + (t8 + 1) * 64;
            kr = *(const f16x8*)&khh[(size_t)(kn + krow) * 32 + kcol];
            vr = *(const f16x8*)&vth[(size_t)vrow * S + kn + vcol];
        }

        f32x4 st[4];
#pragma unroll
        for (int t = 0; t < 4; t++) {
            f16x8 kf = *(const f16x8*)&Ks[cur][t * 16 + lc][lr * 8];
            f32x4 zz = {0.f, 0.f, 0.f, 0.f};
            st[t] = __builtin_amdgcn_mfma_f32_16x16x32_f16(kf, qf, zz, 0, 0, 0);
        }
#pragma unroll
        for (int t = 0; t < 4; t++) {
            float p0 = exp2f(st[t][0]), p1 = exp2f(st[t][1]);
            float p2 = exp2f(st[t][2]), p3 = exp2f(st[t][3]);
            lp += (p0 + p1) + (p2 + p3);
            f16x2 h0 = {(_Float16)p0, (_Float16)p1};
            f16x2 h1 = {(_Float16)p2, (_Float16)p3};
            *(f16x2*)&Ps[w][lc][t * 16 + lr * 4]     = h0;
            *(f16x2*)&Ps[w][lc][t * 16 + lr * 4 + 2] = h1;
        }
        asm volatile("s_waitcnt lgkmcnt(0)" ::: "memory");
#pragma unroll
        for (int ch = 0; ch < 2; ch++) {
            f16x8 pf = *(const f16x8*)&Ps[w][lc][ch * 32 + lr * 8];
            f16x8 v0 = *(const f16x8*)&Vt[cur][lc][ch * 32 + lr * 8];
            f16x8 v1 = *(const f16x8*)&Vt[cur][16 + lc][ch * 32 + lr * 8];
            o0 = __builtin_amdgcn_mfma_f32_16x16x32_f16(pf, v0, o0, 0, 0, 0);
            o1 = __builtin_amdgcn_mfma_f32_16x16x32_f16(pf, v1, o1, 0, 0, 0);
        }
        if (more) {
            *(f16x8*)&Ks[cur ^ 1][krow][kcol] = kr;
            *(f16x8*)&Vt[cur ^ 1][vrow][vcol] = vr;
            __syncthreads();
        }
        cur ^= 1;
    }

    lp += __shfl_xor(lp, 16);
    lp += __shfl_xor(lp, 32);

    _Float16* pz = part + (size_t)z * 524288;
#pragma unroll
    for (int i = 0; i < 4; i++) {
        int q = q0 + w * 16 + lr * 4 + i;
        pz[(size_t)q * 128 + h * 32 + lc]      = (_Float16)o0[i];
        pz[(size_t)q * 128 + h * 32 + 16 + lc] = (_Float16)o1[i];
    }
    if (l < 16) mll[((size_t)z * 4 + h) * 4096 + q0 + w * 16 + lc] = lp;
}

// ---------------------------------------------------------------------------
// Wo GEMM + split-attention merge + residual(x0) + LN1 -> x1 (fp32), xh (f16).
// 16-row tiles, glds B staging; merge-A written with element swizzle.
// ---------------------------------------------------------------------------
__global__ __launch_bounds__(256) void wo_ln_merge(const _Float16* __restrict__ part,
                                                   const float* __restrict__ mll,
                                                   const _Float16* __restrict__ Wh,
                                                   const float* __restrict__ bias,
                                                   const float* __restrict__ xres,
                                                   float* __restrict__ xo,
                                                   _Float16* __restrict__ xh,
                                                   const float* __restrict__ g,
                                                   const float* __restrict__ b)
{
    __shared__ _Float16 Ah[16][128], Bh[128][128];
    __shared__ float Red[16][4][2];
    int tid = threadIdx.x, w = tid >> 6, l = tid & 63, lc = l & 15, lr = l >> 4;
    int m0 = blockIdx.x * 16;

    stageGL<128>(Bh, Wh, 128, 0, 0, tid);
    {   // merge-stage A: 16 rows x 128 cols, 8 cols/thread (granule-aligned)
        int row = tid >> 4, qg = tid & 15;
        int col0 = qg * 8;
        int q = m0 + row, hh = col0 >> 5;
        float lsum = 0.f;
#pragma unroll
        for (int s = 0; s < SPLIT; s++) lsum += mll[((size_t)s * 4 + hh) * 4096 + q];
        float am[8];
#pragma unroll
        for (int e = 0; e < 8; e++) am[e] = 0.f;
#pragma unroll
        for (int s = 0; s < SPLIT; s++) {
            f16x8 t = *(const f16x8*)&part[(size_t)s * 524288 + (size_t)q * 128 + col0];
#pragma unroll
            for (int e = 0; e < 8; e++) am[e] += (float)t[e];
        }
        float inv = 1.f / lsum;
        f16x8 hv;
#pragma unroll
        for (int e = 0; e < 8; e++) hv[e] = (_Float16)(am[e] * inv);
        *(f16x8*)&Ah[row][(qg ^ (row & 15)) << 3] = hv;   // swizzled slot
    }
    __syncthreads();

    f32x4 acc[2];
#pragma unroll
    for (int j = 0; j < 2; j++) acc[j] = {0.f, 0.f, 0.f, 0.f};
#pragma unroll
    for (int ks = 0; ks < 4; ks++) {
        f16x8 af = rdS(Ah, lc, ks * 4 + lr);
#pragma unroll
        for (int j = 0; j < 2; j++) {
            f16x8 bf = rdS(Bh, w * 32 + j * 16 + lc, ks * 4 + lr);
            acc[j] = __builtin_amdgcn_mfma_f32_16x16x32_f16(af, bf, acc[j], 0, 0, 0);
        }
    }

#pragma unroll
    for (int j = 0; j < 2; j++) {
        int n = w * 32 + j * 16 + lc;
        float bb = bias[n];
#pragma unroll
        for (int r = 0; r < 4; r++)
            acc[j][r] += bb + xres[(size_t)(m0 + lr * 4 + r) * 128 + n];
    }
#pragma unroll
    for (int r = 0; r < 4; r++) {
        float s1 = acc[0][r] + acc[1][r];
        float s2 = acc[0][r] * acc[0][r] + acc[1][r] * acc[1][r];
#pragma unroll
        for (int off = 1; off < 16; off <<= 1) {
            s1 += __shfl_xor(s1, off);
            s2 += __shfl_xor(s2, off);
        }
        if (lc == 0) { Red[lr * 4 + r][w][0] = s1; Red[lr * 4 + r][w][1] = s2; }
    }
    __syncthreads();
#pragma unroll
    for (int r = 0; r < 4; r++) {
        int rl = lr * 4 + r;
        float S1 = (Red[rl][0][0] + Red[rl][1][0]) + (Red[rl][2][0] + Red[rl][3][0]);
        float S2 = (Red[rl][0][1] + Red[rl][1][1]) + (Red[rl][2][1] + Red[rl][3][1]);
        float mean = S1 * (1.0f / 128.0f);
        float var = S2 * (1.0f / 128.0f) - mean * mean;
        float inv = rsqrtf(var + 1e-5f);
        int m = m0 + rl;
#pragma unroll
        for (int j = 0; j < 2; j++) {
            int n = w * 32 + j * 16 + lc;
            float o = (acc[j][r] - mean) * inv * g[n] + b[n];
            xo[(size_t)m * 128 + n] = o;
            xh[(size_t)m * 128 + n] = (_Float16)o;
        }
    }
}

// ---------------------------------------------------------------------------
// Fused W1+W2 pair, 64-row tiles, grid (64, 8) = 512 blocks, glds staging.
// relu(F) written back into Ah with element swizzle.
// ---------------------------------------------------------------------------
__global__ __launch_bounds__(256) void ffn_pair(const _Float16* __restrict__ xh,
                                                const _Float16* __restrict__ W1h,
                                                const float* __restrict__ b1,
                                                const _Float16* __restrict__ W2h,
                                                _Float16* __restrict__ wpart)
{
    __shared__ _Float16 Ah[64][128], Bh[128][128];
    int tid = threadIdx.x, w = tid >> 6, l = tid & 63, lc = l & 15, lr = l >> 4;
    int wr = w >> 1, wc = w & 1;
    int m0 = blockIdx.x * 64, c = blockIdx.y;

    stageGL<64>(Ah, xh, 128, m0, 0, tid);
    stageGL<128>(Bh, W1h, 128, c * 128, 0, tid);
    __syncthreads();

    f32x4 acc[2][4];
#pragma unroll
    for (int i = 0; i < 2; i++)
#pragma unroll
        for (int j = 0; j < 4; j++) acc[i][j] = {0.f, 0.f, 0.f, 0.f};
#pragma unroll
    for (int ks = 0; ks < 4; ks++) {
        f16x8 af0 = rdS(Ah, wr * 32 + lc, ks * 4 + lr);
        f16x8 af1 = rdS(Ah, wr * 32 + 16 + lc, ks * 4 + lr);
#pragma unroll
        for (int j = 0; j < 4; j++) {
            f16x8 bf = rdS(Bh, wc * 64 + j * 16 + lc, ks * 4 + lr);
            acc[0][j] = __builtin_amdgcn_mfma_f32_16x16x32_f16(af0, bf, acc[0][j], 0, 0, 0);
            acc[1][j] = __builtin_amdgcn_mfma_f32_16x16x32_f16(af1, bf, acc[1][j], 0, 0, 0);
        }
    }
    __syncthreads();   // all pass-1 reads of Ah/Bh done

    // relu + bias -> F (into Ah, swizzled element writes)
#pragma unroll
    for (int i = 0; i < 2; i++)
#pragma unroll
        for (int j = 0; j < 4; j++) {
            int n = wc * 64 + j * 16 + lc;
            float bb = b1[c * 128 + n];
#pragma unroll
            for (int r = 0; r < 4; r++)
                wrS(Ah, wr * 32 + i * 16 + lr * 4 + r, n,
                    (_Float16)fmaxf(acc[i][j][r] + bb, 0.f));
        }
    stageGL<128>(Bh, W2h, 1024, 0, c * 128, tid);
    __syncthreads();

    f32x4 oacc[2][4];
#pragma unroll
    for (int i = 0; i < 2; i++)
#pragma unroll
        for (int j = 0; j < 4; j++) oacc[i][j] = {0.f, 0.f, 0.f, 0.f};
#pragma unroll
    for (int ks = 0; ks < 4; ks++) {
        f16x8 af0 = rdS(Ah, wr * 32 + lc, ks * 4 + lr);
        f16x8 af1 = rdS(Ah, wr * 32 + 16 + lc, ks * 4 + lr);
#pragma unroll
        for (int j = 0; j < 4; j++) {
            f16x8 bf = rdS(Bh, wc * 64 + j * 16 + lc, ks * 4 + lr);
            oacc[0][j] = __builtin_amdgcn_mfma_f32_16x16x32_f16(af0, bf, oacc[0][j], 0, 0, 0);
            oacc[1][j] = __builtin_amdgcn_mfma_f32_16x16x32_f16(af1, bf, oacc[1][j], 0, 0, 0);
        }
    }

    _Float16* pz = wpart + (size_t)c * 524288;
#pragma unroll
    for (int i = 0; i < 2; i++) {
        int mb = m0 + wr * 32 + i * 16 + lr * 4;
#pragma unroll
        for (int j = 0; j < 4; j++) {
            int n = wc * 64 + j * 16 + lc;
#pragma unroll
            for (int r = 0; r < 4; r++)
                pz[(size_t)(mb + r) * 128 + n] = (_Float16)oacc[i][j][r];
        }
    }
}

// ---------------------------------------------------------------------------
// fc1 + relu + fc2 + rownorm fused, with fused FFN-merge + LN2 A-stage
// (layer 2). 16-row tiles, grid 256, glds staging for weights.
// ---------------------------------------------------------------------------
__global__ __launch_bounds__(256) void fc_fused(const _Float16* __restrict__ wpart,
                                                const float* __restrict__ x1,
                                                const float* __restrict__ b2l,
                                                const float* __restrict__ g2,
                                                const float* __restrict__ bn2,
                                                const _Float16* __restrict__ W1h,
                                                const float* __restrict__ b1f,
                                                const _Float16* __restrict__ W2h,
                                                const float* __restrict__ b2f,
                                                _Float16* __restrict__ aoh)
{
    __shared__ _Float16 Ah[16][128], Bh[128][128];
    __shared__ float Red[16][4];
    int tid = threadIdx.x, w = tid >> 6, l = tid & 63, lc = l & 15, lr = l >> 4;
    int m0 = blockIdx.x * 16;

    stageGL<128>(Bh, W1h, 128, 0, 0, tid);
    {   // merge 8 W2-partials + b2 + residual + LN2 -> Ah
        int row = tid >> 4, qg = tid & 15, col0 = qg * 8;
        int q = m0 + row;
        float am[8];
#pragma unroll
        for (int e = 0; e < 8; e++) am[e] = 0.f;
#pragma unroll
        for (int s = 0; s < 8; s++) {
            f16x8 t = *(const f16x8*)&wpart[(size_t)s * 524288 + (size_t)q * 128 + col0];
#pragma unroll
            for (int e = 0; e < 8; e++) am[e] += (float)t[e];
        }
#pragma unroll
        for (int e = 0; e < 8; e++)
            am[e] += b2l[col0 + e] + x1[(size_t)q * 128 + col0 + e];
        float s1 = 0.f, s2 = 0.f;
#pragma unroll
        for (int e = 0; e < 8; e++) { s1 += am[e]; s2 += am[e] * am[e]; }
#pragma unroll
        for (int off = 1; off < 16; off <<= 1) {
            s1 += __shfl_xor(s1, off);
            s2 += __shfl_xor(s2, off);
        }
        float mean = s1 * (1.0f / 128.0f);
        float var = s2 * (1.0f / 128.0f) - mean * mean;
        float inv = rsqrtf(var + 1e-5f);
        f16x8 hv;
#pragma unroll
        for (int e = 0; e < 8; e++)
            hv[e] = (_Float16)((am[e] - mean) * inv * g2[col0 + e] + bn2[col0 + e]);
        *(f16x8*)&Ah[row][(qg ^ (row & 15)) << 3] = hv;
    }
    __syncthreads();

    f32x4 acc[2];
#pragma unroll
    for (int j = 0; j < 2; j++) acc[j] = {0.f, 0.f, 0.f, 0.f};
#pragma unroll
    for (int ks = 0; ks < 4; ks++) {
        f16x8 af = rdS(Ah, lc, ks * 4 + lr);
#pragma unroll
        for (int j = 0; j < 2; j++) {
            f16x8 bf = rdS(Bh, w * 32 + j * 16 + lc, ks * 4 + lr);
            acc[j] = __builtin_amdgcn_mfma_f32_16x16x32_f16(af, bf, acc[j], 0, 0, 0);
        }
    }
    __syncthreads();   // pass-1 reads done
#pragma unroll
    for (int j = 0; j < 2; j++) {
        int n = w * 32 + j * 16 + lc;
        float bb = b1f[n];
#pragma unroll
        for (int r = 0; r < 4; r++)
            wrS(Ah, lr * 4 + r, n, (_Float16)fmaxf(acc[j][r] + bb, 0.f));
    }
    stageGL<128>(Bh, W2h, 128, 0, 0, tid);
    __syncthreads();

    f32x4 o[2];
#pragma unroll
    for (int j = 0; j < 2; j++) o[j] = {0.f, 0.f, 0.f, 0.f};
#pragma unroll
    for (int ks = 0; ks < 4; ks++) {
        f16x8 af = rdS(Ah, lc, ks * 4 + lr);
#pragma unroll
        for (int j = 0; j < 2; j++) {
            f16x8 bf = rdS(Bh, w * 32 + j * 16 + lc, ks * 4 + lr);
            o[j] = __builtin_amdgcn_mfma_f32_16x16x32_f16(af, bf, o[j], 0, 0, 0);
        }
    }
#pragma unroll
    for (int j = 0; j < 2; j++) {
        float bb = b2f[w * 32 + j * 16 + lc];
#pragma unroll
        for (int r = 0; r < 4; r++) o[j][r] += bb;
    }
#pragma unroll
    for (int r = 0; r < 4; r++) {
        float s2 = o[0][r] * o[0][r] + o[1][r] * o[1][r];
#pragma unroll
        for (int off = 1; off < 16; off <<= 1) s2 += __shfl_xor(s2, off);
        if (lc == 0) Red[lr * 4 + r][w] = s2;
    }
    __syncthreads();
#pragma unroll
    for (int r = 0; r < 4; r++) {
        int rl = lr * 4 + r;
        float inv = rsqrtf((Red[rl][0] + Red[rl][1]) + (Red[rl][2] + Red[rl][3]));
        int m = m0 + rl;
#pragma unroll
        for (int j = 0; j < 2; j++) {
            int n = w * 32 + j * 16 + lc;
            aoh[(size_t)m * 128 + n] = (_Float16)(o[j][r] * inv);
        }
    }
}

// ---------------------------------------------------------------------------
// Gram: C = max(aoh @ aoh^T, 1e-6). 64x128 tiles, glds staging,
// grid (64, 32) = 2048 blocks.
// ---------------------------------------------------------------------------
__global__ __launch_bounds__(256) void gram_f16(const _Float16* __restrict__ aoh,
                                                float* __restrict__ C)
{
    __shared__ _Float16 Ah[64][128], Bh[128][128];
    int tid = threadIdx.x, w = tid >> 6, l = tid & 63, lc = l & 15, lr = l >> 4;
    int wr = w >> 1, wc = w & 1;
    int m0 = blockIdx.x * 64, n0 = blockIdx.y * 128;

    stageGL<64>(Ah, aoh, 128, m0, 0, tid);
    stageGL<128>(Bh, aoh, 128, n0, 0, tid);
    __syncthreads();

    f32x4 acc[2][4];
#pragma unroll
    for (int i = 0; i < 2; i++)
#pragma unroll
        for (int j = 0; j < 4; j++) acc[i][j] = {0.f, 0.f, 0.f, 0.f};
#pragma unroll
    for (int ks = 0; ks < 4; ks++) {
        f16x8 af0 = rdS(Ah, wr * 32 + lc, ks * 4 + lr);
        f16x8 af1 = rdS(Ah, wr * 32 + 16 + lc, ks * 4 + lr);
#pragma unroll
        for (int j = 0; j < 4; j++) {
            f16x8 bf = rdS(Bh, wc * 64 + j * 16 + lc, ks * 4 + lr);
            acc[0][j] = __builtin_amdgcn_mfma_f32_16x16x32_f16(af0, bf, acc[0][j], 0, 0, 0);
            acc[1][j] = __builtin_amdgcn_mfma_f32_16x16x32_f16(af1, bf, acc[1][j], 0, 0, 0);
        }
    }

#pragma unroll
    for (int i = 0; i < 2; i++) {
        int mb = m0 + wr * 32 + i * 16 + lr * 4;
#pragma unroll
        for (int j = 0; j < 4; j++) {
            int n = n0 + wc * 64 + j * 16 + lc;
#pragma unroll
            for (int r = 0; r < 4; r++)
                C[(size_t)(mb + r) * 4096 + n] = fmaxf(acc[i][j][r], 1e-6f);
        }
    }
}

// ---------------------------------------------------------------------------
extern "C" void kernel_launch(void* const* d_in, const int* in_sizes, int n_in,
                              void* d_out, int out_size, void* d_ws, size_t ws_size,
                              hipStream_t stream)
{
    const float* src  = (const float*)d_in[0];
    const float* Wqkv = (const float*)d_in[1];
    const float* bqkv = (const float*)d_in[2];
    const float* Wo   = (const float*)d_in[3];
    const float* bo   = (const float*)d_in[4];
    const float* ln1g = (const float*)d_in[5];
    const float* ln1b = (const float*)d_in[6];
    const float* W1   = (const float*)d_in[7];
    const float* b1   = (const float*)d_in[8];
    const float* W2   = (const float*)d_in[9];
    const float* b2   = (const float*)d_in[10];
    const float* ln2g = (const float*)d_in[11];
    const float* ln2b = (const float*)d_in[12];
    const float* fc1W = (const float*)d_in[13];
    const float* fc1b = (const float*)d_in[14];
    const float* fc2W = (const float*)d_in[15];
    const float* fc2b = (const float*)d_in[16];

    float* ws = (float*)d_ws;
    float*    x   = ws;                                   // 524288 f32 (post-LN2 chain)
    _Float16* xh  = (_Float16*)(ws + 524288);             // 524288 f16 (post-LN1 / init)
    _Float16* aoh = (_Float16*)(ws + 786432);             // 524288 f16
    _Float16* qh  = (_Float16*)(ws + 1048576);            // 524288 f16
    _Float16* kh  = (_Float16*)(ws + 1310720);            // 524288 f16
    _Float16* vt  = (_Float16*)(ws + 1572864);            // 524288 f16
    float*    mll = ws + 1835008;                         // 131072 f32

    // d_out scratch (all dead before gram writes):
    _Float16* wpart = (_Float16*)d_out + 4194304;         // bytes [ 8MiB,16MiB)
    _Float16* apart = (_Float16*)d_out + 12582912;        // bytes [24MiB,32MiB)
    _Float16* wh    = (_Float16*)d_out + 16777216;        // bytes [32MiB,~34MiB)
    float*    x1    = (float*)d_out + 9437184;            // bytes [36MiB,38MiB) post-LN1
    float*    out   = (float*)d_out;

    _Float16* qkvh = wh;                  // 3 x 384 x 128
    _Float16* woh  = wh + 147456;         // 3 x 128 x 128
    _Float16* w1h  = wh + 196608;         // 3 x 1024 x 128
    _Float16* w2h  = wh + 589824;         // 3 x 128 x 1024
    _Float16* fc1h = wh + 983040;         // 128 x 128
    _Float16* fc2h = wh + 999424;         // 128 x 128

    setup_cvt<<<1504, 256, 0, stream>>>(Wqkv, Wo, W1, W2, fc1W, fc2W, wh,
                                        src, x, xh);
    // layer 0
    gemm_qkv<<<dim3(256, 3), 256, 0, stream>>>(xh, qkvh, bqkv, qh, kh, vt);
    attn_mfma<<<dim3(64, 4, SPLIT), 256, 0, stream>>>(qh, kh, vt, apart, mll);
    wo_ln_merge<<<256, 256, 0, stream>>>(apart, mll, woh, bo, x, x1, xh,
                                         ln1g, ln1b);
    ffn_pair<<<dim3(64, 8), 256, 0, stream>>>(xh, w1h, b1, w2h, wpart);
    // layers 1, 2: QKV with fused FFN-merge + LN2 of previous layer
    for (int l = 1; l < 3; l++) {
        gemm_qkv_merge<<<dim3(256, 3), 256, 0, stream>>>(
            wpart, x1, b2 + (l - 1) * 128, ln2g + (l - 1) * 128,
            ln2b + (l - 1) * 128, x,
            qkvh + l * 49152, bqkv + l * 384, qh, kh, vt);
        attn_mfma<<<dim3(64, 4, SPLIT), 256, 0, stream>>>(qh, kh, vt, apart, mll);
        wo_ln_merge<<<256, 256, 0, stream>>>(apart, mll, woh + l * 16384,
                                             bo + l * 128, x, x1, xh,
                                             ln1g + l * 128, ln1b + l * 128);
        ffn_pair<<<dim3(64, 8), 256, 0, stream>>>(xh, w1h + l * 131072,
                                                  b1 + l * 1024,
                                                  w2h + l * 131072, wpart);
    }
    // fc chain with fused FFN-merge + LN2 of layer 2
    fc_fused<<<256, 256, 0, stream>>>(wpart, x1, b2 + 256, ln2g + 256,
                                      ln2b + 256, fc1h, fc1b, fc2h, fc2b, aoh);
    gram_f16<<<dim3(64, 32), 256, 0, stream>>>(aoh, out);
}

// Round 8
// 260.826 us; speedup vs baseline: 1.0540x; 1.0004x over previous
//
#include <hip/hip_runtime.h>
#include <math.h>

#define S 4096
#define QK_SCALE 0.17677669529663687f  // 1/sqrt(32)
#define LOG2E    1.44269504088896f
#define SPLIT 8
#define KS (S / SPLIT)                 // 512 keys per split

typedef _Float16 f16x8 __attribute__((ext_vector_type(8)));
typedef _Float16 f16x4 __attribute__((ext_vector_type(4)));
typedef _Float16 f16x2 __attribute__((ext_vector_type(2)));
typedef float f32x4 __attribute__((ext_vector_type(4)));

// ---------------------------------------------------------------------------
// MFMA lane map (HW-verified R4): A-frag m=l&15, k=(l>>4)*8+j; B-frag n=l&15;
// C reg r: row=(l>>4)*4+r, col=l&15.
// R17: base = R7 (260.9us, best). ONE change: s_setprio(1) around attn's
// MFMA clusters (T5 — attn-positive in isolation per m191; never isolated
// here, R3 bundled it with regressions). Mechanism: 6 blocks/CU co-resident,
// waves at different phases (staging/exp2/MFMA) -> priority lets MFMA-issuing
// waves preempt other blocks' staging waves. Everything else identical.
// Staging: global_load_lds 16B direct-to-LDS, source-granule XOR swizzle
// (g ^= row&15) + same XOR on reads (both-sides involution, 2 lanes/bank).
// ---------------------------------------------------------------------------

// direct-to-LDS stage of ROWS x 128 f16 tile, linear [128] stride, source
// granule-swizzled so a swizzled read recovers logical layout.
template<int ROWS>
__device__ __forceinline__ void stageGL(_Float16 (*dst)[128], const _Float16* src,
                                        int ld, int row0, int col0, int tid) {
    int w = tid >> 6, l = tid & 63;
    constexpr int NISS = ROWS / 16;         // wave-issues per wave (4 waves)
#pragma unroll
    for (int v = 0; v < NISS; v++) {
        int G = (w * NISS + v) * 64 + l;    // linear granule id
        int row = G >> 4, g = G & 15;
        int gs = g ^ (row & 15);            // swizzled source granule
        const void* gp = src + (size_t)(row0 + row) * ld + col0 + gs * 8;
        void* lp = (char*)&dst[0][0] + (size_t)G * 16;
        __builtin_amdgcn_global_load_lds(
            (const __attribute__((address_space(1))) void*)gp,
            (__attribute__((address_space(3))) void*)lp, 16, 0, 0);
    }
}

// swizzled 16B fragment read: logical granule qg of row
__device__ __forceinline__ f16x8 rdS(const _Float16 (*B)[128], int row, int qg) {
    return *(const f16x8*)&B[row][(qg ^ (row & 15)) << 3];
}
// swizzled element write (for register-computed tiles)
__device__ __forceinline__ void wrS(_Float16 (*B)[128], int row, int col, _Float16 v) {
    B[row][((((col >> 3) ^ (row & 15))) << 3) | (col & 7)] = v;
}

// ---------------------------------------------------------------------------
// setup: weight fp32->fp16 conversion (blocks 0..991) + x/xh copy (992..1503).
// ---------------------------------------------------------------------------
__global__ __launch_bounds__(256) void setup_cvt(const float* __restrict__ q,
                                                 const float* __restrict__ wo,
                                                 const float* __restrict__ w1,
                                                 const float* __restrict__ w2,
                                                 const float* __restrict__ f1,
                                                 const float* __restrict__ f2,
                                                 _Float16* __restrict__ dst,
                                                 const float* __restrict__ a,
                                                 float* __restrict__ x,
                                                 _Float16* __restrict__ xh)
{
    int bb = blockIdx.x;
    if (bb < 992) {
        const float* src; size_t dof; int lb;
        if (bb < 144)      { src = q;  dof = 0;      lb = bb; }
        else if (bb < 192) { src = wo; dof = 147456; lb = bb - 144; }
        else if (bb < 576) { src = w1; dof = 196608; lb = bb - 192; }
        else if (bb < 960) { src = w2; dof = 589824; lb = bb - 576; }
        else if (bb < 976) { src = f1; dof = 983040; lb = bb - 960; }
        else               { src = f2; dof = 999424; lb = bb - 976; }
        int i = lb * 1024 + threadIdx.x * 4;
        float4 v = *(const float4*)(src + i);
        f16x4 h = {(_Float16)v.x, (_Float16)v.y, (_Float16)v.z, (_Float16)v.w};
        *(f16x4*)(dst + dof + i) = h;
    } else {
        int i = (bb - 992) * 256 + threadIdx.x;
        float4 v = ((const float4*)a)[i];
        ((float4*)x)[i] = v;
        f16x4 h = {(_Float16)v.x, (_Float16)v.y, (_Float16)v.z, (_Float16)v.w};
        ((f16x4*)xh)[i] = h;
    }
}

// ---------------------------------------------------------------------------
// QKV GEMM (layer 0), 16-row tiles, full-K single barrier, glds staging.
// grid (256, 3): by=0 -> qh (scaled), by=1 -> kh, by=2 -> vt (transposed).
// ---------------------------------------------------------------------------
__global__ __launch_bounds__(256) void gemm_qkv(const _Float16* __restrict__ xh,
                                                const _Float16* __restrict__ Wh,
                                                const float* __restrict__ bias,
                                                _Float16* __restrict__ qh,
                                                _Float16* __restrict__ kh,
                                                _Float16* __restrict__ vt)
{
    __shared__ _Float16 Ah[16][128], Bh[128][128];
    int tid = threadIdx.x, w = tid >> 6, l = tid & 63, lc = l & 15, lr = l >> 4;
    int m0 = blockIdx.x * 16, by = blockIdx.y;

    stageGL<16>(Ah, xh, 128, m0, 0, tid);
    stageGL<128>(Bh, Wh, 128, by * 128, 0, tid);
    __syncthreads();

    f32x4 acc[2];
#pragma unroll
    for (int j = 0; j < 2; j++) acc[j] = {0.f, 0.f, 0.f, 0.f};
#pragma unroll
    for (int ks = 0; ks < 4; ks++) {
        f16x8 af = rdS(Ah, lc, ks * 4 + lr);
#pragma unroll
        for (int j = 0; j < 2; j++) {
            f16x8 bf = rdS(Bh, w * 32 + j * 16 + lc, ks * 4 + lr);
            acc[j] = __builtin_amdgcn_mfma_f32_16x16x32_f16(af, bf, acc[j], 0, 0, 0);
        }
    }

    int mb = m0 + lr * 4;
#pragma unroll
    for (int j = 0; j < 2; j++) {
        int n = w * 32 + j * 16 + lc;
        float bb = bias[by * 128 + n];
        if (by == 0) {
#pragma unroll
            for (int r = 0; r < 4; r++)
                qh[(size_t)(mb + r) * 128 + n] =
                    (_Float16)((acc[j][r] + bb) * (QK_SCALE * LOG2E));
        } else if (by == 1) {
            int hh = n >> 5, d = n & 31;
#pragma unroll
            for (int r = 0; r < 4; r++)
                kh[((size_t)hh * S + mb + r) * 32 + d] = (_Float16)(acc[j][r] + bb);
        } else {
            f16x4 pk;
#pragma unroll
            for (int r = 0; r < 4; r++) pk[r] = (_Float16)(acc[j][r] + bb);
            *(f16x4*)&vt[(size_t)n * S + mb] = pk;
        }
    }
}

// ---------------------------------------------------------------------------
// QKV GEMM with fused FFN-merge + LN2 A-stage (layers 1,2). A-tile built from
// 8 W2 partials + b2 + residual(x1, post-LN1) -> LN2 -> Ah. by==0 writes the
// fp32 post-LN2 to x0 (residual for this layer's wo_ln_merge).
// ---------------------------------------------------------------------------
__global__ __launch_bounds__(256) void gemm_qkv_merge(
    const _Float16* __restrict__ wpart, const float* __restrict__ x1,
    const float* __restrict__ b2, const float* __restrict__ g2,
    const float* __restrict__ bn2, float* __restrict__ x0,
    const _Float16* __restrict__ Wh, const float* __restrict__ bias,
    _Float16* __restrict__ qh, _Float16* __restrict__ kh,
    _Float16* __restrict__ vt)
{
    __shared__ _Float16 Ah[16][128], Bh[128][128];
    int tid = threadIdx.x, w = tid >> 6, l = tid & 63, lc = l & 15, lr = l >> 4;
    int m0 = blockIdx.x * 16, by = blockIdx.y;

    stageGL<128>(Bh, Wh, 128, by * 128, 0, tid);   // B in flight during merge
    {   // merge 8 W2-partials + b2 + residual + LN2 -> Ah (16 x 128)
        int row = tid >> 4, qg = tid & 15, col0 = qg * 8;
        int q = m0 + row;
        float am[8];
#pragma unroll
        for (int e = 0; e < 8; e++) am[e] = 0.f;
#pragma unroll
        for (int s = 0; s < 8; s++) {
            f16x8 t = *(const f16x8*)&wpart[(size_t)s * 524288 + (size_t)q * 128 + col0];
#pragma unroll
            for (int e = 0; e < 8; e++) am[e] += (float)t[e];
        }
#pragma unroll
        for (int e = 0; e < 8; e++)
            am[e] += b2[col0 + e] + x1[(size_t)q * 128 + col0 + e];
        float s1 = 0.f, s2 = 0.f;
#pragma unroll
        for (int e = 0; e < 8; e++) { s1 += am[e]; s2 += am[e] * am[e]; }
#pragma unroll
        for (int off = 1; off < 16; off <<= 1) {   // row = aligned 16-lane group
            s1 += __shfl_xor(s1, off);
            s2 += __shfl_xor(s2, off);
        }
        float mean = s1 * (1.0f / 128.0f);
        float var = s2 * (1.0f / 128.0f) - mean * mean;
        float inv = rsqrtf(var + 1e-5f);
        float o[8];
        f16x8 hv;
#pragma unroll
        for (int e = 0; e < 8; e++) {
            o[e] = (am[e] - mean) * inv * g2[col0 + e] + bn2[col0 + e];
            hv[e] = (_Float16)o[e];
        }
        *(f16x8*)&Ah[row][(qg ^ (row & 15)) << 3] = hv;
        if (by == 0) {
            float4 v0 = {o[0], o[1], o[2], o[3]};
            float4 v1 = {o[4], o[5], o[6], o[7]};
            *(float4*)&x0[(size_t)q * 128 + col0]     = v0;
            *(float4*)&x0[(size_t)q * 128 + col0 + 4] = v1;
        }
    }
    __syncthreads();

    f32x4 acc[2];
#pragma unroll
    for (int j = 0; j < 2; j++) acc[j] = {0.f, 0.f, 0.f, 0.f};
#pragma unroll
    for (int ks = 0; ks < 4; ks++) {
        f16x8 af = rdS(Ah, lc, ks * 4 + lr);
#pragma unroll
        for (int j = 0; j < 2; j++) {
            f16x8 bf = rdS(Bh, w * 32 + j * 16 + lc, ks * 4 + lr);
            acc[j] = __builtin_amdgcn_mfma_f32_16x16x32_f16(af, bf, acc[j], 0, 0, 0);
        }
    }

    int mb = m0 + lr * 4;
#pragma unroll
    for (int j = 0; j < 2; j++) {
        int n = w * 32 + j * 16 + lc;
        float bb = bias[by * 128 + n];
        if (by == 0) {
#pragma unroll
            for (int r = 0; r < 4; r++)
                qh[(size_t)(mb + r) * 128 + n] =
                    (_Float16)((acc[j][r] + bb) * (QK_SCALE * LOG2E));
        } else if (by == 1) {
            int hh = n >> 5, d = n & 31;
#pragma unroll
            for (int r = 0; r < 4; r++)
                kh[((size_t)hh * S + mb + r) * 32 + d] = (_Float16)(acc[j][r] + bb);
        } else {
            f16x4 pk;
#pragma unroll
            for (int r = 0; r < 4; r++) pk[r] = (_Float16)(acc[j][r] + bb);
            *(f16x4*)&vt[(size_t)n * S + mb] = pk;
        }
    }
}

// ---------------------------------------------------------------------------
// MFMA flash attention: K/V double-buffer, async-split staging, one barrier
// per tile; swapped QK^T, packed Ps. R17: s_setprio(1) around MFMA clusters.
// ---------------------------------------------------------------------------
__global__ __launch_bounds__(256) void attn_mfma(const _Float16* __restrict__ qh,
                                                 const _Float16* __restrict__ kh,
                                                 const _Float16* __restrict__ vt,
                                                 _Float16* __restrict__ part,
                                                 float* __restrict__ mll)
{
    __shared__ _Float16 Ks[2][64][32];
    __shared__ _Float16 Vt[2][32][72];
    __shared__ _Float16 Ps[4][16][72];
    int h = blockIdx.y, q0 = blockIdx.x * 64, z = blockIdx.z;
    int tid = threadIdx.x;
    int w = tid >> 6, l = tid & 63;
    int lc = l & 15, lr = l >> 4;

    f16x8 qf = *(const f16x8*)&qh[(size_t)(q0 + w * 16 + lc) * 128 + h * 32 + lr * 8];

    const _Float16* khh = kh + (size_t)h * S * 32;
    const _Float16* vth = vt + (size_t)h * 32 * S;

    int krow = tid >> 2, kcol = (tid & 3) * 8;
    int vrow = tid >> 3, vcol = (tid & 7) * 8;

    f32x4 o0 = {0.f, 0.f, 0.f, 0.f}, o1 = {0.f, 0.f, 0.f, 0.f};
    float lp = 0.f;

    int k0 = z * KS;
    {   // prologue: stage tile 0
        f16x8 kr = *(const f16x8*)&khh[(size_t)(k0 + krow) * 32 + kcol];
        f16x8 vr = *(const f16x8*)&vth[(size_t)vrow * S + k0 + vcol];
        *(f16x8*)&Ks[0][krow][kcol] = kr;
        *(f16x8*)&Vt[0][vrow][vcol] = vr;
    }
    __syncthreads();

    int cur = 0;
#pragma unroll 1
    for (int t8 = 0; t8 < KS / 64; t8++) {
        bool more = (t8 + 1 < KS / 64);
        f16x8 kr, vr;
        if (more) {   // issue next tile's loads early; latency hides under compute
            int kn = k0 + (t8 + 1) * 64;
            kr = *(const f16x8*)&khh[(size_t)(kn + krow) * 32 + kcol];
            vr = *(const f16x8*)&vth[(size_t)vrow * S + kn + vcol];
        }

        f32x4 st[4];
        __builtin_amdgcn_s_setprio(1);
#pragma unroll
        for (int t = 0; t < 4; t++) {
            f16x8 kf = *(const f16x8*)&Ks[cur][t * 16 + lc][lr * 8];
            f32x4 zz = {0.f, 0.f, 0.f, 0.f};
            st[t] = __builtin_amdgcn_mfma_f32_16x16x32_f16(kf, qf, zz, 0, 0, 0);
        }
        __builtin_amdgcn_s_setprio(0);
#pragma unroll
        for (int t = 0; t < 4; t++) {
            float p0 = exp2f(st[t][0]), p1 = exp2f(st[t][1]);
            float p2 = exp2f(st[t][2]), p3 = exp2f(st[t][3]);
            lp += (p0 + p1) + (p2 + p3);
            f16x2 h0 = {(_Float16)p0, (_Float16)p1};
            f16x2 h1 = {(_Float16)p2, (_Float16)p3};
            *(f16x2*)&Ps[w][lc][t * 16 + lr * 4]     = h0;
            *(f16x2*)&Ps[w][lc][t * 16 + lr * 4 + 2] = h1;
        }
        asm volatile("s_waitcnt lgkmcnt(0)" ::: "memory");
        __builtin_amdgcn_s_setprio(1);
#pragma unroll
        for (int ch = 0; ch < 2; ch++) {
            f16x8 pf = *(const f16x8*)&Ps[w][lc][ch * 32 + lr * 8];
            f16x8 v0 = *(const f16x8*)&Vt[cur][lc][ch * 32 + lr * 8];
            f16x8 v1 = *(const f16x8*)&Vt[cur][16 + lc][ch * 32 + lr * 8];
            o0 = __builtin_amdgcn_mfma_f32_16x16x32_f16(pf, v0, o0, 0, 0, 0);
            o1 = __builtin_amdgcn_mfma_f32_16x16x32_f16(pf, v1, o1, 0, 0, 0);
        }
        __builtin_amdgcn_s_setprio(0);
        if (more) {
            *(f16x8*)&Ks[cur ^ 1][krow][kcol] = kr;
            *(f16x8*)&Vt[cur ^ 1][vrow][vcol] = vr;
            __syncthreads();
        }
        cur ^= 1;
    }

    lp += __shfl_xor(lp, 16);
    lp += __shfl_xor(lp, 32);

    _Float16* pz = part + (size_t)z * 524288;
#pragma unroll
    for (int i = 0; i < 4; i++) {
        int q = q0 + w * 16 + lr * 4 + i;
        pz[(size_t)q * 128 + h * 32 + lc]      = (_Float16)o0[i];
        pz[(size_t)q * 128 + h * 32 + 16 + lc] = (_Float16)o1[i];
    }
    if (l < 16) mll[((size_t)z * 4 + h) * 4096 + q0 + w * 16 + lc] = lp;
}

// ---------------------------------------------------------------------------
// Wo GEMM + split-attention merge + residual(x0) + LN1 -> x1 (fp32), xh (f16).
// 16-row tiles, glds B staging; merge-A written with element swizzle.
// ---------------------------------------------------------------------------
__global__ __launch_bounds__(256) void wo_ln_merge(const _Float16* __restrict__ part,
                                                   const float* __restrict__ mll,
                                                   const _Float16* __restrict__ Wh,
                                                   const float* __restrict__ bias,
                                                   const float* __restrict__ xres,
                                                   float* __restrict__ xo,
                                                   _Float16* __restrict__ xh,
                                                   const float* __restrict__ g,
                                                   const float* __restrict__ b)
{
    __shared__ _Float16 Ah[16][128], Bh[128][128];
    __shared__ float Red[16][4][2];
    int tid = threadIdx.x, w = tid >> 6, l = tid & 63, lc = l & 15, lr = l >> 4;
    int m0 = blockIdx.x * 16;

    stageGL<128>(Bh, Wh, 128, 0, 0, tid);
    {   // merge-stage A: 16 rows x 128 cols, 8 cols/thread (granule-aligned)
        int row = tid >> 4, qg = tid & 15;
        int col0 = qg * 8;
        int q = m0 + row, hh = col0 >> 5;
        float lsum = 0.f;
#pragma unroll
        for (int s = 0; s < SPLIT; s++) lsum += mll[((size_t)s * 4 + hh) * 4096 + q];
        float am[8];
#pragma unroll
        for (int e = 0; e < 8; e++) am[e] = 0.f;
#pragma unroll
        for (int s = 0; s < SPLIT; s++) {
            f16x8 t = *(const f16x8*)&part[(size_t)s * 524288 + (size_t)q * 128 + col0];
#pragma unroll
            for (int e = 0; e < 8; e++) am[e] += (float)t[e];
        }
        float inv = 1.f / lsum;
        f16x8 hv;
#pragma unroll
        for (int e = 0; e < 8; e++) hv[e] = (_Float16)(am[e] * inv);
        *(f16x8*)&Ah[row][(qg ^ (row & 15)) << 3] = hv;   // swizzled slot
    }
    __syncthreads();

    f32x4 acc[2];
#pragma unroll
    for (int j = 0; j < 2; j++) acc[j] = {0.f, 0.f, 0.f, 0.f};
#pragma unroll
    for (int ks = 0; ks < 4; ks++) {
        f16x8 af = rdS(Ah, lc, ks * 4 + lr);
#pragma unroll
        for (int j = 0; j < 2; j++) {
            f16x8 bf = rdS(Bh, w * 32 + j * 16 + lc, ks * 4 + lr);
            acc[j] = __builtin_amdgcn_mfma_f32_16x16x32_f16(af, bf, acc[j], 0, 0, 0);
        }
    }

#pragma unroll
    for (int j = 0; j < 2; j++) {
        int n = w * 32 + j * 16 + lc;
        float bb = bias[n];
#pragma unroll
        for (int r = 0; r < 4; r++)
            acc[j][r] += bb + xres[(size_t)(m0 + lr * 4 + r) * 128 + n];
    }
#pragma unroll
    for (int r = 0; r < 4; r++) {
        float s1 = acc[0][r] + acc[1][r];
        float s2 = acc[0][r] * acc[0][r] + acc[1][r] * acc[1][r];
#pragma unroll
        for (int off = 1; off < 16; off <<= 1) {
            s1 += __shfl_xor(s1, off);
            s2 += __shfl_xor(s2, off);
        }
        if (lc == 0) { Red[lr * 4 + r][w][0] = s1; Red[lr * 4 + r][w][1] = s2; }
    }
    __syncthreads();
#pragma unroll
    for (int r = 0; r < 4; r++) {
        int rl = lr * 4 + r;
        float S1 = (Red[rl][0][0] + Red[rl][1][0]) + (Red[rl][2][0] + Red[rl][3][0]);
        float S2 = (Red[rl][0][1] + Red[rl][1][1]) + (Red[rl][2][1] + Red[rl][3][1]);
        float mean = S1 * (1.0f / 128.0f);
        float var = S2 * (1.0f / 128.0f) - mean * mean;
        float inv = rsqrtf(var + 1e-5f);
        int m = m0 + rl;
#pragma unroll
        for (int j = 0; j < 2; j++) {
            int n = w * 32 + j * 16 + lc;
            float o = (acc[j][r] - mean) * inv * g[n] + b[n];
            xo[(size_t)m * 128 + n] = o;
            xh[(size_t)m * 128 + n] = (_Float16)o;
        }
    }
}

// ---------------------------------------------------------------------------
// Fused W1+W2 pair, 64-row tiles, grid (64, 8) = 512 blocks, glds staging.
// relu(F) written back into Ah with element swizzle.
// ---------------------------------------------------------------------------
__global__ __launch_bounds__(256) void ffn_pair(const _Float16* __restrict__ xh,
                                                const _Float16* __restrict__ W1h,
                                                const float* __restrict__ b1,
                                                const _Float16* __restrict__ W2h,
                                                _Float16* __restrict__ wpart)
{
    __shared__ _Float16 Ah[64][128], Bh[128][128];
    int tid = threadIdx.x, w = tid >> 6, l = tid & 63, lc = l & 15, lr = l >> 4;
    int wr = w >> 1, wc = w & 1;
    int m0 = blockIdx.x * 64, c = blockIdx.y;

    stageGL<64>(Ah, xh, 128, m0, 0, tid);
    stageGL<128>(Bh, W1h, 128, c * 128, 0, tid);
    __syncthreads();

    f32x4 acc[2][4];
#pragma unroll
    for (int i = 0; i < 2; i++)
#pragma unroll
        for (int j = 0; j < 4; j++) acc[i][j] = {0.f, 0.f, 0.f, 0.f};
#pragma unroll
    for (int ks = 0; ks < 4; ks++) {
        f16x8 af0 = rdS(Ah, wr * 32 + lc, ks * 4 + lr);
        f16x8 af1 = rdS(Ah, wr * 32 + 16 + lc, ks * 4 + lr);
#pragma unroll
        for (int j = 0; j < 4; j++) {
            f16x8 bf = rdS(Bh, wc * 64 + j * 16 + lc, ks * 4 + lr);
            acc[0][j] = __builtin_amdgcn_mfma_f32_16x16x32_f16(af0, bf, acc[0][j], 0, 0, 0);
            acc[1][j] = __builtin_amdgcn_mfma_f32_16x16x32_f16(af1, bf, acc[1][j], 0, 0, 0);
        }
    }
    __syncthreads();   // all pass-1 reads of Ah/Bh done

    // relu + bias -> F (into Ah, swizzled element writes)
#pragma unroll
    for (int i = 0; i < 2; i++)
#pragma unroll
        for (int j = 0; j < 4; j++) {
            int n = wc * 64 + j * 16 + lc;
            float bb = b1[c * 128 + n];
#pragma unroll
            for (int r = 0; r < 4; r++)
                wrS(Ah, wr * 32 + i * 16 + lr * 4 + r, n,
                    (_Float16)fmaxf(acc[i][j][r] + bb, 0.f));
        }
    stageGL<128>(Bh, W2h, 1024, 0, c * 128, tid);
    __syncthreads();

    f32x4 oacc[2][4];
#pragma unroll
    for (int i = 0; i < 2; i++)
#pragma unroll
        for (int j = 0; j < 4; j++) oacc[i][j] = {0.f, 0.f, 0.f, 0.f};
#pragma unroll
    for (int ks = 0; ks < 4; ks++) {
        f16x8 af0 = rdS(Ah, wr * 32 + lc, ks * 4 + lr);
        f16x8 af1 = rdS(Ah, wr * 32 + 16 + lc, ks * 4 + lr);
#pragma unroll
        for (int j = 0; j < 4; j++) {
            f16x8 bf = rdS(Bh, wc * 64 + j * 16 + lc, ks * 4 + lr);
            oacc[0][j] = __builtin_amdgcn_mfma_f32_16x16x32_f16(af0, bf, oacc[0][j], 0, 0, 0);
            oacc[1][j] = __builtin_amdgcn_mfma_f32_16x16x32_f16(af1, bf, oacc[1][j], 0, 0, 0);
        }
    }

    _Float16* pz = wpart + (size_t)c * 524288;
#pragma unroll
    for (int i = 0; i < 2; i++) {
        int mb = m0 + wr * 32 + i * 16 + lr * 4;
#pragma unroll
        for (int j = 0; j < 4; j++) {
            int n = wc * 64 + j * 16 + lc;
#pragma unroll
            for (int r = 0; r < 4; r++)
                pz[(size_t)(mb + r) * 128 + n] = (_Float16)oacc[i][j][r];
        }
    }
}

// ---------------------------------------------------------------------------
// fc1 + relu + fc2 + rownorm fused, with fused FFN-merge + LN2 A-stage
// (layer 2). 16-row tiles, grid 256, glds staging for weights.
// ---------------------------------------------------------------------------
__global__ __launch_bounds__(256) void fc_fused(const _Float16* __restrict__ wpart,
                                                const float* __restrict__ x1,
                                                const float* __restrict__ b2l,
                                                const float* __restrict__ g2,
                                                const float* __restrict__ bn2,
                                                const _Float16* __restrict__ W1h,
                                                const float* __restrict__ b1f,
                                                const _Float16* __restrict__ W2h,
                                                const float* __restrict__ b2f,
                                                _Float16* __restrict__ aoh)
{
    __shared__ _Float16 Ah[16][128], Bh[128][128];
    __shared__ float Red[16][4];
    int tid = threadIdx.x, w = tid >> 6, l = tid & 63, lc = l & 15, lr = l >> 4;
    int m0 = blockIdx.x * 16;

    stageGL<128>(Bh, W1h, 128, 0, 0, tid);
    {   // merge 8 W2-partials + b2 + residual + LN2 -> Ah
        int row = tid >> 4, qg = tid & 15, col0 = qg * 8;
        int q = m0 + row;
        float am[8];
#pragma unroll
        for (int e = 0; e < 8; e++) am[e] = 0.f;
#pragma unroll
        for (int s = 0; s < 8; s++) {
            f16x8 t = *(const f16x8*)&wpart[(size_t)s * 524288 + (size_t)q * 128 + col0];
#pragma unroll
            for (int e = 0; e < 8; e++) am[e] += (float)t[e];
        }
#pragma unroll
        for (int e = 0; e < 8; e++)
            am[e] += b2l[col0 + e] + x1[(size_t)q * 128 + col0 + e];
        float s1 = 0.f, s2 = 0.f;
#pragma unroll
        for (int e = 0; e < 8; e++) { s1 += am[e]; s2 += am[e] * am[e]; }
#pragma unroll
        for (int off = 1; off < 16; off <<= 1) {
            s1 += __shfl_xor(s1, off);
            s2 += __shfl_xor(s2, off);
        }
        float mean = s1 * (1.0f / 128.0f);
        float var = s2 * (1.0f / 128.0f) - mean * mean;
        float inv = rsqrtf(var + 1e-5f);
        f16x8 hv;
#pragma unroll
        for (int e = 0; e < 8; e++)
            hv[e] = (_Float16)((am[e] - mean) * inv * g2[col0 + e] + bn2[col0 + e]);
        *(f16x8*)&Ah[row][(qg ^ (row & 15)) << 3] = hv;
    }
    __syncthreads();

    f32x4 acc[2];
#pragma unroll
    for (int j = 0; j < 2; j++) acc[j] = {0.f, 0.f, 0.f, 0.f};
#pragma unroll
    for (int ks = 0; ks < 4; ks++) {
        f16x8 af = rdS(Ah, lc, ks * 4 + lr);
#pragma unroll
        for (int j = 0; j < 2; j++) {
            f16x8 bf = rdS(Bh, w * 32 + j * 16 + lc, ks * 4 + lr);
            acc[j] = __builtin_amdgcn_mfma_f32_16x16x32_f16(af, bf, acc[j], 0, 0, 0);
        }
    }
    __syncthreads();   // pass-1 reads done
#pragma unroll
    for (int j = 0; j < 2; j++) {
        int n = w * 32 + j * 16 + lc;
        float bb = b1f[n];
#pragma unroll
        for (int r = 0; r < 4; r++)
            wrS(Ah, lr * 4 + r, n, (_Float16)fmaxf(acc[j][r] + bb, 0.f));
    }
    stageGL<128>(Bh, W2h, 128, 0, 0, tid);
    __syncthreads();

    f32x4 o[2];
#pragma unroll
    for (int j = 0; j < 2; j++) o[j] = {0.f, 0.f, 0.f, 0.f};
#pragma unroll
    for (int ks = 0; ks < 4; ks++) {
        f16x8 af = rdS(Ah, lc, ks * 4 + lr);
#pragma unroll
        for (int j = 0; j < 2; j++) {
            f16x8 bf = rdS(Bh, w * 32 + j * 16 + lc, ks * 4 + lr);
            o[j] = __builtin_amdgcn_mfma_f32_16x16x32_f16(af, bf, o[j], 0, 0, 0);
        }
    }
#pragma unroll
    for (int j = 0; j < 2; j++) {
        float bb = b2f[w * 32 + j * 16 + lc];
#pragma unroll
        for (int r = 0; r < 4; r++) o[j][r] += bb;
    }
#pragma unroll
    for (int r = 0; r < 4; r++) {
        float s2 = o[0][r] * o[0][r] + o[1][r] * o[1][r];
#pragma unroll
        for (int off = 1; off < 16; off <<= 1) s2 += __shfl_xor(s2, off);
        if (lc == 0) Red[lr * 4 + r][w] = s2;
    }
    __syncthreads();
#pragma unroll
    for (int r = 0; r < 4; r++) {
        int rl = lr * 4 + r;
        float inv = rsqrtf((Red[rl][0] + Red[rl][1]) + (Red[rl][2] + Red[rl][3]));
        int m = m0 + rl;
#pragma unroll
        for (int j = 0; j < 2; j++) {
            int n = w * 32 + j * 16 + lc;
            aoh[(size_t)m * 128 + n] = (_Float16)(o[j][r] * inv);
        }
    }
}

// ---------------------------------------------------------------------------
// Gram: C = max(aoh @ aoh^T, 1e-6). 64x128 tiles, glds staging,
// grid (64, 32) = 2048 blocks.
// ---------------------------------------------------------------------------
__global__ __launch_bounds__(256) void gram_f16(const _Float16* __restrict__ aoh,
                                                float* __restrict__ C)
{
    __shared__ _Float16 Ah[64][128], Bh[128][128];
    int tid = threadIdx.x, w = tid >> 6, l = tid & 63, lc = l & 15, lr = l >> 4;
    int wr = w >> 1, wc = w & 1;
    int m0 = blockIdx.x * 64, n0 = blockIdx.y * 128;

    stageGL<64>(Ah, aoh, 128, m0, 0, tid);
    stageGL<128>(Bh, aoh, 128, n0, 0, tid);
    __syncthreads();

    f32x4 acc[2][4];
#pragma unroll
    for (int i = 0; i < 2; i++)
#pragma unroll
        for (int j = 0; j < 4; j++) acc[i][j] = {0.f, 0.f, 0.f, 0.f};
#pragma unroll
    for (int ks = 0; ks < 4; ks++) {
        f16x8 af0 = rdS(Ah, wr * 32 + lc, ks * 4 + lr);
        f16x8 af1 = rdS(Ah, wr * 32 + 16 + lc, ks * 4 + lr);
#pragma unroll
        for (int j = 0; j < 4; j++) {
            f16x8 bf = rdS(Bh, wc * 64 + j * 16 + lc, ks * 4 + lr);
            acc[0][j] = __builtin_amdgcn_mfma_f32_16x16x32_f16(af0, bf, acc[0][j], 0, 0, 0);
            acc[1][j] = __builtin_amdgcn_mfma_f32_16x16x32_f16(af1, bf, acc[1][j], 0, 0, 0);
        }
    }

#pragma unroll
    for (int i = 0; i < 2; i++) {
        int mb = m0 + wr * 32 + i * 16 + lr * 4;
#pragma unroll
        for (int j = 0; j < 4; j++) {
            int n = n0 + wc * 64 + j * 16 + lc;
#pragma unroll
            for (int r = 0; r < 4; r++)
                C[(size_t)(mb + r) * 4096 + n] = fmaxf(acc[i][j][r], 1e-6f);
        }
    }
}

// ---------------------------------------------------------------------------
extern "C" void kernel_launch(void* const* d_in, const int* in_sizes, int n_in,
                              void* d_out, int out_size, void* d_ws, size_t ws_size,
                              hipStream_t stream)
{
    const float* src  = (const float*)d_in[0];
    const float* Wqkv = (const float*)d_in[1];
    const float* bqkv = (const float*)d_in[2];
    const float* Wo   = (const float*)d_in[3];
    const float* bo   = (const float*)d_in[4];
    const float* ln1g = (const float*)d_in[5];
    const float* ln1b = (const float*)d_in[6];
    const float* W1   = (const float*)d_in[7];
    const float* b1   = (const float*)d_in[8];
    const float* W2   = (const float*)d_in[9];
    const float* b2   = (const float*)d_in[10];
    const float* ln2g = (const float*)d_in[11];
    const float* ln2b = (const float*)d_in[12];
    const float* fc1W = (const float*)d_in[13];
    const float* fc1b = (const float*)d_in[14];
    const float* fc2W = (const float*)d_in[15];
    const float* fc2b = (const float*)d_in[16];

    float* ws = (float*)d_ws;
    float*    x   = ws;                                   // 524288 f32 (post-LN2 chain)
    _Float16* xh  = (_Float16*)(ws + 524288);             // 524288 f16 (post-LN1 / init)
    _Float16* aoh = (_Float16*)(ws + 786432);             // 524288 f16
    _Float16* qh  = (_Float16*)(ws + 1048576);            // 524288 f16
    _Float16* kh  = (_Float16*)(ws + 1310720);            // 524288 f16
    _Float16* vt  = (_Float16*)(ws + 1572864);            // 524288 f16
    float*    mll = ws + 1835008;                         // 131072 f32

    // d_out scratch (all dead before gram writes):
    _Float16* wpart = (_Float16*)d_out + 4194304;         // bytes [ 8MiB,16MiB)
    _Float16* apart = (_Float16*)d_out + 12582912;        // bytes [24MiB,32MiB)
    _Float16* wh    = (_Float16*)d_out + 16777216;        // bytes [32MiB,~34MiB)
    float*    x1    = (float*)d_out + 9437184;            // bytes [36MiB,38MiB) post-LN1
    float*    out   = (float*)d_out;

    _Float16* qkvh = wh;                  // 3 x 384 x 128
    _Float16* woh  = wh + 147456;         // 3 x 128 x 128
    _Float16* w1h  = wh + 196608;         // 3 x 1024 x 128
    _Float16* w2h  = wh + 589824;         // 3 x 128 x 1024
    _Float16* fc1h = wh + 983040;         // 128 x 128
    _Float16* fc2h = wh + 999424;         // 128 x 128

    setup_cvt<<<1504, 256, 0, stream>>>(Wqkv, Wo, W1, W2, fc1W, fc2W, wh,
                                        src, x, xh);
    // layer 0
    gemm_qkv<<<dim3(256, 3), 256, 0, stream>>>(xh, qkvh, bqkv, qh, kh, vt);
    attn_mfma<<<dim3(64, 4, SPLIT), 256, 0, stream>>>(qh, kh, vt, apart, mll);
    wo_ln_merge<<<256, 256, 0, stream>>>(apart, mll, woh, bo, x, x1, xh,
                                         ln1g, ln1b);
    ffn_pair<<<dim3(64, 8), 256, 0, stream>>>(xh, w1h, b1, w2h, wpart);
    // layers 1, 2: QKV with fused FFN-merge + LN2 of previous layer
    for (int l = 1; l < 3; l++) {
        gemm_qkv_merge<<<dim3(256, 3), 256, 0, stream>>>(
            wpart, x1, b2 + (l - 1) * 128, ln2g + (l - 1) * 128,
            ln2b + (l - 1) * 128, x,
            qkvh + l * 49152, bqkv + l * 384, qh, kh, vt);
        attn_mfma<<<dim3(64, 4, SPLIT), 256, 0, stream>>>(qh, kh, vt, apart, mll);
        wo_ln_merge<<<256, 256, 0, stream>>>(apart, mll, woh + l * 16384,
                                             bo + l * 128, x, x1, xh,
                                             ln1g + l * 128, ln1b + l * 128);
        ffn_pair<<<dim3(64, 8), 256, 0, stream>>>(xh, w1h + l * 131072,
                                                  b1 + l * 1024,
                                                  w2h + l * 131072, wpart);
    }
    // fc chain with fused FFN-merge + LN2 of layer 2
    fc_fused<<<256, 256, 0, stream>>>(wpart, x1, b2 + 256, ln2g + 256,
                                      ln2b + 256, fc1h, fc1b, fc2h, fc2b, aoh);
    gram_f16<<<dim3(64, 32), 256, 0, stream>>>(aoh, out);
}

// Round 9
// 259.779 us; speedup vs baseline: 1.0582x; 1.0040x over previous
//
#include <hip/hip_runtime.h>
#include <math.h>

#define S 4096
#define QK_SCALE 0.17677669529663687f  // 1/sqrt(32)
#define LOG2E    1.44269504088896f
#define SPLIT 8
#define KS (S / SPLIT)                 // 512 keys per split

typedef _Float16 f16x8 __attribute__((ext_vector_type(8)));
typedef _Float16 f16x4 __attribute__((ext_vector_type(4)));
typedef _Float16 f16x2 __attribute__((ext_vector_type(2)));
typedef float f32x4 __attribute__((ext_vector_type(4)));

// ---------------------------------------------------------------------------
// MFMA lane map (HW-verified R4): A-frag m=l&15, k=(l>>4)*8+j; B-frag n=l&15;
// C reg r: row=(l>>4)*4+r, col=l&15.
// R18: base = R8 (260.8us best; setprio null -> kept, harmless). ONE target:
// attn softmax VALU (16 exp + 16 adds + 8 ds_write/tile dominates; MFMA idle).
// (a) l-sum via ones-column MFMA: ol = mfma(pf, ones, ol) -> moves 16 f32
//     adds/tile from VALU to matrix pipe; mll written from ol[i] (lc==0),
//     end-shfls gone. l now sums f16-rounded P (consistent w/ numerator).
// (b) Ps writes fused b32->b64 (adjacent addresses, 8B aligned).
// Staging: global_load_lds 16B direct-to-LDS, source-granule XOR swizzle
// (g ^= row&15) + same XOR on reads (both-sides involution, 2 lanes/bank).
// ---------------------------------------------------------------------------

// direct-to-LDS stage of ROWS x 128 f16 tile, linear [128] stride, source
// granule-swizzled so a swizzled read recovers logical layout.
template<int ROWS>
__device__ __forceinline__ void stageGL(_Float16 (*dst)[128], const _Float16* src,
                                        int ld, int row0, int col0, int tid) {
    int w = tid >> 6, l = tid & 63;
    constexpr int NISS = ROWS / 16;         // wave-issues per wave (4 waves)
#pragma unroll
    for (int v = 0; v < NISS; v++) {
        int G = (w * NISS + v) * 64 + l;    // linear granule id
        int row = G >> 4, g = G & 15;
        int gs = g ^ (row & 15);            // swizzled source granule
        const void* gp = src + (size_t)(row0 + row) * ld + col0 + gs * 8;
        void* lp = (char*)&dst[0][0] + (size_t)G * 16;
        __builtin_amdgcn_global_load_lds(
            (const __attribute__((address_space(1))) void*)gp,
            (__attribute__((address_space(3))) void*)lp, 16, 0, 0);
    }
}

// swizzled 16B fragment read: logical granule qg of row
__device__ __forceinline__ f16x8 rdS(const _Float16 (*B)[128], int row, int qg) {
    return *(const f16x8*)&B[row][(qg ^ (row & 15)) << 3];
}
// swizzled element write (for register-computed tiles)
__device__ __forceinline__ void wrS(_Float16 (*B)[128], int row, int col, _Float16 v) {
    B[row][((((col >> 3) ^ (row & 15))) << 3) | (col & 7)] = v;
}

// ---------------------------------------------------------------------------
// setup: weight fp32->fp16 conversion (blocks 0..991) + x/xh copy (992..1503).
// ---------------------------------------------------------------------------
__global__ __launch_bounds__(256) void setup_cvt(const float* __restrict__ q,
                                                 const float* __restrict__ wo,
                                                 const float* __restrict__ w1,
                                                 const float* __restrict__ w2,
                                                 const float* __restrict__ f1,
                                                 const float* __restrict__ f2,
                                                 _Float16* __restrict__ dst,
                                                 const float* __restrict__ a,
                                                 float* __restrict__ x,
                                                 _Float16* __restrict__ xh)
{
    int bb = blockIdx.x;
    if (bb < 992) {
        const float* src; size_t dof; int lb;
        if (bb < 144)      { src = q;  dof = 0;      lb = bb; }
        else if (bb < 192) { src = wo; dof = 147456; lb = bb - 144; }
        else if (bb < 576) { src = w1; dof = 196608; lb = bb - 192; }
        else if (bb < 960) { src = w2; dof = 589824; lb = bb - 576; }
        else if (bb < 976) { src = f1; dof = 983040; lb = bb - 960; }
        else               { src = f2; dof = 999424; lb = bb - 976; }
        int i = lb * 1024 + threadIdx.x * 4;
        float4 v = *(const float4*)(src + i);
        f16x4 h = {(_Float16)v.x, (_Float16)v.y, (_Float16)v.z, (_Float16)v.w};
        *(f16x4*)(dst + dof + i) = h;
    } else {
        int i = (bb - 992) * 256 + threadIdx.x;
        float4 v = ((const float4*)a)[i];
        ((float4*)x)[i] = v;
        f16x4 h = {(_Float16)v.x, (_Float16)v.y, (_Float16)v.z, (_Float16)v.w};
        ((f16x4*)xh)[i] = h;
    }
}

// ---------------------------------------------------------------------------
// QKV GEMM (layer 0), 16-row tiles, full-K single barrier, glds staging.
// grid (256, 3): by=0 -> qh (scaled), by=1 -> kh, by=2 -> vt (transposed).
// ---------------------------------------------------------------------------
__global__ __launch_bounds__(256) void gemm_qkv(const _Float16* __restrict__ xh,
                                                const _Float16* __restrict__ Wh,
                                                const float* __restrict__ bias,
                                                _Float16* __restrict__ qh,
                                                _Float16* __restrict__ kh,
                                                _Float16* __restrict__ vt)
{
    __shared__ _Float16 Ah[16][128], Bh[128][128];
    int tid = threadIdx.x, w = tid >> 6, l = tid & 63, lc = l & 15, lr = l >> 4;
    int m0 = blockIdx.x * 16, by = blockIdx.y;

    stageGL<16>(Ah, xh, 128, m0, 0, tid);
    stageGL<128>(Bh, Wh, 128, by * 128, 0, tid);
    __syncthreads();

    f32x4 acc[2];
#pragma unroll
    for (int j = 0; j < 2; j++) acc[j] = {0.f, 0.f, 0.f, 0.f};
#pragma unroll
    for (int ks = 0; ks < 4; ks++) {
        f16x8 af = rdS(Ah, lc, ks * 4 + lr);
#pragma unroll
        for (int j = 0; j < 2; j++) {
            f16x8 bf = rdS(Bh, w * 32 + j * 16 + lc, ks * 4 + lr);
            acc[j] = __builtin_amdgcn_mfma_f32_16x16x32_f16(af, bf, acc[j], 0, 0, 0);
        }
    }

    int mb = m0 + lr * 4;
#pragma unroll
    for (int j = 0; j < 2; j++) {
        int n = w * 32 + j * 16 + lc;
        float bb = bias[by * 128 + n];
        if (by == 0) {
#pragma unroll
            for (int r = 0; r < 4; r++)
                qh[(size_t)(mb + r) * 128 + n] =
                    (_Float16)((acc[j][r] + bb) * (QK_SCALE * LOG2E));
        } else if (by == 1) {
            int hh = n >> 5, d = n & 31;
#pragma unroll
            for (int r = 0; r < 4; r++)
                kh[((size_t)hh * S + mb + r) * 32 + d] = (_Float16)(acc[j][r] + bb);
        } else {
            f16x4 pk;
#pragma unroll
            for (int r = 0; r < 4; r++) pk[r] = (_Float16)(acc[j][r] + bb);
            *(f16x4*)&vt[(size_t)n * S + mb] = pk;
        }
    }
}

// ---------------------------------------------------------------------------
// QKV GEMM with fused FFN-merge + LN2 A-stage (layers 1,2). A-tile built from
// 8 W2 partials + b2 + residual(x1, post-LN1) -> LN2 -> Ah. by==0 writes the
// fp32 post-LN2 to x0 (residual for this layer's wo_ln_merge).
// ---------------------------------------------------------------------------
__global__ __launch_bounds__(256) void gemm_qkv_merge(
    const _Float16* __restrict__ wpart, const float* __restrict__ x1,
    const float* __restrict__ b2, const float* __restrict__ g2,
    const float* __restrict__ bn2, float* __restrict__ x0,
    const _Float16* __restrict__ Wh, const float* __restrict__ bias,
    _Float16* __restrict__ qh, _Float16* __restrict__ kh,
    _Float16* __restrict__ vt)
{
    __shared__ _Float16 Ah[16][128], Bh[128][128];
    int tid = threadIdx.x, w = tid >> 6, l = tid & 63, lc = l & 15, lr = l >> 4;
    int m0 = blockIdx.x * 16, by = blockIdx.y;

    stageGL<128>(Bh, Wh, 128, by * 128, 0, tid);   // B in flight during merge
    {   // merge 8 W2-partials + b2 + residual + LN2 -> Ah (16 x 128)
        int row = tid >> 4, qg = tid & 15, col0 = qg * 8;
        int q = m0 + row;
        float am[8];
#pragma unroll
        for (int e = 0; e < 8; e++) am[e] = 0.f;
#pragma unroll
        for (int s = 0; s < 8; s++) {
            f16x8 t = *(const f16x8*)&wpart[(size_t)s * 524288 + (size_t)q * 128 + col0];
#pragma unroll
            for (int e = 0; e < 8; e++) am[e] += (float)t[e];
        }
#pragma unroll
        for (int e = 0; e < 8; e++)
            am[e] += b2[col0 + e] + x1[(size_t)q * 128 + col0 + e];
        float s1 = 0.f, s2 = 0.f;
#pragma unroll
        for (int e = 0; e < 8; e++) { s1 += am[e]; s2 += am[e] * am[e]; }
#pragma unroll
        for (int off = 1; off < 16; off <<= 1) {   // row = aligned 16-lane group
            s1 += __shfl_xor(s1, off);
            s2 += __shfl_xor(s2, off);
        }
        float mean = s1 * (1.0f / 128.0f);
        float var = s2 * (1.0f / 128.0f) - mean * mean;
        float inv = rsqrtf(var + 1e-5f);
        float o[8];
        f16x8 hv;
#pragma unroll
        for (int e = 0; e < 8; e++) {
            o[e] = (am[e] - mean) * inv * g2[col0 + e] + bn2[col0 + e];
            hv[e] = (_Float16)o[e];
        }
        *(f16x8*)&Ah[row][(qg ^ (row & 15)) << 3] = hv;
        if (by == 0) {
            float4 v0 = {o[0], o[1], o[2], o[3]};
            float4 v1 = {o[4], o[5], o[6], o[7]};
            *(float4*)&x0[(size_t)q * 128 + col0]     = v0;
            *(float4*)&x0[(size_t)q * 128 + col0 + 4] = v1;
        }
    }
    __syncthreads();

    f32x4 acc[2];
#pragma unroll
    for (int j = 0; j < 2; j++) acc[j] = {0.f, 0.f, 0.f, 0.f};
#pragma unroll
    for (int ks = 0; ks < 4; ks++) {
        f16x8 af = rdS(Ah, lc, ks * 4 + lr);
#pragma unroll
        for (int j = 0; j < 2; j++) {
            f16x8 bf = rdS(Bh, w * 32 + j * 16 + lc, ks * 4 + lr);
            acc[j] = __builtin_amdgcn_mfma_f32_16x16x32_f16(af, bf, acc[j], 0, 0, 0);
        }
    }

    int mb = m0 + lr * 4;
#pragma unroll
    for (int j = 0; j < 2; j++) {
        int n = w * 32 + j * 16 + lc;
        float bb = bias[by * 128 + n];
        if (by == 0) {
#pragma unroll
            for (int r = 0; r < 4; r++)
                qh[(size_t)(mb + r) * 128 + n] =
                    (_Float16)((acc[j][r] + bb) * (QK_SCALE * LOG2E));
        } else if (by == 1) {
            int hh = n >> 5, d = n & 31;
#pragma unroll
            for (int r = 0; r < 4; r++)
                kh[((size_t)hh * S + mb + r) * 32 + d] = (_Float16)(acc[j][r] + bb);
        } else {
            f16x4 pk;
#pragma unroll
            for (int r = 0; r < 4; r++) pk[r] = (_Float16)(acc[j][r] + bb);
            *(f16x4*)&vt[(size_t)n * S + mb] = pk;
        }
    }
}

// ---------------------------------------------------------------------------
// MFMA flash attention: K/V double-buffer, async-split staging, one barrier
// per tile; swapped QK^T. R18: f16x4 Ps writes; l-sum via ones-column MFMA
// (ol accumulates row-sums of f16 P on the matrix pipe).
// ---------------------------------------------------------------------------
__global__ __launch_bounds__(256) void attn_mfma(const _Float16* __restrict__ qh,
                                                 const _Float16* __restrict__ kh,
                                                 const _Float16* __restrict__ vt,
                                                 _Float16* __restrict__ part,
                                                 float* __restrict__ mll)
{
    __shared__ _Float16 Ks[2][64][32];
    __shared__ _Float16 Vt[2][32][72];
    __shared__ _Float16 Ps[4][16][72];
    int h = blockIdx.y, q0 = blockIdx.x * 64, z = blockIdx.z;
    int tid = threadIdx.x;
    int w = tid >> 6, l = tid & 63;
    int lc = l & 15, lr = l >> 4;

    f16x8 qf = *(const f16x8*)&qh[(size_t)(q0 + w * 16 + lc) * 128 + h * 32 + lr * 8];

    const _Float16* khh = kh + (size_t)h * S * 32;
    const _Float16* vth = vt + (size_t)h * 32 * S;

    int krow = tid >> 2, kcol = (tid & 3) * 8;
    int vrow = tid >> 3, vcol = (tid & 7) * 8;

    f32x4 o0 = {0.f, 0.f, 0.f, 0.f}, o1 = {0.f, 0.f, 0.f, 0.f};
    f32x4 ol = {0.f, 0.f, 0.f, 0.f};
    f16x8 vone = {(_Float16)1.f, (_Float16)1.f, (_Float16)1.f, (_Float16)1.f,
                  (_Float16)1.f, (_Float16)1.f, (_Float16)1.f, (_Float16)1.f};

    int k0 = z * KS;
    {   // prologue: stage tile 0
        f16x8 kr = *(const f16x8*)&khh[(size_t)(k0 + krow) * 32 + kcol];
        f16x8 vr = *(const f16x8*)&vth[(size_t)vrow * S + k0 + vcol];
        *(f16x8*)&Ks[0][krow][kcol] = kr;
        *(f16x8*)&Vt[0][vrow][vcol] = vr;
    }
    __syncthreads();

    int cur = 0;
#pragma unroll 1
    for (int t8 = 0; t8 < KS / 64; t8++) {
        bool more = (t8 + 1 < KS / 64);
        f16x8 kr, vr;
        if (more) {   // issue next tile's loads early; latency hides under compute
            int kn = k0 + (t8 + 1) * 64;
            kr = *(const f16x8*)&khh[(size_t)(kn + krow) * 32 + kcol];
            vr = *(const f16x8*)&vth[(size_t)vrow * S + kn + vcol];
        }

        f32x4 st[4];
        __builtin_amdgcn_s_setprio(1);
#pragma unroll
        for (int t = 0; t < 4; t++) {
            f16x8 kf = *(const f16x8*)&Ks[cur][t * 16 + lc][lr * 8];
            f32x4 zz = {0.f, 0.f, 0.f, 0.f};
            st[t] = __builtin_amdgcn_mfma_f32_16x16x32_f16(kf, qf, zz, 0, 0, 0);
        }
        __builtin_amdgcn_s_setprio(0);
#pragma unroll
        for (int t = 0; t < 4; t++) {
            float p0 = exp2f(st[t][0]), p1 = exp2f(st[t][1]);
            float p2 = exp2f(st[t][2]), p3 = exp2f(st[t][3]);
            f16x4 pk = {(_Float16)p0, (_Float16)p1, (_Float16)p2, (_Float16)p3};
            *(f16x4*)&Ps[w][lc][t * 16 + lr * 4] = pk;
        }
        asm volatile("s_waitcnt lgkmcnt(0)" ::: "memory");
        __builtin_amdgcn_s_setprio(1);
#pragma unroll
        for (int ch = 0; ch < 2; ch++) {
            f16x8 pf = *(const f16x8*)&Ps[w][lc][ch * 32 + lr * 8];
            f16x8 v0 = *(const f16x8*)&Vt[cur][lc][ch * 32 + lr * 8];
            f16x8 v1 = *(const f16x8*)&Vt[cur][16 + lc][ch * 32 + lr * 8];
            o0 = __builtin_amdgcn_mfma_f32_16x16x32_f16(pf, v0, o0, 0, 0, 0);
            o1 = __builtin_amdgcn_mfma_f32_16x16x32_f16(pf, v1, o1, 0, 0, 0);
            ol = __builtin_amdgcn_mfma_f32_16x16x32_f16(pf, vone, ol, 0, 0, 0);
        }
        __builtin_amdgcn_s_setprio(0);
        if (more) {
            *(f16x8*)&Ks[cur ^ 1][krow][kcol] = kr;
            *(f16x8*)&Vt[cur ^ 1][vrow][vcol] = vr;
            __syncthreads();
        }
        cur ^= 1;
    }

    _Float16* pz = part + (size_t)z * 524288;
#pragma unroll
    for (int i = 0; i < 4; i++) {
        int q = q0 + w * 16 + lr * 4 + i;
        pz[(size_t)q * 128 + h * 32 + lc]      = (_Float16)o0[i];
        pz[(size_t)q * 128 + h * 32 + 16 + lc] = (_Float16)o1[i];
        if (lc == 0) mll[((size_t)z * 4 + h) * 4096 + q] = ol[i];
    }
}

// ---------------------------------------------------------------------------
// Wo GEMM + split-attention merge + residual(x0) + LN1 -> x1 (fp32), xh (f16).
// 16-row tiles, glds B staging; merge-A written with element swizzle.
// ---------------------------------------------------------------------------
__global__ __launch_bounds__(256) void wo_ln_merge(const _Float16* __restrict__ part,
                                                   const float* __restrict__ mll,
                                                   const _Float16* __restrict__ Wh,
                                                   const float* __restrict__ bias,
                                                   const float* __restrict__ xres,
                                                   float* __restrict__ xo,
                                                   _Float16* __restrict__ xh,
                                                   const float* __restrict__ g,
                                                   const float* __restrict__ b)
{
    __shared__ _Float16 Ah[16][128], Bh[128][128];
    __shared__ float Red[16][4][2];
    int tid = threadIdx.x, w = tid >> 6, l = tid & 63, lc = l & 15, lr = l >> 4;
    int m0 = blockIdx.x * 16;

    stageGL<128>(Bh, Wh, 128, 0, 0, tid);
    {   // merge-stage A: 16 rows x 128 cols, 8 cols/thread (granule-aligned)
        int row = tid >> 4, qg = tid & 15;
        int col0 = qg * 8;
        int q = m0 + row, hh = col0 >> 5;
        float lsum = 0.f;
#pragma unroll
        for (int s = 0; s < SPLIT; s++) lsum += mll[((size_t)s * 4 + hh) * 4096 + q];
        float am[8];
#pragma unroll
        for (int e = 0; e < 8; e++) am[e] = 0.f;
#pragma unroll
        for (int s = 0; s < SPLIT; s++) {
            f16x8 t = *(const f16x8*)&part[(size_t)s * 524288 + (size_t)q * 128 + col0];
#pragma unroll
            for (int e = 0; e < 8; e++) am[e] += (float)t[e];
        }
        float inv = 1.f / lsum;
        f16x8 hv;
#pragma unroll
        for (int e = 0; e < 8; e++) hv[e] = (_Float16)(am[e] * inv);
        *(f16x8*)&Ah[row][(qg ^ (row & 15)) << 3] = hv;   // swizzled slot
    }
    __syncthreads();

    f32x4 acc[2];
#pragma unroll
    for (int j = 0; j < 2; j++) acc[j] = {0.f, 0.f, 0.f, 0.f};
#pragma unroll
    for (int ks = 0; ks < 4; ks++) {
        f16x8 af = rdS(Ah, lc, ks * 4 + lr);
#pragma unroll
        for (int j = 0; j < 2; j++) {
            f16x8 bf = rdS(Bh, w * 32 + j * 16 + lc, ks * 4 + lr);
            acc[j] = __builtin_amdgcn_mfma_f32_16x16x32_f16(af, bf, acc[j], 0, 0, 0);
        }
    }

#pragma unroll
    for (int j = 0; j < 2; j++) {
        int n = w * 32 + j * 16 + lc;
        float bb = bias[n];
#pragma unroll
        for (int r = 0; r < 4; r++)
            acc[j][r] += bb + xres[(size_t)(m0 + lr * 4 + r) * 128 + n];
    }
#pragma unroll
    for (int r = 0; r < 4; r++) {
        float s1 = acc[0][r] + acc[1][r];
        float s2 = acc[0][r] * acc[0][r] + acc[1][r] * acc[1][r];
#pragma unroll
        for (int off = 1; off < 16; off <<= 1) {
            s1 += __shfl_xor(s1, off);
            s2 += __shfl_xor(s2, off);
        }
        if (lc == 0) { Red[lr * 4 + r][w][0] = s1; Red[lr * 4 + r][w][1] = s2; }
    }
    __syncthreads();
#pragma unroll
    for (int r = 0; r < 4; r++) {
        int rl = lr * 4 + r;
        float S1 = (Red[rl][0][0] + Red[rl][1][0]) + (Red[rl][2][0] + Red[rl][3][0]);
        float S2 = (Red[rl][0][1] + Red[rl][1][1]) + (Red[rl][2][1] + Red[rl][3][1]);
        float mean = S1 * (1.0f / 128.0f);
        float var = S2 * (1.0f / 128.0f) - mean * mean;
        float inv = rsqrtf(var + 1e-5f);
        int m = m0 + rl;
#pragma unroll
        for (int j = 0; j < 2; j++) {
            int n = w * 32 + j * 16 + lc;
            float o = (acc[j][r] - mean) * inv * g[n] + b[n];
            xo[(size_t)m * 128 + n] = o;
            xh[(size_t)m * 128 + n] = (_Float16)o;
        }
    }
}

// ---------------------------------------------------------------------------
// Fused W1+W2 pair, 64-row tiles, grid (64, 8) = 512 blocks, glds staging.
// relu(F) written back into Ah with element swizzle.
// ---------------------------------------------------------------------------
__global__ __launch_bounds__(256) void ffn_pair(const _Float16* __restrict__ xh,
                                                const _Float16* __restrict__ W1h,
                                                const float* __restrict__ b1,
                                                const _Float16* __restrict__ W2h,
                                                _Float16* __restrict__ wpart)
{
    __shared__ _Float16 Ah[64][128], Bh[128][128];
    int tid = threadIdx.x, w = tid >> 6, l = tid & 63, lc = l & 15, lr = l >> 4;
    int wr = w >> 1, wc = w & 1;
    int m0 = blockIdx.x * 64, c = blockIdx.y;

    stageGL<64>(Ah, xh, 128, m0, 0, tid);
    stageGL<128>(Bh, W1h, 128, c * 128, 0, tid);
    __syncthreads();

    f32x4 acc[2][4];
#pragma unroll
    for (int i = 0; i < 2; i++)
#pragma unroll
        for (int j = 0; j < 4; j++) acc[i][j] = {0.f, 0.f, 0.f, 0.f};
#pragma unroll
    for (int ks = 0; ks < 4; ks++) {
        f16x8 af0 = rdS(Ah, wr * 32 + lc, ks * 4 + lr);
        f16x8 af1 = rdS(Ah, wr * 32 + 16 + lc, ks * 4 + lr);
#pragma unroll
        for (int j = 0; j < 4; j++) {
            f16x8 bf = rdS(Bh, wc * 64 + j * 16 + lc, ks * 4 + lr);
            acc[0][j] = __builtin_amdgcn_mfma_f32_16x16x32_f16(af0, bf, acc[0][j], 0, 0, 0);
            acc[1][j] = __builtin_amdgcn_mfma_f32_16x16x32_f16(af1, bf, acc[1][j], 0, 0, 0);
        }
    }
    __syncthreads();   // all pass-1 reads of Ah/Bh done

    // relu + bias -> F (into Ah, swizzled element writes)
#pragma unroll
    for (int i = 0; i < 2; i++)
#pragma unroll
        for (int j = 0; j < 4; j++) {
            int n = wc * 64 + j * 16 + lc;
            float bb = b1[c * 128 + n];
#pragma unroll
            for (int r = 0; r < 4; r++)
                wrS(Ah, wr * 32 + i * 16 + lr * 4 + r, n,
                    (_Float16)fmaxf(acc[i][j][r] + bb, 0.f));
        }
    stageGL<128>(Bh, W2h, 1024, 0, c * 128, tid);
    __syncthreads();

    f32x4 oacc[2][4];
#pragma unroll
    for (int i = 0; i < 2; i++)
#pragma unroll
        for (int j = 0; j < 4; j++) oacc[i][j] = {0.f, 0.f, 0.f, 0.f};
#pragma unroll
    for (int ks = 0; ks < 4; ks++) {
        f16x8 af0 = rdS(Ah, wr * 32 + lc, ks * 4 + lr);
        f16x8 af1 = rdS(Ah, wr * 32 + 16 + lc, ks * 4 + lr);
#pragma unroll
        for (int j = 0; j < 4; j++) {
            f16x8 bf = rdS(Bh, wc * 64 + j * 16 + lc, ks * 4 + lr);
            oacc[0][j] = __builtin_amdgcn_mfma_f32_16x16x32_f16(af0, bf, oacc[0][j], 0, 0, 0);
            oacc[1][j] = __builtin_amdgcn_mfma_f32_16x16x32_f16(af1, bf, oacc[1][j], 0, 0, 0);
        }
    }

    _Float16* pz = wpart + (size_t)c * 524288;
#pragma unroll
    for (int i = 0; i < 2; i++) {
        int mb = m0 + wr * 32 + i * 16 + lr * 4;
#pragma unroll
        for (int j = 0; j < 4; j++) {
            int n = wc * 64 + j * 16 + lc;
#pragma unroll
            for (int r = 0; r < 4; r++)
                pz[(size_t)(mb + r) * 128 + n] = (_Float16)oacc[i][j][r];
        }
    }
}

// ---------------------------------------------------------------------------
// fc1 + relu + fc2 + rownorm fused, with fused FFN-merge + LN2 A-stage
// (layer 2). 16-row tiles, grid 256, glds staging for weights.
// ---------------------------------------------------------------------------
__global__ __launch_bounds__(256) void fc_fused(const _Float16* __restrict__ wpart,
                                                const float* __restrict__ x1,
                                                const float* __restrict__ b2l,
                                                const float* __restrict__ g2,
                                                const float* __restrict__ bn2,
                                                const _Float16* __restrict__ W1h,
                                                const float* __restrict__ b1f,
                                                const _Float16* __restrict__ W2h,
                                                const float* __restrict__ b2f,
                                                _Float16* __restrict__ aoh)
{
    __shared__ _Float16 Ah[16][128], Bh[128][128];
    __shared__ float Red[16][4];
    int tid = threadIdx.x, w = tid >> 6, l = tid & 63, lc = l & 15, lr = l >> 4;
    int m0 = blockIdx.x * 16;

    stageGL<128>(Bh, W1h, 128, 0, 0, tid);
    {   // merge 8 W2-partials + b2 + residual + LN2 -> Ah
        int row = tid >> 4, qg = tid & 15, col0 = qg * 8;
        int q = m0 + row;
        float am[8];
#pragma unroll
        for (int e = 0; e < 8; e++) am[e] = 0.f;
#pragma unroll
        for (int s = 0; s < 8; s++) {
            f16x8 t = *(const f16x8*)&wpart[(size_t)s * 524288 + (size_t)q * 128 + col0];
#pragma unroll
            for (int e = 0; e < 8; e++) am[e] += (float)t[e];
        }
#pragma unroll
        for (int e = 0; e < 8; e++)
            am[e] += b2l[col0 + e] + x1[(size_t)q * 128 + col0 + e];
        float s1 = 0.f, s2 = 0.f;
#pragma unroll
        for (int e = 0; e < 8; e++) { s1 += am[e]; s2 += am[e] * am[e]; }
#pragma unroll
        for (int off = 1; off < 16; off <<= 1) {
            s1 += __shfl_xor(s1, off);
            s2 += __shfl_xor(s2, off);
        }
        float mean = s1 * (1.0f / 128.0f);
        float var = s2 * (1.0f / 128.0f) - mean * mean;
        float inv = rsqrtf(var + 1e-5f);
        f16x8 hv;
#pragma unroll
        for (int e = 0; e < 8; e++)
            hv[e] = (_Float16)((am[e] - mean) * inv * g2[col0 + e] + bn2[col0 + e]);
        *(f16x8*)&Ah[row][(qg ^ (row & 15)) << 3] = hv;
    }
    __syncthreads();

    f32x4 acc[2];
#pragma unroll
    for (int j = 0; j < 2; j++) acc[j] = {0.f, 0.f, 0.f, 0.f};
#pragma unroll
    for (int ks = 0; ks < 4; ks++) {
        f16x8 af = rdS(Ah, lc, ks * 4 + lr);
#pragma unroll
        for (int j = 0; j < 2; j++) {
            f16x8 bf = rdS(Bh, w * 32 + j * 16 + lc, ks * 4 + lr);
            acc[j] = __builtin_amdgcn_mfma_f32_16x16x32_f16(af, bf, acc[j], 0, 0, 0);
        }
    }
    __syncthreads();   // pass-1 reads done
#pragma unroll
    for (int j = 0; j < 2; j++) {
        int n = w * 32 + j * 16 + lc;
        float bb = b1f[n];
#pragma unroll
        for (int r = 0; r < 4; r++)
            wrS(Ah, lr * 4 + r, n, (_Float16)fmaxf(acc[j][r] + bb, 0.f));
    }
    stageGL<128>(Bh, W2h, 128, 0, 0, tid);
    __syncthreads();

    f32x4 o[2];
#pragma unroll
    for (int j = 0; j < 2; j++) o[j] = {0.f, 0.f, 0.f, 0.f};
#pragma unroll
    for (int ks = 0; ks < 4; ks++) {
        f16x8 af = rdS(Ah, lc, ks * 4 + lr);
#pragma unroll
        for (int j = 0; j < 2; j++) {
            f16x8 bf = rdS(Bh, w * 32 + j * 16 + lc, ks * 4 + lr);
            o[j] = __builtin_amdgcn_mfma_f32_16x16x32_f16(af, bf, o[j], 0, 0, 0);
        }
    }
#pragma unroll
    for (int j = 0; j < 2; j++) {
        float bb = b2f[w * 32 + j * 16 + lc];
#pragma unroll
        for (int r = 0; r < 4; r++) o[j][r] += bb;
    }
#pragma unroll
    for (int r = 0; r < 4; r++) {
        float s2 = o[0][r] * o[0][r] + o[1][r] * o[1][r];
#pragma unroll
        for (int off = 1; off < 16; off <<= 1) s2 += __shfl_xor(s2, off);
        if (lc == 0) Red[lr * 4 + r][w] = s2;
    }
    __syncthreads();
#pragma unroll
    for (int r = 0; r < 4; r++) {
        int rl = lr * 4 + r;
        float inv = rsqrtf((Red[rl][0] + Red[rl][1]) + (Red[rl][2] + Red[rl][3]));
        int m = m0 + rl;
#pragma unroll
        for (int j = 0; j < 2; j++) {
            int n = w * 32 + j * 16 + lc;
            aoh[(size_t)m * 128 + n] = (_Float16)(o[j][r] * inv);
        }
    }
}

// ---------------------------------------------------------------------------
// Gram: C = max(aoh @ aoh^T, 1e-6). 64x128 tiles, glds staging,
// grid (64, 32) = 2048 blocks.
// ---------------------------------------------------------------------------
__global__ __launch_bounds__(256) void gram_f16(const _Float16* __restrict__ aoh,
                                                float* __restrict__ C)
{
    __shared__ _Float16 Ah[64][128], Bh[128][128];
    int tid = threadIdx.x, w = tid >> 6, l = tid & 63, lc = l & 15, lr = l >> 4;
    int wr = w >> 1, wc = w & 1;
    int m0 = blockIdx.x * 64, n0 = blockIdx.y * 128;

    stageGL<64>(Ah, aoh, 128, m0, 0, tid);
    stageGL<128>(Bh, aoh, 128, n0, 0, tid);
    __syncthreads();

    f32x4 acc[2][4];
#pragma unroll
    for (int i = 0; i < 2; i++)
#pragma unroll
        for (int j = 0; j < 4; j++) acc[i][j] = {0.f, 0.f, 0.f, 0.f};
#pragma unroll
    for (int ks = 0; ks < 4; ks++) {
        f16x8 af0 = rdS(Ah, wr * 32 + lc, ks * 4 + lr);
        f16x8 af1 = rdS(Ah, wr * 32 + 16 + lc, ks * 4 + lr);
#pragma unroll
        for (int j = 0; j < 4; j++) {
            f16x8 bf = rdS(Bh, wc * 64 + j * 16 + lc, ks * 4 + lr);
            acc[0][j] = __builtin_amdgcn_mfma_f32_16x16x32_f16(af0, bf, acc[0][j], 0, 0, 0);
            acc[1][j] = __builtin_amdgcn_mfma_f32_16x16x32_f16(af1, bf, acc[1][j], 0, 0, 0);
        }
    }

#pragma unroll
    for (int i = 0; i < 2; i++) {
        int mb = m0 + wr * 32 + i * 16 + lr * 4;
#pragma unroll
        for (int j = 0; j < 4; j++) {
            int n = n0 + wc * 64 + j * 16 + lc;
#pragma unroll
            for (int r = 0; r < 4; r++)
                C[(size_t)(mb + r) * 4096 + n] = fmaxf(acc[i][j][r], 1e-6f);
        }
    }
}

// ---------------------------------------------------------------------------
extern "C" void kernel_launch(void* const* d_in, const int* in_sizes, int n_in,
                              void* d_out, int out_size, void* d_ws, size_t ws_size,
                              hipStream_t stream)
{
    const float* src  = (const float*)d_in[0];
    const float* Wqkv = (const float*)d_in[1];
    const float* bqkv = (const float*)d_in[2];
    const float* Wo   = (const float*)d_in[3];
    const float* bo   = (const float*)d_in[4];
    const float* ln1g = (const float*)d_in[5];
    const float* ln1b = (const float*)d_in[6];
    const float* W1   = (const float*)d_in[7];
    const float* b1   = (const float*)d_in[8];
    const float* W2   = (const float*)d_in[9];
    const float* b2   = (const float*)d_in[10];
    const float* ln2g = (const float*)d_in[11];
    const float* ln2b = (const float*)d_in[12];
    const float* fc1W = (const float*)d_in[13];
    const float* fc1b = (const float*)d_in[14];
    const float* fc2W = (const float*)d_in[15];
    const float* fc2b = (const float*)d_in[16];

    float* ws = (float*)d_ws;
    float*    x   = ws;                                   // 524288 f32 (post-LN2 chain)
    _Float16* xh  = (_Float16*)(ws + 524288);             // 524288 f16 (post-LN1 / init)
    _Float16* aoh = (_Float16*)(ws + 786432);             // 524288 f16
    _Float16* qh  = (_Float16*)(ws + 1048576);            // 524288 f16
    _Float16* kh  = (_Float16*)(ws + 1310720);            // 524288 f16
    _Float16* vt  = (_Float16*)(ws + 1572864);            // 524288 f16
    float*    mll = ws + 1835008;                         // 131072 f32

    // d_out scratch (all dead before gram writes):
    _Float16* wpart = (_Float16*)d_out + 4194304;         // bytes [ 8MiB,16MiB)
    _Float16* apart = (_Float16*)d_out + 12582912;        // bytes [24MiB,32MiB)
    _Float16* wh    = (_Float16*)d_out + 16777216;        // bytes [32MiB,~34MiB)
    float*    x1    = (float*)d_out + 9437184;            // bytes [36MiB,38MiB) post-LN1
    float*    out   = (float*)d_out;

    _Float16* qkvh = wh;                  // 3 x 384 x 128
    _Float16* woh  = wh + 147456;         // 3 x 128 x 128
    _Float16* w1h  = wh + 196608;         // 3 x 1024 x 128
    _Float16* w2h  = wh + 589824;         // 3 x 128 x 1024
    _Float16* fc1h = wh + 983040;         // 128 x 128
    _Float16* fc2h = wh + 999424;         // 128 x 128

    setup_cvt<<<1504, 256, 0, stream>>>(Wqkv, Wo, W1, W2, fc1W, fc2W, wh,
                                        src, x, xh);
    // layer 0
    gemm_qkv<<<dim3(256, 3), 256, 0, stream>>>(xh, qkvh, bqkv, qh, kh, vt);
    attn_mfma<<<dim3(64, 4, SPLIT), 256, 0, stream>>>(qh, kh, vt, apart, mll);
    wo_ln_merge<<<256, 256, 0, stream>>>(apart, mll, woh, bo, x, x1, xh,
                                         ln1g, ln1b);
    ffn_pair<<<dim3(64, 8), 256, 0, stream>>>(xh, w1h, b1, w2h, wpart);
    // layers 1, 2: QKV with fused FFN-merge + LN2 of previous layer
    for (int l = 1; l < 3; l++) {
        gemm_qkv_merge<<<dim3(256, 3), 256, 0, stream>>>(
            wpart, x1, b2 + (l - 1) * 128, ln2g + (l - 1) * 128,
            ln2b + (l - 1) * 128, x,
            qkvh + l * 49152, bqkv + l * 384, qh, kh, vt);
        attn_mfma<<<dim3(64, 4, SPLIT), 256, 0, stream>>>(qh, kh, vt, apart, mll);
        wo_ln_merge<<<256, 256, 0, stream>>>(apart, mll, woh + l * 16384,
                                             bo + l * 128, x, x1, xh,
                                             ln1g + l * 128, ln1b + l * 128);
        ffn_pair<<<dim3(64, 8), 256, 0, stream>>>(xh, w1h + l * 131072,
                                                  b1 + l * 1024,
                                                  w2h + l * 131072, wpart);
    }
    // fc chain with fused FFN-merge + LN2 of layer 2
    fc_fused<<<256, 256, 0, stream>>>(wpart, x1, b2 + 256, ln2g + 256,
                                      ln2b + 256, fc1h, fc1b, fc2h, fc2b, aoh);
    gram_f16<<<dim3(64, 32), 256, 0, stream>>>(aoh, out);
}

// Round 10
// 257.027 us; speedup vs baseline: 1.0695x; 1.0107x over previous
//
#include <hip/hip_runtime.h>
#include <math.h>

#define S 4096
#define QK_SCALE 0.17677669529663687f  // 1/sqrt(32)
#define LOG2E    1.44269504088896f
#define SPLIT 4
#define KS (S / SPLIT)                 // 1024 keys per split

typedef _Float16 f16x8 __attribute__((ext_vector_type(8)));
typedef _Float16 f16x4 __attribute__((ext_vector_type(4)));
typedef _Float16 f16x2 __attribute__((ext_vector_type(2)));
typedef float f32x4 __attribute__((ext_vector_type(4)));

// ---------------------------------------------------------------------------
// MFMA lane map (HW-verified R4): A-frag m=l&15, k=(l>>4)*8+j; B-frag n=l&15;
// C reg r: row=(l>>4)*4+r, col=l&15.
// R19: base = R9 (259.8us best). ONE change: attn SPLIT 8->4, ISOLATED this
// time (R3 bundled it with the layer_tail regression). Mechanism: SPLIT=8 ->
// 2048 blocks at ~6/CU resident = ragged ~33% second pass; SPLIT=4 -> 1024
// blocks at 4/CU exactly co-resident (tail-free), 16 dbuf'd tiles/block,
// and wo_ln's merge reads 4 partials not 8. If this regresses, SPLIT=8 TLP
// is confirmed optimal and ~260us is the practical plateau.
// Staging: global_load_lds 16B direct-to-LDS, source-granule XOR swizzle
// (g ^= row&15) + same XOR on reads (both-sides involution, 2 lanes/bank).
// ---------------------------------------------------------------------------

// direct-to-LDS stage of ROWS x 128 f16 tile, linear [128] stride, source
// granule-swizzled so a swizzled read recovers logical layout.
template<int ROWS>
__device__ __forceinline__ void stageGL(_Float16 (*dst)[128], const _Float16* src,
                                        int ld, int row0, int col0, int tid) {
    int w = tid >> 6, l = tid & 63;
    constexpr int NISS = ROWS / 16;         // wave-issues per wave (4 waves)
#pragma unroll
    for (int v = 0; v < NISS; v++) {
        int G = (w * NISS + v) * 64 + l;    // linear granule id
        int row = G >> 4, g = G & 15;
        int gs = g ^ (row & 15);            // swizzled source granule
        const void* gp = src + (size_t)(row0 + row) * ld + col0 + gs * 8;
        void* lp = (char*)&dst[0][0] + (size_t)G * 16;
        __builtin_amdgcn_global_load_lds(
            (const __attribute__((address_space(1))) void*)gp,
            (__attribute__((address_space(3))) void*)lp, 16, 0, 0);
    }
}

// swizzled 16B fragment read: logical granule qg of row
__device__ __forceinline__ f16x8 rdS(const _Float16 (*B)[128], int row, int qg) {
    return *(const f16x8*)&B[row][(qg ^ (row & 15)) << 3];
}
// swizzled element write (for register-computed tiles)
__device__ __forceinline__ void wrS(_Float16 (*B)[128], int row, int col, _Float16 v) {
    B[row][((((col >> 3) ^ (row & 15))) << 3) | (col & 7)] = v;
}

// ---------------------------------------------------------------------------
// setup: weight fp32->fp16 conversion (blocks 0..991) + x/xh copy (992..1503).
// ---------------------------------------------------------------------------
__global__ __launch_bounds__(256) void setup_cvt(const float* __restrict__ q,
                                                 const float* __restrict__ wo,
                                                 const float* __restrict__ w1,
                                                 const float* __restrict__ w2,
                                                 const float* __restrict__ f1,
                                                 const float* __restrict__ f2,
                                                 _Float16* __restrict__ dst,
                                                 const float* __restrict__ a,
                                                 float* __restrict__ x,
                                                 _Float16* __restrict__ xh)
{
    int bb = blockIdx.x;
    if (bb < 992) {
        const float* src; size_t dof; int lb;
        if (bb < 144)      { src = q;  dof = 0;      lb = bb; }
        else if (bb < 192) { src = wo; dof = 147456; lb = bb - 144; }
        else if (bb < 576) { src = w1; dof = 196608; lb = bb - 192; }
        else if (bb < 960) { src = w2; dof = 589824; lb = bb - 576; }
        else if (bb < 976) { src = f1; dof = 983040; lb = bb - 960; }
        else               { src = f2; dof = 999424; lb = bb - 976; }
        int i = lb * 1024 + threadIdx.x * 4;
        float4 v = *(const float4*)(src + i);
        f16x4 h = {(_Float16)v.x, (_Float16)v.y, (_Float16)v.z, (_Float16)v.w};
        *(f16x4*)(dst + dof + i) = h;
    } else {
        int i = (bb - 992) * 256 + threadIdx.x;
        float4 v = ((const float4*)a)[i];
        ((float4*)x)[i] = v;
        f16x4 h = {(_Float16)v.x, (_Float16)v.y, (_Float16)v.z, (_Float16)v.w};
        ((f16x4*)xh)[i] = h;
    }
}

// ---------------------------------------------------------------------------
// QKV GEMM (layer 0), 16-row tiles, full-K single barrier, glds staging.
// grid (256, 3): by=0 -> qh (scaled), by=1 -> kh, by=2 -> vt (transposed).
// ---------------------------------------------------------------------------
__global__ __launch_bounds__(256) void gemm_qkv(const _Float16* __restrict__ xh,
                                                const _Float16* __restrict__ Wh,
                                                const float* __restrict__ bias,
                                                _Float16* __restrict__ qh,
                                                _Float16* __restrict__ kh,
                                                _Float16* __restrict__ vt)
{
    __shared__ _Float16 Ah[16][128], Bh[128][128];
    int tid = threadIdx.x, w = tid >> 6, l = tid & 63, lc = l & 15, lr = l >> 4;
    int m0 = blockIdx.x * 16, by = blockIdx.y;

    stageGL<16>(Ah, xh, 128, m0, 0, tid);
    stageGL<128>(Bh, Wh, 128, by * 128, 0, tid);
    __syncthreads();

    f32x4 acc[2];
#pragma unroll
    for (int j = 0; j < 2; j++) acc[j] = {0.f, 0.f, 0.f, 0.f};
#pragma unroll
    for (int ks = 0; ks < 4; ks++) {
        f16x8 af = rdS(Ah, lc, ks * 4 + lr);
#pragma unroll
        for (int j = 0; j < 2; j++) {
            f16x8 bf = rdS(Bh, w * 32 + j * 16 + lc, ks * 4 + lr);
            acc[j] = __builtin_amdgcn_mfma_f32_16x16x32_f16(af, bf, acc[j], 0, 0, 0);
        }
    }

    int mb = m0 + lr * 4;
#pragma unroll
    for (int j = 0; j < 2; j++) {
        int n = w * 32 + j * 16 + lc;
        float bb = bias[by * 128 + n];
        if (by == 0) {
#pragma unroll
            for (int r = 0; r < 4; r++)
                qh[(size_t)(mb + r) * 128 + n] =
                    (_Float16)((acc[j][r] + bb) * (QK_SCALE * LOG2E));
        } else if (by == 1) {
            int hh = n >> 5, d = n & 31;
#pragma unroll
            for (int r = 0; r < 4; r++)
                kh[((size_t)hh * S + mb + r) * 32 + d] = (_Float16)(acc[j][r] + bb);
        } else {
            f16x4 pk;
#pragma unroll
            for (int r = 0; r < 4; r++) pk[r] = (_Float16)(acc[j][r] + bb);
            *(f16x4*)&vt[(size_t)n * S + mb] = pk;
        }
    }
}

// ---------------------------------------------------------------------------
// QKV GEMM with fused FFN-merge + LN2 A-stage (layers 1,2). A-tile built from
// 8 W2 partials + b2 + residual(x1, post-LN1) -> LN2 -> Ah. by==0 writes the
// fp32 post-LN2 to x0 (residual for this layer's wo_ln_merge).
// ---------------------------------------------------------------------------
__global__ __launch_bounds__(256) void gemm_qkv_merge(
    const _Float16* __restrict__ wpart, const float* __restrict__ x1,
    const float* __restrict__ b2, const float* __restrict__ g2,
    const float* __restrict__ bn2, float* __restrict__ x0,
    const _Float16* __restrict__ Wh, const float* __restrict__ bias,
    _Float16* __restrict__ qh, _Float16* __restrict__ kh,
    _Float16* __restrict__ vt)
{
    __shared__ _Float16 Ah[16][128], Bh[128][128];
    int tid = threadIdx.x, w = tid >> 6, l = tid & 63, lc = l & 15, lr = l >> 4;
    int m0 = blockIdx.x * 16, by = blockIdx.y;

    stageGL<128>(Bh, Wh, 128, by * 128, 0, tid);   // B in flight during merge
    {   // merge 8 W2-partials + b2 + residual + LN2 -> Ah (16 x 128)
        int row = tid >> 4, qg = tid & 15, col0 = qg * 8;
        int q = m0 + row;
        float am[8];
#pragma unroll
        for (int e = 0; e < 8; e++) am[e] = 0.f;
#pragma unroll
        for (int s = 0; s < 8; s++) {
            f16x8 t = *(const f16x8*)&wpart[(size_t)s * 524288 + (size_t)q * 128 + col0];
#pragma unroll
            for (int e = 0; e < 8; e++) am[e] += (float)t[e];
        }
#pragma unroll
        for (int e = 0; e < 8; e++)
            am[e] += b2[col0 + e] + x1[(size_t)q * 128 + col0 + e];
        float s1 = 0.f, s2 = 0.f;
#pragma unroll
        for (int e = 0; e < 8; e++) { s1 += am[e]; s2 += am[e] * am[e]; }
#pragma unroll
        for (int off = 1; off < 16; off <<= 1) {   // row = aligned 16-lane group
            s1 += __shfl_xor(s1, off);
            s2 += __shfl_xor(s2, off);
        }
        float mean = s1 * (1.0f / 128.0f);
        float var = s2 * (1.0f / 128.0f) - mean * mean;
        float inv = rsqrtf(var + 1e-5f);
        float o[8];
        f16x8 hv;
#pragma unroll
        for (int e = 0; e < 8; e++) {
            o[e] = (am[e] - mean) * inv * g2[col0 + e] + bn2[col0 + e];
            hv[e] = (_Float16)o[e];
        }
        *(f16x8*)&Ah[row][(qg ^ (row & 15)) << 3] = hv;
        if (by == 0) {
            float4 v0 = {o[0], o[1], o[2], o[3]};
            float4 v1 = {o[4], o[5], o[6], o[7]};
            *(float4*)&x0[(size_t)q * 128 + col0]     = v0;
            *(float4*)&x0[(size_t)q * 128 + col0 + 4] = v1;
        }
    }
    __syncthreads();

    f32x4 acc[2];
#pragma unroll
    for (int j = 0; j < 2; j++) acc[j] = {0.f, 0.f, 0.f, 0.f};
#pragma unroll
    for (int ks = 0; ks < 4; ks++) {
        f16x8 af = rdS(Ah, lc, ks * 4 + lr);
#pragma unroll
        for (int j = 0; j < 2; j++) {
            f16x8 bf = rdS(Bh, w * 32 + j * 16 + lc, ks * 4 + lr);
            acc[j] = __builtin_amdgcn_mfma_f32_16x16x32_f16(af, bf, acc[j], 0, 0, 0);
        }
    }

    int mb = m0 + lr * 4;
#pragma unroll
    for (int j = 0; j < 2; j++) {
        int n = w * 32 + j * 16 + lc;
        float bb = bias[by * 128 + n];
        if (by == 0) {
#pragma unroll
            for (int r = 0; r < 4; r++)
                qh[(size_t)(mb + r) * 128 + n] =
                    (_Float16)((acc[j][r] + bb) * (QK_SCALE * LOG2E));
        } else if (by == 1) {
            int hh = n >> 5, d = n & 31;
#pragma unroll
            for (int r = 0; r < 4; r++)
                kh[((size_t)hh * S + mb + r) * 32 + d] = (_Float16)(acc[j][r] + bb);
        } else {
            f16x4 pk;
#pragma unroll
            for (int r = 0; r < 4; r++) pk[r] = (_Float16)(acc[j][r] + bb);
            *(f16x4*)&vt[(size_t)n * S + mb] = pk;
        }
    }
}

// ---------------------------------------------------------------------------
// MFMA flash attention: K/V double-buffer, async-split staging, one barrier
// per tile; swapped QK^T; f16x4 Ps writes; l-sum via ones-column MFMA.
// SPLIT=4: 1024 blocks, 4/CU co-resident, tail-free; 16 tiles/block.
// ---------------------------------------------------------------------------
__global__ __launch_bounds__(256) void attn_mfma(const _Float16* __restrict__ qh,
                                                 const _Float16* __restrict__ kh,
                                                 const _Float16* __restrict__ vt,
                                                 _Float16* __restrict__ part,
                                                 float* __restrict__ mll)
{
    __shared__ _Float16 Ks[2][64][32];
    __shared__ _Float16 Vt[2][32][72];
    __shared__ _Float16 Ps[4][16][72];
    int h = blockIdx.y, q0 = blockIdx.x * 64, z = blockIdx.z;
    int tid = threadIdx.x;
    int w = tid >> 6, l = tid & 63;
    int lc = l & 15, lr = l >> 4;

    f16x8 qf = *(const f16x8*)&qh[(size_t)(q0 + w * 16 + lc) * 128 + h * 32 + lr * 8];

    const _Float16* khh = kh + (size_t)h * S * 32;
    const _Float16* vth = vt + (size_t)h * 32 * S;

    int krow = tid >> 2, kcol = (tid & 3) * 8;
    int vrow = tid >> 3, vcol = (tid & 7) * 8;

    f32x4 o0 = {0.f, 0.f, 0.f, 0.f}, o1 = {0.f, 0.f, 0.f, 0.f};
    f32x4 ol = {0.f, 0.f, 0.f, 0.f};
    f16x8 vone = {(_Float16)1.f, (_Float16)1.f, (_Float16)1.f, (_Float16)1.f,
                  (_Float16)1.f, (_Float16)1.f, (_Float16)1.f, (_Float16)1.f};

    int k0 = z * KS;
    {   // prologue: stage tile 0
        f16x8 kr = *(const f16x8*)&khh[(size_t)(k0 + krow) * 32 + kcol];
        f16x8 vr = *(const f16x8*)&vth[(size_t)vrow * S + k0 + vcol];
        *(f16x8*)&Ks[0][krow][kcol] = kr;
        *(f16x8*)&Vt[0][vrow][vcol] = vr;
    }
    __syncthreads();

    int cur = 0;
#pragma unroll 1
    for (int t8 = 0; t8 < KS / 64; t8++) {
        bool more = (t8 + 1 < KS / 64);
        f16x8 kr, vr;
        if (more) {   // issue next tile's loads early; latency hides under compute
            int kn = k0 + (t8 + 1) * 64;
            kr = *(const f16x8*)&khh[(size_t)(kn + krow) * 32 + kcol];
            vr = *(const f16x8*)&vth[(size_t)vrow * S + kn + vcol];
        }

        f32x4 st[4];
        __builtin_amdgcn_s_setprio(1);
#pragma unroll
        for (int t = 0; t < 4; t++) {
            f16x8 kf = *(const f16x8*)&Ks[cur][t * 16 + lc][lr * 8];
            f32x4 zz = {0.f, 0.f, 0.f, 0.f};
            st[t] = __builtin_amdgcn_mfma_f32_16x16x32_f16(kf, qf, zz, 0, 0, 0);
        }
        __builtin_amdgcn_s_setprio(0);
#pragma unroll
        for (int t = 0; t < 4; t++) {
            float p0 = exp2f(st[t][0]), p1 = exp2f(st[t][1]);
            float p2 = exp2f(st[t][2]), p3 = exp2f(st[t][3]);
            f16x4 pk = {(_Float16)p0, (_Float16)p1, (_Float16)p2, (_Float16)p3};
            *(f16x4*)&Ps[w][lc][t * 16 + lr * 4] = pk;
        }
        asm volatile("s_waitcnt lgkmcnt(0)" ::: "memory");
        __builtin_amdgcn_s_setprio(1);
#pragma unroll
        for (int ch = 0; ch < 2; ch++) {
            f16x8 pf = *(const f16x8*)&Ps[w][lc][ch * 32 + lr * 8];
            f16x8 v0 = *(const f16x8*)&Vt[cur][lc][ch * 32 + lr * 8];
            f16x8 v1 = *(const f16x8*)&Vt[cur][16 + lc][ch * 32 + lr * 8];
            o0 = __builtin_amdgcn_mfma_f32_16x16x32_f16(pf, v0, o0, 0, 0, 0);
            o1 = __builtin_amdgcn_mfma_f32_16x16x32_f16(pf, v1, o1, 0, 0, 0);
            ol = __builtin_amdgcn_mfma_f32_16x16x32_f16(pf, vone, ol, 0, 0, 0);
        }
        __builtin_amdgcn_s_setprio(0);
        if (more) {
            *(f16x8*)&Ks[cur ^ 1][krow][kcol] = kr;
            *(f16x8*)&Vt[cur ^ 1][vrow][vcol] = vr;
            __syncthreads();
        }
        cur ^= 1;
    }

    _Float16* pz = part + (size_t)z * 524288;
#pragma unroll
    for (int i = 0; i < 4; i++) {
        int q = q0 + w * 16 + lr * 4 + i;
        pz[(size_t)q * 128 + h * 32 + lc]      = (_Float16)o0[i];
        pz[(size_t)q * 128 + h * 32 + 16 + lc] = (_Float16)o1[i];
        if (lc == 0) mll[((size_t)z * 4 + h) * 4096 + q] = ol[i];
    }
}

// ---------------------------------------------------------------------------
// Wo GEMM + split-attention merge + residual(x0) + LN1 -> x1 (fp32), xh (f16).
// 16-row tiles, glds B staging; merge-A written with element swizzle.
// ---------------------------------------------------------------------------
__global__ __launch_bounds__(256) void wo_ln_merge(const _Float16* __restrict__ part,
                                                   const float* __restrict__ mll,
                                                   const _Float16* __restrict__ Wh,
                                                   const float* __restrict__ bias,
                                                   const float* __restrict__ xres,
                                                   float* __restrict__ xo,
                                                   _Float16* __restrict__ xh,
                                                   const float* __restrict__ g,
                                                   const float* __restrict__ b)
{
    __shared__ _Float16 Ah[16][128], Bh[128][128];
    __shared__ float Red[16][4][2];
    int tid = threadIdx.x, w = tid >> 6, l = tid & 63, lc = l & 15, lr = l >> 4;
    int m0 = blockIdx.x * 16;

    stageGL<128>(Bh, Wh, 128, 0, 0, tid);
    {   // merge-stage A: 16 rows x 128 cols, 8 cols/thread (granule-aligned)
        int row = tid >> 4, qg = tid & 15;
        int col0 = qg * 8;
        int q = m0 + row, hh = col0 >> 5;
        float lsum = 0.f;
#pragma unroll
        for (int s = 0; s < SPLIT; s++) lsum += mll[((size_t)s * 4 + hh) * 4096 + q];
        float am[8];
#pragma unroll
        for (int e = 0; e < 8; e++) am[e] = 0.f;
#pragma unroll
        for (int s = 0; s < SPLIT; s++) {
            f16x8 t = *(const f16x8*)&part[(size_t)s * 524288 + (size_t)q * 128 + col0];
#pragma unroll
            for (int e = 0; e < 8; e++) am[e] += (float)t[e];
        }
        float inv = 1.f / lsum;
        f16x8 hv;
#pragma unroll
        for (int e = 0; e < 8; e++) hv[e] = (_Float16)(am[e] * inv);
        *(f16x8*)&Ah[row][(qg ^ (row & 15)) << 3] = hv;   // swizzled slot
    }
    __syncthreads();

    f32x4 acc[2];
#pragma unroll
    for (int j = 0; j < 2; j++) acc[j] = {0.f, 0.f, 0.f, 0.f};
#pragma unroll
    for (int ks = 0; ks < 4; ks++) {
        f16x8 af = rdS(Ah, lc, ks * 4 + lr);
#pragma unroll
        for (int j = 0; j < 2; j++) {
            f16x8 bf = rdS(Bh, w * 32 + j * 16 + lc, ks * 4 + lr);
            acc[j] = __builtin_amdgcn_mfma_f32_16x16x32_f16(af, bf, acc[j], 0, 0, 0);
        }
    }

#pragma unroll
    for (int j = 0; j < 2; j++) {
        int n = w * 32 + j * 16 + lc;
        float bb = bias[n];
#pragma unroll
        for (int r = 0; r < 4; r++)
            acc[j][r] += bb + xres[(size_t)(m0 + lr * 4 + r) * 128 + n];
    }
#pragma unroll
    for (int r = 0; r < 4; r++) {
        float s1 = acc[0][r] + acc[1][r];
        float s2 = acc[0][r] * acc[0][r] + acc[1][r] * acc[1][r];
#pragma unroll
        for (int off = 1; off < 16; off <<= 1) {
            s1 += __shfl_xor(s1, off);
            s2 += __shfl_xor(s2, off);
        }
        if (lc == 0) { Red[lr * 4 + r][w][0] = s1; Red[lr * 4 + r][w][1] = s2; }
    }
    __syncthreads();
#pragma unroll
    for (int r = 0; r < 4; r++) {
        int rl = lr * 4 + r;
        float S1 = (Red[rl][0][0] + Red[rl][1][0]) + (Red[rl][2][0] + Red[rl][3][0]);
        float S2 = (Red[rl][0][1] + Red[rl][1][1]) + (Red[rl][2][1] + Red[rl][3][1]);
        float mean = S1 * (1.0f / 128.0f);
        float var = S2 * (1.0f / 128.0f) - mean * mean;
        float inv = rsqrtf(var + 1e-5f);
        int m = m0 + rl;
#pragma unroll
        for (int j = 0; j < 2; j++) {
            int n = w * 32 + j * 16 + lc;
            float o = (acc[j][r] - mean) * inv * g[n] + b[n];
            xo[(size_t)m * 128 + n] = o;
            xh[(size_t)m * 128 + n] = (_Float16)o;
        }
    }
}

// ---------------------------------------------------------------------------
// Fused W1+W2 pair, 64-row tiles, grid (64, 8) = 512 blocks, glds staging.
// relu(F) written back into Ah with element swizzle.
// ---------------------------------------------------------------------------
__global__ __launch_bounds__(256) void ffn_pair(const _Float16* __restrict__ xh,
                                                const _Float16* __restrict__ W1h,
                                                const float* __restrict__ b1,
                                                const _Float16* __restrict__ W2h,
                                                _Float16* __restrict__ wpart)
{
    __shared__ _Float16 Ah[64][128], Bh[128][128];
    int tid = threadIdx.x, w = tid >> 6, l = tid & 63, lc = l & 15, lr = l >> 4;
    int wr = w >> 1, wc = w & 1;
    int m0 = blockIdx.x * 64, c = blockIdx.y;

    stageGL<64>(Ah, xh, 128, m0, 0, tid);
    stageGL<128>(Bh, W1h, 128, c * 128, 0, tid);
    __syncthreads();

    f32x4 acc[2][4];
#pragma unroll
    for (int i = 0; i < 2; i++)
#pragma unroll
        for (int j = 0; j < 4; j++) acc[i][j] = {0.f, 0.f, 0.f, 0.f};
#pragma unroll
    for (int ks = 0; ks < 4; ks++) {
        f16x8 af0 = rdS(Ah, wr * 32 + lc, ks * 4 + lr);
        f16x8 af1 = rdS(Ah, wr * 32 + 16 + lc, ks * 4 + lr);
#pragma unroll
        for (int j = 0; j < 4; j++) {
            f16x8 bf = rdS(Bh, wc * 64 + j * 16 + lc, ks * 4 + lr);
            acc[0][j] = __builtin_amdgcn_mfma_f32_16x16x32_f16(af0, bf, acc[0][j], 0, 0, 0);
            acc[1][j] = __builtin_amdgcn_mfma_f32_16x16x32_f16(af1, bf, acc[1][j], 0, 0, 0);
        }
    }
    __syncthreads();   // all pass-1 reads of Ah/Bh done

    // relu + bias -> F (into Ah, swizzled element writes)
#pragma unroll
    for (int i = 0; i < 2; i++)
#pragma unroll
        for (int j = 0; j < 4; j++) {
            int n = wc * 64 + j * 16 + lc;
            float bb = b1[c * 128 + n];
#pragma unroll
            for (int r = 0; r < 4; r++)
                wrS(Ah, wr * 32 + i * 16 + lr * 4 + r, n,
                    (_Float16)fmaxf(acc[i][j][r] + bb, 0.f));
        }
    stageGL<128>(Bh, W2h, 1024, 0, c * 128, tid);
    __syncthreads();

    f32x4 oacc[2][4];
#pragma unroll
    for (int i = 0; i < 2; i++)
#pragma unroll
        for (int j = 0; j < 4; j++) oacc[i][j] = {0.f, 0.f, 0.f, 0.f};
#pragma unroll
    for (int ks = 0; ks < 4; ks++) {
        f16x8 af0 = rdS(Ah, wr * 32 + lc, ks * 4 + lr);
        f16x8 af1 = rdS(Ah, wr * 32 + 16 + lc, ks * 4 + lr);
#pragma unroll
        for (int j = 0; j < 4; j++) {
            f16x8 bf = rdS(Bh, wc * 64 + j * 16 + lc, ks * 4 + lr);
            oacc[0][j] = __builtin_amdgcn_mfma_f32_16x16x32_f16(af0, bf, oacc[0][j], 0, 0, 0);
            oacc[1][j] = __builtin_amdgcn_mfma_f32_16x16x32_f16(af1, bf, oacc[1][j], 0, 0, 0);
        }
    }

    _Float16* pz = wpart + (size_t)c * 524288;
#pragma unroll
    for (int i = 0; i < 2; i++) {
        int mb = m0 + wr * 32 + i * 16 + lr * 4;
#pragma unroll
        for (int j = 0; j < 4; j++) {
            int n = wc * 64 + j * 16 + lc;
#pragma unroll
            for (int r = 0; r < 4; r++)
                pz[(size_t)(mb + r) * 128 + n] = (_Float16)oacc[i][j][r];
        }
    }
}

// ---------------------------------------------------------------------------
// fc1 + relu + fc2 + rownorm fused, with fused FFN-merge + LN2 A-stage
// (layer 2). 16-row tiles, grid 256, glds staging for weights.
// ---------------------------------------------------------------------------
__global__ __launch_bounds__(256) void fc_fused(const _Float16* __restrict__ wpart,
                                                const float* __restrict__ x1,
                                                const float* __restrict__ b2l,
                                                const float* __restrict__ g2,
                                                const float* __restrict__ bn2,
                                                const _Float16* __restrict__ W1h,
                                                const float* __restrict__ b1f,
                                                const _Float16* __restrict__ W2h,
                                                const float* __restrict__ b2f,
                                                _Float16* __restrict__ aoh)
{
    __shared__ _Float16 Ah[16][128], Bh[128][128];
    __shared__ float Red[16][4];
    int tid = threadIdx.x, w = tid >> 6, l = tid & 63, lc = l & 15, lr = l >> 4;
    int m0 = blockIdx.x * 16;

    stageGL<128>(Bh, W1h, 128, 0, 0, tid);
    {   // merge 8 W2-partials + b2 + residual + LN2 -> Ah
        int row = tid >> 4, qg = tid & 15, col0 = qg * 8;
        int q = m0 + row;
        float am[8];
#pragma unroll
        for (int e = 0; e < 8; e++) am[e] = 0.f;
#pragma unroll
        for (int s = 0; s < 8; s++) {
            f16x8 t = *(const f16x8*)&wpart[(size_t)s * 524288 + (size_t)q * 128 + col0];
#pragma unroll
            for (int e = 0; e < 8; e++) am[e] += (float)t[e];
        }
#pragma unroll
        for (int e = 0; e < 8; e++)
            am[e] += b2l[col0 + e] + x1[(size_t)q * 128 + col0 + e];
        float s1 = 0.f, s2 = 0.f;
#pragma unroll
        for (int e = 0; e < 8; e++) { s1 += am[e]; s2 += am[e] * am[e]; }
#pragma unroll
        for (int off = 1; off < 16; off <<= 1) {
            s1 += __shfl_xor(s1, off);
            s2 += __shfl_xor(s2, off);
        }
        float mean = s1 * (1.0f / 128.0f);
        float var = s2 * (1.0f / 128.0f) - mean * mean;
        float inv = rsqrtf(var + 1e-5f);
        f16x8 hv;
#pragma unroll
        for (int e = 0; e < 8; e++)
            hv[e] = (_Float16)((am[e] - mean) * inv * g2[col0 + e] + bn2[col0 + e]);
        *(f16x8*)&Ah[row][(qg ^ (row & 15)) << 3] = hv;
    }
    __syncthreads();

    f32x4 acc[2];
#pragma unroll
    for (int j = 0; j < 2; j++) acc[j] = {0.f, 0.f, 0.f, 0.f};
#pragma unroll
    for (int ks = 0; ks < 4; ks++) {
        f16x8 af = rdS(Ah, lc, ks * 4 + lr);
#pragma unroll
        for (int j = 0; j < 2; j++) {
            f16x8 bf = rdS(Bh, w * 32 + j * 16 + lc, ks * 4 + lr);
            acc[j] = __builtin_amdgcn_mfma_f32_16x16x32_f16(af, bf, acc[j], 0, 0, 0);
        }
    }
    __syncthreads();   // pass-1 reads done
#pragma unroll
    for (int j = 0; j < 2; j++) {
        int n = w * 32 + j * 16 + lc;
        float bb = b1f[n];
#pragma unroll
        for (int r = 0; r < 4; r++)
            wrS(Ah, lr * 4 + r, n, (_Float16)fmaxf(acc[j][r] + bb, 0.f));
    }
    stageGL<128>(Bh, W2h, 128, 0, 0, tid);
    __syncthreads();

    f32x4 o[2];
#pragma unroll
    for (int j = 0; j < 2; j++) o[j] = {0.f, 0.f, 0.f, 0.f};
#pragma unroll
    for (int ks = 0; ks < 4; ks++) {
        f16x8 af = rdS(Ah, lc, ks * 4 + lr);
#pragma unroll
        for (int j = 0; j < 2; j++) {
            f16x8 bf = rdS(Bh, w * 32 + j * 16 + lc, ks * 4 + lr);
            o[j] = __builtin_amdgcn_mfma_f32_16x16x32_f16(af, bf, o[j], 0, 0, 0);
        }
    }
#pragma unroll
    for (int j = 0; j < 2; j++) {
        float bb = b2f[w * 32 + j * 16 + lc];
#pragma unroll
        for (int r = 0; r < 4; r++) o[j][r] += bb;
    }
#pragma unroll
    for (int r = 0; r < 4; r++) {
        float s2 = o[0][r] * o[0][r] + o[1][r] * o[1][r];
#pragma unroll
        for (int off = 1; off < 16; off <<= 1) s2 += __shfl_xor(s2, off);
        if (lc == 0) Red[lr * 4 + r][w] = s2;
    }
    __syncthreads();
#pragma unroll
    for (int r = 0; r < 4; r++) {
        int rl = lr * 4 + r;
        float inv = rsqrtf((Red[rl][0] + Red[rl][1]) + (Red[rl][2] + Red[rl][3]));
        int m = m0 + rl;
#pragma unroll
        for (int j = 0; j < 2; j++) {
            int n = w * 32 + j * 16 + lc;
            aoh[(size_t)m * 128 + n] = (_Float16)(o[j][r] * inv);
        }
    }
}

// ---------------------------------------------------------------------------
// Gram: C = max(aoh @ aoh^T, 1e-6). 64x128 tiles, glds staging,
// grid (64, 32) = 2048 blocks.
// ---------------------------------------------------------------------------
__global__ __launch_bounds__(256) void gram_f16(const _Float16* __restrict__ aoh,
                                                float* __restrict__ C)
{
    __shared__ _Float16 Ah[64][128], Bh[128][128];
    int tid = threadIdx.x, w = tid >> 6, l = tid & 63, lc = l & 15, lr = l >> 4;
    int wr = w >> 1, wc = w & 1;
    int m0 = blockIdx.x * 64, n0 = blockIdx.y * 128;

    stageGL<64>(Ah, aoh, 128, m0, 0, tid);
    stageGL<128>(Bh, aoh, 128, n0, 0, tid);
    __syncthreads();

    f32x4 acc[2][4];
#pragma unroll
    for (int i = 0; i < 2; i++)
#pragma unroll
        for (int j = 0; j < 4; j++) acc[i][j] = {0.f, 0.f, 0.f, 0.f};
#pragma unroll
    for (int ks = 0; ks < 4; ks++) {
        f16x8 af0 = rdS(Ah, wr * 32 + lc, ks * 4 + lr);
        f16x8 af1 = rdS(Ah, wr * 32 + 16 + lc, ks * 4 + lr);
#pragma unroll
        for (int j = 0; j < 4; j++) {
            f16x8 bf = rdS(Bh, wc * 64 + j * 16 + lc, ks * 4 + lr);
            acc[0][j] = __builtin_amdgcn_mfma_f32_16x16x32_f16(af0, bf, acc[0][j], 0, 0, 0);
            acc[1][j] = __builtin_amdgcn_mfma_f32_16x16x32_f16(af1, bf, acc[1][j], 0, 0, 0);
        }
    }

#pragma unroll
    for (int i = 0; i < 2; i++) {
        int mb = m0 + wr * 32 + i * 16 + lr * 4;
#pragma unroll
        for (int j = 0; j < 4; j++) {
            int n = n0 + wc * 64 + j * 16 + lc;
#pragma unroll
            for (int r = 0; r < 4; r++)
                C[(size_t)(mb + r) * 4096 + n] = fmaxf(acc[i][j][r], 1e-6f);
        }
    }
}

// ---------------------------------------------------------------------------
extern "C" void kernel_launch(void* const* d_in, const int* in_sizes, int n_in,
                              void* d_out, int out_size, void* d_ws, size_t ws_size,
                              hipStream_t stream)
{
    const float* src  = (const float*)d_in[0];
    const float* Wqkv = (const float*)d_in[1];
    const float* bqkv = (const float*)d_in[2];
    const float* Wo   = (const float*)d_in[3];
    const float* bo   = (const float*)d_in[4];
    const float* ln1g = (const float*)d_in[5];
    const float* ln1b = (const float*)d_in[6];
    const float* W1   = (const float*)d_in[7];
    const float* b1   = (const float*)d_in[8];
    const float* W2   = (const float*)d_in[9];
    const float* b2   = (const float*)d_in[10];
    const float* ln2g = (const float*)d_in[11];
    const float* ln2b = (const float*)d_in[12];
    const float* fc1W = (const float*)d_in[13];
    const float* fc1b = (const float*)d_in[14];
    const float* fc2W = (const float*)d_in[15];
    const float* fc2b = (const float*)d_in[16];

    float* ws = (float*)d_ws;
    float*    x   = ws;                                   // 524288 f32 (post-LN2 chain)
    _Float16* xh  = (_Float16*)(ws + 524288);             // 524288 f16 (post-LN1 / init)
    _Float16* aoh = (_Float16*)(ws + 786432);             // 524288 f16
    _Float16* qh  = (_Float16*)(ws + 1048576);            // 524288 f16
    _Float16* kh  = (_Float16*)(ws + 1310720);            // 524288 f16
    _Float16* vt  = (_Float16*)(ws + 1572864);            // 524288 f16
    float*    mll = ws + 1835008;                         // 65536 f32 (SPLIT=4)

    // d_out scratch (all dead before gram writes):
    _Float16* wpart = (_Float16*)d_out + 4194304;         // bytes [ 8MiB,16MiB)
    _Float16* apart = (_Float16*)d_out + 12582912;        // bytes [24MiB,28MiB) SPLIT=4
    _Float16* wh    = (_Float16*)d_out + 16777216;        // bytes [32MiB,~34MiB)
    float*    x1    = (float*)d_out + 9437184;            // bytes [36MiB,38MiB) post-LN1
    float*    out   = (float*)d_out;

    _Float16* qkvh = wh;                  // 3 x 384 x 128
    _Float16* woh  = wh + 147456;         // 3 x 128 x 128
    _Float16* w1h  = wh + 196608;         // 3 x 1024 x 128
    _Float16* w2h  = wh + 589824;         // 3 x 128 x 1024
    _Float16* fc1h = wh + 983040;         // 128 x 128
    _Float16* fc2h = wh + 999424;         // 128 x 128

    setup_cvt<<<1504, 256, 0, stream>>>(Wqkv, Wo, W1, W2, fc1W, fc2W, wh,
                                        src, x, xh);
    // layer 0
    gemm_qkv<<<dim3(256, 3), 256, 0, stream>>>(xh, qkvh, bqkv, qh, kh, vt);
    attn_mfma<<<dim3(64, 4, SPLIT), 256, 0, stream>>>(qh, kh, vt, apart, mll);
    wo_ln_merge<<<256, 256, 0, stream>>>(apart, mll, woh, bo, x, x1, xh,
                                         ln1g, ln1b);
    ffn_pair<<<dim3(64, 8), 256, 0, stream>>>(xh, w1h, b1, w2h, wpart);
    // layers 1, 2: QKV with fused FFN-merge + LN2 of previous layer
    for (int l = 1; l < 3; l++) {
        gemm_qkv_merge<<<dim3(256, 3), 256, 0, stream>>>(
            wpart, x1, b2 + (l - 1) * 128, ln2g + (l - 1) * 128,
            ln2b + (l - 1) * 128, x,
            qkvh + l * 49152, bqkv + l * 384, qh, kh, vt);
        attn_mfma<<<dim3(64, 4, SPLIT), 256, 0, stream>>>(qh, kh, vt, apart, mll);
        wo_ln_merge<<<256, 256, 0, stream>>>(apart, mll, woh + l * 16384,
                                             bo + l * 128, x, x1, xh,
                                             ln1g + l * 128, ln1b + l * 128);
        ffn_pair<<<dim3(64, 8), 256, 0, stream>>>(xh, w1h + l * 131072,
                                                  b1 + l * 1024,
                                                  w2h + l * 131072, wpart);
    }
    // fc chain with fused FFN-merge + LN2 of layer 2
    fc_fused<<<256, 256, 0, stream>>>(wpart, x1, b2 + 256, ln2g + 256,
                                      ln2b + 256, fc1h, fc1b, fc2h, fc2b, aoh);
    gram_f16<<<dim3(64, 32), 256, 0, stream>>>(aoh, out);
}

// Round 11
// 256.882 us; speedup vs baseline: 1.0701x; 1.0006x over previous
//
#include <hip/hip_runtime.h>
#include <math.h>

#define S 4096
#define QK_SCALE 0.17677669529663687f  // 1/sqrt(32)
#define LOG2E    1.44269504088896f
#define SPLIT 4
#define KS (S / SPLIT)                 // 1024 keys per split

typedef _Float16 f16x8 __attribute__((ext_vector_type(8)));
typedef _Float16 f16x4 __attribute__((ext_vector_type(4)));
typedef _Float16 f16x2 __attribute__((ext_vector_type(2)));
typedef float f32x4 __attribute__((ext_vector_type(4)));

// ---------------------------------------------------------------------------
// MFMA lane map (HW-verified R4): A-frag m=l&15, k=(l>>4)*8+j; B-frag n=l&15;
// C reg r: row=(l>>4)*4+r, col=l&15.
// R20: base = R10 (257.0us best; SPLIT=4 tail-free won). ONE change: gram
// re-tile 64x128 -> 128x128. Old: 2048 blocks @48KB LDS -> 3/CU -> 768
// resident -> 2.67 ragged passes, 98MB staging. New: grid (32,32)=1024
// blocks @64KB LDS -> exactly 2/CU -> two clean passes of 512; staging 64MB;
// MFMA per staged byte doubled. Gram floor = 64MB fp32 HBM write (~10.5us).
// Staging: global_load_lds 16B direct-to-LDS, source-granule XOR swizzle
// (g ^= row&15) + same XOR on reads (both-sides involution, 2 lanes/bank).
// ---------------------------------------------------------------------------

// direct-to-LDS stage of ROWS x 128 f16 tile, linear [128] stride, source
// granule-swizzled so a swizzled read recovers logical layout.
template<int ROWS>
__device__ __forceinline__ void stageGL(_Float16 (*dst)[128], const _Float16* src,
                                        int ld, int row0, int col0, int tid) {
    int w = tid >> 6, l = tid & 63;
    constexpr int NISS = ROWS / 16;         // wave-issues per wave (4 waves)
#pragma unroll
    for (int v = 0; v < NISS; v++) {
        int G = (w * NISS + v) * 64 + l;    // linear granule id
        int row = G >> 4, g = G & 15;
        int gs = g ^ (row & 15);            // swizzled source granule
        const void* gp = src + (size_t)(row0 + row) * ld + col0 + gs * 8;
        void* lp = (char*)&dst[0][0] + (size_t)G * 16;
        __builtin_amdgcn_global_load_lds(
            (const __attribute__((address_space(1))) void*)gp,
            (__attribute__((address_space(3))) void*)lp, 16, 0, 0);
    }
}

// swizzled 16B fragment read: logical granule qg of row
__device__ __forceinline__ f16x8 rdS(const _Float16 (*B)[128], int row, int qg) {
    return *(const f16x8*)&B[row][(qg ^ (row & 15)) << 3];
}
// swizzled element write (for register-computed tiles)
__device__ __forceinline__ void wrS(_Float16 (*B)[128], int row, int col, _Float16 v) {
    B[row][((((col >> 3) ^ (row & 15))) << 3) | (col & 7)] = v;
}

// ---------------------------------------------------------------------------
// setup: weight fp32->fp16 conversion (blocks 0..991) + x/xh copy (992..1503).
// ---------------------------------------------------------------------------
__global__ __launch_bounds__(256) void setup_cvt(const float* __restrict__ q,
                                                 const float* __restrict__ wo,
                                                 const float* __restrict__ w1,
                                                 const float* __restrict__ w2,
                                                 const float* __restrict__ f1,
                                                 const float* __restrict__ f2,
                                                 _Float16* __restrict__ dst,
                                                 const float* __restrict__ a,
                                                 float* __restrict__ x,
                                                 _Float16* __restrict__ xh)
{
    int bb = blockIdx.x;
    if (bb < 992) {
        const float* src; size_t dof; int lb;
        if (bb < 144)      { src = q;  dof = 0;      lb = bb; }
        else if (bb < 192) { src = wo; dof = 147456; lb = bb - 144; }
        else if (bb < 576) { src = w1; dof = 196608; lb = bb - 192; }
        else if (bb < 960) { src = w2; dof = 589824; lb = bb - 576; }
        else if (bb < 976) { src = f1; dof = 983040; lb = bb - 960; }
        else               { src = f2; dof = 999424; lb = bb - 976; }
        int i = lb * 1024 + threadIdx.x * 4;
        float4 v = *(const float4*)(src + i);
        f16x4 h = {(_Float16)v.x, (_Float16)v.y, (_Float16)v.z, (_Float16)v.w};
        *(f16x4*)(dst + dof + i) = h;
    } else {
        int i = (bb - 992) * 256 + threadIdx.x;
        float4 v = ((const float4*)a)[i];
        ((float4*)x)[i] = v;
        f16x4 h = {(_Float16)v.x, (_Float16)v.y, (_Float16)v.z, (_Float16)v.w};
        ((f16x4*)xh)[i] = h;
    }
}

// ---------------------------------------------------------------------------
// QKV GEMM (layer 0), 16-row tiles, full-K single barrier, glds staging.
// grid (256, 3): by=0 -> qh (scaled), by=1 -> kh, by=2 -> vt (transposed).
// ---------------------------------------------------------------------------
__global__ __launch_bounds__(256) void gemm_qkv(const _Float16* __restrict__ xh,
                                                const _Float16* __restrict__ Wh,
                                                const float* __restrict__ bias,
                                                _Float16* __restrict__ qh,
                                                _Float16* __restrict__ kh,
                                                _Float16* __restrict__ vt)
{
    __shared__ _Float16 Ah[16][128], Bh[128][128];
    int tid = threadIdx.x, w = tid >> 6, l = tid & 63, lc = l & 15, lr = l >> 4;
    int m0 = blockIdx.x * 16, by = blockIdx.y;

    stageGL<16>(Ah, xh, 128, m0, 0, tid);
    stageGL<128>(Bh, Wh, 128, by * 128, 0, tid);
    __syncthreads();

    f32x4 acc[2];
#pragma unroll
    for (int j = 0; j < 2; j++) acc[j] = {0.f, 0.f, 0.f, 0.f};
#pragma unroll
    for (int ks = 0; ks < 4; ks++) {
        f16x8 af = rdS(Ah, lc, ks * 4 + lr);
#pragma unroll
        for (int j = 0; j < 2; j++) {
            f16x8 bf = rdS(Bh, w * 32 + j * 16 + lc, ks * 4 + lr);
            acc[j] = __builtin_amdgcn_mfma_f32_16x16x32_f16(af, bf, acc[j], 0, 0, 0);
        }
    }

    int mb = m0 + lr * 4;
#pragma unroll
    for (int j = 0; j < 2; j++) {
        int n = w * 32 + j * 16 + lc;
        float bb = bias[by * 128 + n];
        if (by == 0) {
#pragma unroll
            for (int r = 0; r < 4; r++)
                qh[(size_t)(mb + r) * 128 + n] =
                    (_Float16)((acc[j][r] + bb) * (QK_SCALE * LOG2E));
        } else if (by == 1) {
            int hh = n >> 5, d = n & 31;
#pragma unroll
            for (int r = 0; r < 4; r++)
                kh[((size_t)hh * S + mb + r) * 32 + d] = (_Float16)(acc[j][r] + bb);
        } else {
            f16x4 pk;
#pragma unroll
            for (int r = 0; r < 4; r++) pk[r] = (_Float16)(acc[j][r] + bb);
            *(f16x4*)&vt[(size_t)n * S + mb] = pk;
        }
    }
}

// ---------------------------------------------------------------------------
// QKV GEMM with fused FFN-merge + LN2 A-stage (layers 1,2). A-tile built from
// 8 W2 partials + b2 + residual(x1, post-LN1) -> LN2 -> Ah. by==0 writes the
// fp32 post-LN2 to x0 (residual for this layer's wo_ln_merge).
// ---------------------------------------------------------------------------
__global__ __launch_bounds__(256) void gemm_qkv_merge(
    const _Float16* __restrict__ wpart, const float* __restrict__ x1,
    const float* __restrict__ b2, const float* __restrict__ g2,
    const float* __restrict__ bn2, float* __restrict__ x0,
    const _Float16* __restrict__ Wh, const float* __restrict__ bias,
    _Float16* __restrict__ qh, _Float16* __restrict__ kh,
    _Float16* __restrict__ vt)
{
    __shared__ _Float16 Ah[16][128], Bh[128][128];
    int tid = threadIdx.x, w = tid >> 6, l = tid & 63, lc = l & 15, lr = l >> 4;
    int m0 = blockIdx.x * 16, by = blockIdx.y;

    stageGL<128>(Bh, Wh, 128, by * 128, 0, tid);   // B in flight during merge
    {   // merge 8 W2-partials + b2 + residual + LN2 -> Ah (16 x 128)
        int row = tid >> 4, qg = tid & 15, col0 = qg * 8;
        int q = m0 + row;
        float am[8];
#pragma unroll
        for (int e = 0; e < 8; e++) am[e] = 0.f;
#pragma unroll
        for (int s = 0; s < 8; s++) {
            f16x8 t = *(const f16x8*)&wpart[(size_t)s * 524288 + (size_t)q * 128 + col0];
#pragma unroll
            for (int e = 0; e < 8; e++) am[e] += (float)t[e];
        }
#pragma unroll
        for (int e = 0; e < 8; e++)
            am[e] += b2[col0 + e] + x1[(size_t)q * 128 + col0 + e];
        float s1 = 0.f, s2 = 0.f;
#pragma unroll
        for (int e = 0; e < 8; e++) { s1 += am[e]; s2 += am[e] * am[e]; }
#pragma unroll
        for (int off = 1; off < 16; off <<= 1) {   // row = aligned 16-lane group
            s1 += __shfl_xor(s1, off);
            s2 += __shfl_xor(s2, off);
        }
        float mean = s1 * (1.0f / 128.0f);
        float var = s2 * (1.0f / 128.0f) - mean * mean;
        float inv = rsqrtf(var + 1e-5f);
        float o[8];
        f16x8 hv;
#pragma unroll
        for (int e = 0; e < 8; e++) {
            o[e] = (am[e] - mean) * inv * g2[col0 + e] + bn2[col0 + e];
            hv[e] = (_Float16)o[e];
        }
        *(f16x8*)&Ah[row][(qg ^ (row & 15)) << 3] = hv;
        if (by == 0) {
            float4 v0 = {o[0], o[1], o[2], o[3]};
            float4 v1 = {o[4], o[5], o[6], o[7]};
            *(float4*)&x0[(size_t)q * 128 + col0]     = v0;
            *(float4*)&x0[(size_t)q * 128 + col0 + 4] = v1;
        }
    }
    __syncthreads();

    f32x4 acc[2];
#pragma unroll
    for (int j = 0; j < 2; j++) acc[j] = {0.f, 0.f, 0.f, 0.f};
#pragma unroll
    for (int ks = 0; ks < 4; ks++) {
        f16x8 af = rdS(Ah, lc, ks * 4 + lr);
#pragma unroll
        for (int j = 0; j < 2; j++) {
            f16x8 bf = rdS(Bh, w * 32 + j * 16 + lc, ks * 4 + lr);
            acc[j] = __builtin_amdgcn_mfma_f32_16x16x32_f16(af, bf, acc[j], 0, 0, 0);
        }
    }

    int mb = m0 + lr * 4;
#pragma unroll
    for (int j = 0; j < 2; j++) {
        int n = w * 32 + j * 16 + lc;
        float bb = bias[by * 128 + n];
        if (by == 0) {
#pragma unroll
            for (int r = 0; r < 4; r++)
                qh[(size_t)(mb + r) * 128 + n] =
                    (_Float16)((acc[j][r] + bb) * (QK_SCALE * LOG2E));
        } else if (by == 1) {
            int hh = n >> 5, d = n & 31;
#pragma unroll
            for (int r = 0; r < 4; r++)
                kh[((size_t)hh * S + mb + r) * 32 + d] = (_Float16)(acc[j][r] + bb);
        } else {
            f16x4 pk;
#pragma unroll
            for (int r = 0; r < 4; r++) pk[r] = (_Float16)(acc[j][r] + bb);
            *(f16x4*)&vt[(size_t)n * S + mb] = pk;
        }
    }
}

// ---------------------------------------------------------------------------
// MFMA flash attention: K/V double-buffer, async-split staging, one barrier
// per tile; swapped QK^T; f16x4 Ps writes; l-sum via ones-column MFMA.
// SPLIT=4: 1024 blocks, 4/CU co-resident, tail-free; 16 tiles/block.
// ---------------------------------------------------------------------------
__global__ __launch_bounds__(256) void attn_mfma(const _Float16* __restrict__ qh,
                                                 const _Float16* __restrict__ kh,
                                                 const _Float16* __restrict__ vt,
                                                 _Float16* __restrict__ part,
                                                 float* __restrict__ mll)
{
    __shared__ _Float16 Ks[2][64][32];
    __shared__ _Float16 Vt[2][32][72];
    __shared__ _Float16 Ps[4][16][72];
    int h = blockIdx.y, q0 = blockIdx.x * 64, z = blockIdx.z;
    int tid = threadIdx.x;
    int w = tid >> 6, l = tid & 63;
    int lc = l & 15, lr = l >> 4;

    f16x8 qf = *(const f16x8*)&qh[(size_t)(q0 + w * 16 + lc) * 128 + h * 32 + lr * 8];

    const _Float16* khh = kh + (size_t)h * S * 32;
    const _Float16* vth = vt + (size_t)h * 32 * S;

    int krow = tid >> 2, kcol = (tid & 3) * 8;
    int vrow = tid >> 3, vcol = (tid & 7) * 8;

    f32x4 o0 = {0.f, 0.f, 0.f, 0.f}, o1 = {0.f, 0.f, 0.f, 0.f};
    f32x4 ol = {0.f, 0.f, 0.f, 0.f};
    f16x8 vone = {(_Float16)1.f, (_Float16)1.f, (_Float16)1.f, (_Float16)1.f,
                  (_Float16)1.f, (_Float16)1.f, (_Float16)1.f, (_Float16)1.f};

    int k0 = z * KS;
    {   // prologue: stage tile 0
        f16x8 kr = *(const f16x8*)&khh[(size_t)(k0 + krow) * 32 + kcol];
        f16x8 vr = *(const f16x8*)&vth[(size_t)vrow * S + k0 + vcol];
        *(f16x8*)&Ks[0][krow][kcol] = kr;
        *(f16x8*)&Vt[0][vrow][vcol] = vr;
    }
    __syncthreads();

    int cur = 0;
#pragma unroll 1
    for (int t8 = 0; t8 < KS / 64; t8++) {
        bool more = (t8 + 1 < KS / 64);
        f16x8 kr, vr;
        if (more) {   // issue next tile's loads early; latency hides under compute
            int kn = k0 + (t8 + 1) * 64;
            kr = *(const f16x8*)&khh[(size_t)(kn + krow) * 32 + kcol];
            vr = *(const f16x8*)&vth[(size_t)vrow * S + kn + vcol];
        }

        f32x4 st[4];
        __builtin_amdgcn_s_setprio(1);
#pragma unroll
        for (int t = 0; t < 4; t++) {
            f16x8 kf = *(const f16x8*)&Ks[cur][t * 16 + lc][lr * 8];
            f32x4 zz = {0.f, 0.f, 0.f, 0.f};
            st[t] = __builtin_amdgcn_mfma_f32_16x16x32_f16(kf, qf, zz, 0, 0, 0);
        }
        __builtin_amdgcn_s_setprio(0);
#pragma unroll
        for (int t = 0; t < 4; t++) {
            float p0 = exp2f(st[t][0]), p1 = exp2f(st[t][1]);
            float p2 = exp2f(st[t][2]), p3 = exp2f(st[t][3]);
            f16x4 pk = {(_Float16)p0, (_Float16)p1, (_Float16)p2, (_Float16)p3};
            *(f16x4*)&Ps[w][lc][t * 16 + lr * 4] = pk;
        }
        asm volatile("s_waitcnt lgkmcnt(0)" ::: "memory");
        __builtin_amdgcn_s_setprio(1);
#pragma unroll
        for (int ch = 0; ch < 2; ch++) {
            f16x8 pf = *(const f16x8*)&Ps[w][lc][ch * 32 + lr * 8];
            f16x8 v0 = *(const f16x8*)&Vt[cur][lc][ch * 32 + lr * 8];
            f16x8 v1 = *(const f16x8*)&Vt[cur][16 + lc][ch * 32 + lr * 8];
            o0 = __builtin_amdgcn_mfma_f32_16x16x32_f16(pf, v0, o0, 0, 0, 0);
            o1 = __builtin_amdgcn_mfma_f32_16x16x32_f16(pf, v1, o1, 0, 0, 0);
            ol = __builtin_amdgcn_mfma_f32_16x16x32_f16(pf, vone, ol, 0, 0, 0);
        }
        __builtin_amdgcn_s_setprio(0);
        if (more) {
            *(f16x8*)&Ks[cur ^ 1][krow][kcol] = kr;
            *(f16x8*)&Vt[cur ^ 1][vrow][vcol] = vr;
            __syncthreads();
        }
        cur ^= 1;
    }

    _Float16* pz = part + (size_t)z * 524288;
#pragma unroll
    for (int i = 0; i < 4; i++) {
        int q = q0 + w * 16 + lr * 4 + i;
        pz[(size_t)q * 128 + h * 32 + lc]      = (_Float16)o0[i];
        pz[(size_t)q * 128 + h * 32 + 16 + lc] = (_Float16)o1[i];
        if (lc == 0) mll[((size_t)z * 4 + h) * 4096 + q] = ol[i];
    }
}

// ---------------------------------------------------------------------------
// Wo GEMM + split-attention merge + residual(x0) + LN1 -> x1 (fp32), xh (f16).
// 16-row tiles, glds B staging; merge-A written with element swizzle.
// ---------------------------------------------------------------------------
__global__ __launch_bounds__(256) void wo_ln_merge(const _Float16* __restrict__ part,
                                                   const float* __restrict__ mll,
                                                   const _Float16* __restrict__ Wh,
                                                   const float* __restrict__ bias,
                                                   const float* __restrict__ xres,
                                                   float* __restrict__ xo,
                                                   _Float16* __restrict__ xh,
                                                   const float* __restrict__ g,
                                                   const float* __restrict__ b)
{
    __shared__ _Float16 Ah[16][128], Bh[128][128];
    __shared__ float Red[16][4][2];
    int tid = threadIdx.x, w = tid >> 6, l = tid & 63, lc = l & 15, lr = l >> 4;
    int m0 = blockIdx.x * 16;

    stageGL<128>(Bh, Wh, 128, 0, 0, tid);
    {   // merge-stage A: 16 rows x 128 cols, 8 cols/thread (granule-aligned)
        int row = tid >> 4, qg = tid & 15;
        int col0 = qg * 8;
        int q = m0 + row, hh = col0 >> 5;
        float lsum = 0.f;
#pragma unroll
        for (int s = 0; s < SPLIT; s++) lsum += mll[((size_t)s * 4 + hh) * 4096 + q];
        float am[8];
#pragma unroll
        for (int e = 0; e < 8; e++) am[e] = 0.f;
#pragma unroll
        for (int s = 0; s < SPLIT; s++) {
            f16x8 t = *(const f16x8*)&part[(size_t)s * 524288 + (size_t)q * 128 + col0];
#pragma unroll
            for (int e = 0; e < 8; e++) am[e] += (float)t[e];
        }
        float inv = 1.f / lsum;
        f16x8 hv;
#pragma unroll
        for (int e = 0; e < 8; e++) hv[e] = (_Float16)(am[e] * inv);
        *(f16x8*)&Ah[row][(qg ^ (row & 15)) << 3] = hv;   // swizzled slot
    }
    __syncthreads();

    f32x4 acc[2];
#pragma unroll
    for (int j = 0; j < 2; j++) acc[j] = {0.f, 0.f, 0.f, 0.f};
#pragma unroll
    for (int ks = 0; ks < 4; ks++) {
        f16x8 af = rdS(Ah, lc, ks * 4 + lr);
#pragma unroll
        for (int j = 0; j < 2; j++) {
            f16x8 bf = rdS(Bh, w * 32 + j * 16 + lc, ks * 4 + lr);
            acc[j] = __builtin_amdgcn_mfma_f32_16x16x32_f16(af, bf, acc[j], 0, 0, 0);
        }
    }

#pragma unroll
    for (int j = 0; j < 2; j++) {
        int n = w * 32 + j * 16 + lc;
        float bb = bias[n];
#pragma unroll
        for (int r = 0; r < 4; r++)
            acc[j][r] += bb + xres[(size_t)(m0 + lr * 4 + r) * 128 + n];
    }
#pragma unroll
    for (int r = 0; r < 4; r++) {
        float s1 = acc[0][r] + acc[1][r];
        float s2 = acc[0][r] * acc[0][r] + acc[1][r] * acc[1][r];
#pragma unroll
        for (int off = 1; off < 16; off <<= 1) {
            s1 += __shfl_xor(s1, off);
            s2 += __shfl_xor(s2, off);
        }
        if (lc == 0) { Red[lr * 4 + r][w][0] = s1; Red[lr * 4 + r][w][1] = s2; }
    }
    __syncthreads();
#pragma unroll
    for (int r = 0; r < 4; r++) {
        int rl = lr * 4 + r;
        float S1 = (Red[rl][0][0] + Red[rl][1][0]) + (Red[rl][2][0] + Red[rl][3][0]);
        float S2 = (Red[rl][0][1] + Red[rl][1][1]) + (Red[rl][2][1] + Red[rl][3][1]);
        float mean = S1 * (1.0f / 128.0f);
        float var = S2 * (1.0f / 128.0f) - mean * mean;
        float inv = rsqrtf(var + 1e-5f);
        int m = m0 + rl;
#pragma unroll
        for (int j = 0; j < 2; j++) {
            int n = w * 32 + j * 16 + lc;
            float o = (acc[j][r] - mean) * inv * g[n] + b[n];
            xo[(size_t)m * 128 + n] = o;
            xh[(size_t)m * 128 + n] = (_Float16)o;
        }
    }
}

// ---------------------------------------------------------------------------
// Fused W1+W2 pair, 64-row tiles, grid (64, 8) = 512 blocks, glds staging.
// relu(F) written back into Ah with element swizzle.
// ---------------------------------------------------------------------------
__global__ __launch_bounds__(256) void ffn_pair(const _Float16* __restrict__ xh,
                                                const _Float16* __restrict__ W1h,
                                                const float* __restrict__ b1,
                                                const _Float16* __restrict__ W2h,
                                                _Float16* __restrict__ wpart)
{
    __shared__ _Float16 Ah[64][128], Bh[128][128];
    int tid = threadIdx.x, w = tid >> 6, l = tid & 63, lc = l & 15, lr = l >> 4;
    int wr = w >> 1, wc = w & 1;
    int m0 = blockIdx.x * 64, c = blockIdx.y;

    stageGL<64>(Ah, xh, 128, m0, 0, tid);
    stageGL<128>(Bh, W1h, 128, c * 128, 0, tid);
    __syncthreads();

    f32x4 acc[2][4];
#pragma unroll
    for (int i = 0; i < 2; i++)
#pragma unroll
        for (int j = 0; j < 4; j++) acc[i][j] = {0.f, 0.f, 0.f, 0.f};
#pragma unroll
    for (int ks = 0; ks < 4; ks++) {
        f16x8 af0 = rdS(Ah, wr * 32 + lc, ks * 4 + lr);
        f16x8 af1 = rdS(Ah, wr * 32 + 16 + lc, ks * 4 + lr);
#pragma unroll
        for (int j = 0; j < 4; j++) {
            f16x8 bf = rdS(Bh, wc * 64 + j * 16 + lc, ks * 4 + lr);
            acc[0][j] = __builtin_amdgcn_mfma_f32_16x16x32_f16(af0, bf, acc[0][j], 0, 0, 0);
            acc[1][j] = __builtin_amdgcn_mfma_f32_16x16x32_f16(af1, bf, acc[1][j], 0, 0, 0);
        }
    }
    __syncthreads();   // all pass-1 reads of Ah/Bh done

    // relu + bias -> F (into Ah, swizzled element writes)
#pragma unroll
    for (int i = 0; i < 2; i++)
#pragma unroll
        for (int j = 0; j < 4; j++) {
            int n = wc * 64 + j * 16 + lc;
            float bb = b1[c * 128 + n];
#pragma unroll
            for (int r = 0; r < 4; r++)
                wrS(Ah, wr * 32 + i * 16 + lr * 4 + r, n,
                    (_Float16)fmaxf(acc[i][j][r] + bb, 0.f));
        }
    stageGL<128>(Bh, W2h, 1024, 0, c * 128, tid);
    __syncthreads();

    f32x4 oacc[2][4];
#pragma unroll
    for (int i = 0; i < 2; i++)
#pragma unroll
        for (int j = 0; j < 4; j++) oacc[i][j] = {0.f, 0.f, 0.f, 0.f};
#pragma unroll
    for (int ks = 0; ks < 4; ks++) {
        f16x8 af0 = rdS(Ah, wr * 32 + lc, ks * 4 + lr);
        f16x8 af1 = rdS(Ah, wr * 32 + 16 + lc, ks * 4 + lr);
#pragma unroll
        for (int j = 0; j < 4; j++) {
            f16x8 bf = rdS(Bh, wc * 64 + j * 16 + lc, ks * 4 + lr);
            oacc[0][j] = __builtin_amdgcn_mfma_f32_16x16x32_f16(af0, bf, oacc[0][j], 0, 0, 0);
            oacc[1][j] = __builtin_amdgcn_mfma_f32_16x16x32_f16(af1, bf, oacc[1][j], 0, 0, 0);
        }
    }

    _Float16* pz = wpart + (size_t)c * 524288;
#pragma unroll
    for (int i = 0; i < 2; i++) {
        int mb = m0 + wr * 32 + i * 16 + lr * 4;
#pragma unroll
        for (int j = 0; j < 4; j++) {
            int n = wc * 64 + j * 16 + lc;
#pragma unroll
            for (int r = 0; r < 4; r++)
                pz[(size_t)(mb + r) * 128 + n] = (_Float16)oacc[i][j][r];
        }
    }
}

// ---------------------------------------------------------------------------
// fc1 + relu + fc2 + rownorm fused, with fused FFN-merge + LN2 A-stage
// (layer 2). 16-row tiles, grid 256, glds staging for weights.
// ---------------------------------------------------------------------------
__global__ __launch_bounds__(256) void fc_fused(const _Float16* __restrict__ wpart,
                                                const float* __restrict__ x1,
                                                const float* __restrict__ b2l,
                                                const float* __restrict__ g2,
                                                const float* __restrict__ bn2,
                                                const _Float16* __restrict__ W1h,
                                                const float* __restrict__ b1f,
                                                const _Float16* __restrict__ W2h,
                                                const float* __restrict__ b2f,
                                                _Float16* __restrict__ aoh)
{
    __shared__ _Float16 Ah[16][128], Bh[128][128];
    __shared__ float Red[16][4];
    int tid = threadIdx.x, w = tid >> 6, l = tid & 63, lc = l & 15, lr = l >> 4;
    int m0 = blockIdx.x * 16;

    stageGL<128>(Bh, W1h, 128, 0, 0, tid);
    {   // merge 8 W2-partials + b2 + residual + LN2 -> Ah
        int row = tid >> 4, qg = tid & 15, col0 = qg * 8;
        int q = m0 + row;
        float am[8];
#pragma unroll
        for (int e = 0; e < 8; e++) am[e] = 0.f;
#pragma unroll
        for (int s = 0; s < 8; s++) {
            f16x8 t = *(const f16x8*)&wpart[(size_t)s * 524288 + (size_t)q * 128 + col0];
#pragma unroll
            for (int e = 0; e < 8; e++) am[e] += (float)t[e];
        }
#pragma unroll
        for (int e = 0; e < 8; e++)
            am[e] += b2l[col0 + e] + x1[(size_t)q * 128 + col0 + e];
        float s1 = 0.f, s2 = 0.f;
#pragma unroll
        for (int e = 0; e < 8; e++) { s1 += am[e]; s2 += am[e] * am[e]; }
#pragma unroll
        for (int off = 1; off < 16; off <<= 1) {
            s1 += __shfl_xor(s1, off);
            s2 += __shfl_xor(s2, off);
        }
        float mean = s1 * (1.0f / 128.0f);
        float var = s2 * (1.0f / 128.0f) - mean * mean;
        float inv = rsqrtf(var + 1e-5f);
        f16x8 hv;
#pragma unroll
        for (int e = 0; e < 8; e++)
            hv[e] = (_Float16)((am[e] - mean) * inv * g2[col0 + e] + bn2[col0 + e]);
        *(f16x8*)&Ah[row][(qg ^ (row & 15)) << 3] = hv;
    }
    __syncthreads();

    f32x4 acc[2];
#pragma unroll
    for (int j = 0; j < 2; j++) acc[j] = {0.f, 0.f, 0.f, 0.f};
#pragma unroll
    for (int ks = 0; ks < 4; ks++) {
        f16x8 af = rdS(Ah, lc, ks * 4 + lr);
#pragma unroll
        for (int j = 0; j < 2; j++) {
            f16x8 bf = rdS(Bh, w * 32 + j * 16 + lc, ks * 4 + lr);
            acc[j] = __builtin_amdgcn_mfma_f32_16x16x32_f16(af, bf, acc[j], 0, 0, 0);
        }
    }
    __syncthreads();   // pass-1 reads done
#pragma unroll
    for (int j = 0; j < 2; j++) {
        int n = w * 32 + j * 16 + lc;
        float bb = b1f[n];
#pragma unroll
        for (int r = 0; r < 4; r++)
            wrS(Ah, lr * 4 + r, n, (_Float16)fmaxf(acc[j][r] + bb, 0.f));
    }
    stageGL<128>(Bh, W2h, 128, 0, 0, tid);
    __syncthreads();

    f32x4 o[2];
#pragma unroll
    for (int j = 0; j < 2; j++) o[j] = {0.f, 0.f, 0.f, 0.f};
#pragma unroll
    for (int ks = 0; ks < 4; ks++) {
        f16x8 af = rdS(Ah, lc, ks * 4 + lr);
#pragma unroll
        for (int j = 0; j < 2; j++) {
            f16x8 bf = rdS(Bh, w * 32 + j * 16 + lc, ks * 4 + lr);
            o[j] = __builtin_amdgcn_mfma_f32_16x16x32_f16(af, bf, o[j], 0, 0, 0);
        }
    }
#pragma unroll
    for (int j = 0; j < 2; j++) {
        float bb = b2f[w * 32 + j * 16 + lc];
#pragma unroll
        for (int r = 0; r < 4; r++) o[j][r] += bb;
    }
#pragma unroll
    for (int r = 0; r < 4; r++) {
        float s2 = o[0][r] * o[0][r] + o[1][r] * o[1][r];
#pragma unroll
        for (int off = 1; off < 16; off <<= 1) s2 += __shfl_xor(s2, off);
        if (lc == 0) Red[lr * 4 + r][w] = s2;
    }
    __syncthreads();
#pragma unroll
    for (int r = 0; r < 4; r++) {
        int rl = lr * 4 + r;
        float inv = rsqrtf((Red[rl][0] + Red[rl][1]) + (Red[rl][2] + Red[rl][3]));
        int m = m0 + rl;
#pragma unroll
        for (int j = 0; j < 2; j++) {
            int n = w * 32 + j * 16 + lc;
            aoh[(size_t)m * 128 + n] = (_Float16)(o[j][r] * inv);
        }
    }
}

// ---------------------------------------------------------------------------
// Gram: C = max(aoh @ aoh^T, 1e-6). R20: 128x128 tiles, 64KB LDS, grid
// (32,32) = 1024 blocks -> exactly 2/CU -> two clean passes of 512. Each
// wave computes a 64x64 sub-tile (acc[4][4]).
// ---------------------------------------------------------------------------
__global__ __launch_bounds__(256) void gram_f16(const _Float16* __restrict__ aoh,
                                                float* __restrict__ C)
{
    __shared__ _Float16 Ah[128][128], Bh[128][128];
    int tid = threadIdx.x, w = tid >> 6, l = tid & 63, lc = l & 15, lr = l >> 4;
    int wr = w >> 1, wc = w & 1;
    int m0 = blockIdx.x * 128, n0 = blockIdx.y * 128;

    stageGL<128>(Ah, aoh, 128, m0, 0, tid);
    stageGL<128>(Bh, aoh, 128, n0, 0, tid);
    __syncthreads();

    f32x4 acc[4][4];
#pragma unroll
    for (int i = 0; i < 4; i++)
#pragma unroll
        for (int j = 0; j < 4; j++) acc[i][j] = {0.f, 0.f, 0.f, 0.f};
#pragma unroll
    for (int ks = 0; ks < 4; ks++) {
        f16x8 af[4], bf[4];
#pragma unroll
        for (int t = 0; t < 4; t++) {
            af[t] = rdS(Ah, wr * 64 + t * 16 + lc, ks * 4 + lr);
            bf[t] = rdS(Bh, wc * 64 + t * 16 + lc, ks * 4 + lr);
        }
#pragma unroll
        for (int i = 0; i < 4; i++)
#pragma unroll
            for (int j = 0; j < 4; j++)
                acc[i][j] = __builtin_amdgcn_mfma_f32_16x16x32_f16(
                    af[i], bf[j], acc[i][j], 0, 0, 0);
    }

#pragma unroll
    for (int i = 0; i < 4; i++) {
        int mb = m0 + wr * 64 + i * 16 + lr * 4;
#pragma unroll
        for (int j = 0; j < 4; j++) {
            int n = n0 + wc * 64 + j * 16 + lc;
#pragma unroll
            for (int r = 0; r < 4; r++)
                C[(size_t)(mb + r) * 4096 + n] = fmaxf(acc[i][j][r], 1e-6f);
        }
    }
}

// ---------------------------------------------------------------------------
extern "C" void kernel_launch(void* const* d_in, const int* in_sizes, int n_in,
                              void* d_out, int out_size, void* d_ws, size_t ws_size,
                              hipStream_t stream)
{
    const float* src  = (const float*)d_in[0];
    const float* Wqkv = (const float*)d_in[1];
    const float* bqkv = (const float*)d_in[2];
    const float* Wo   = (const float*)d_in[3];
    const float* bo   = (const float*)d_in[4];
    const float* ln1g = (const float*)d_in[5];
    const float* ln1b = (const float*)d_in[6];
    const float* W1   = (const float*)d_in[7];
    const float* b1   = (const float*)d_in[8];
    const float* W2   = (const float*)d_in[9];
    const float* b2   = (const float*)d_in[10];
    const float* ln2g = (const float*)d_in[11];
    const float* ln2b = (const float*)d_in[12];
    const float* fc1W = (const float*)d_in[13];
    const float* fc1b = (const float*)d_in[14];
    const float* fc2W = (const float*)d_in[15];
    const float* fc2b = (const float*)d_in[16];

    float* ws = (float*)d_ws;
    float*    x   = ws;                                   // 524288 f32 (post-LN2 chain)
    _Float16* xh  = (_Float16*)(ws + 524288);             // 524288 f16 (post-LN1 / init)
    _Float16* aoh = (_Float16*)(ws + 786432);             // 524288 f16
    _Float16* qh  = (_Float16*)(ws + 1048576);            // 524288 f16
    _Float16* kh  = (_Float16*)(ws + 1310720);            // 524288 f16
    _Float16* vt  = (_Float16*)(ws + 1572864);            // 524288 f16
    float*    mll = ws + 1835008;                         // 65536 f32 (SPLIT=4)

    // d_out scratch (all dead before gram writes):
    _Float16* wpart = (_Float16*)d_out + 4194304;         // bytes [ 8MiB,16MiB)
    _Float16* apart = (_Float16*)d_out + 12582912;        // bytes [24MiB,28MiB) SPLIT=4
    _Float16* wh    = (_Float16*)d_out + 16777216;        // bytes [32MiB,~34MiB)
    float*    x1    = (float*)d_out + 9437184;            // bytes [36MiB,38MiB) post-LN1
    float*    out   = (float*)d_out;

    _Float16* qkvh = wh;                  // 3 x 384 x 128
    _Float16* woh  = wh + 147456;         // 3 x 128 x 128
    _Float16* w1h  = wh + 196608;         // 3 x 1024 x 128
    _Float16* w2h  = wh + 589824;         // 3 x 128 x 1024
    _Float16* fc1h = wh + 983040;         // 128 x 128
    _Float16* fc2h = wh + 999424;         // 128 x 128

    setup_cvt<<<1504, 256, 0, stream>>>(Wqkv, Wo, W1, W2, fc1W, fc2W, wh,
                                        src, x, xh);
    // layer 0
    gemm_qkv<<<dim3(256, 3), 256, 0, stream>>>(xh, qkvh, bqkv, qh, kh, vt);
    attn_mfma<<<dim3(64, 4, SPLIT), 256, 0, stream>>>(qh, kh, vt, apart, mll);
    wo_ln_merge<<<256, 256, 0, stream>>>(apart, mll, woh, bo, x, x1, xh,
                                         ln1g, ln1b);
    ffn_pair<<<dim3(64, 8), 256, 0, stream>>>(xh, w1h, b1, w2h, wpart);
    // layers 1, 2: QKV with fused FFN-merge + LN2 of previous layer
    for (int l = 1; l < 3; l++) {
        gemm_qkv_merge<<<dim3(256, 3), 256, 0, stream>>>(
            wpart, x1, b2 + (l - 1) * 128, ln2g + (l - 1) * 128,
            ln2b + (l - 1) * 128, x,
            qkvh + l * 49152, bqkv + l * 384, qh, kh, vt);
        attn_mfma<<<dim3(64, 4, SPLIT), 256, 0, stream>>>(qh, kh, vt, apart, mll);
        wo_ln_merge<<<256, 256, 0, stream>>>(apart, mll, woh + l * 16384,
                                             bo + l * 128, x, x1, xh,
                                             ln1g + l * 128, ln1b + l * 128);
        ffn_pair<<<dim3(64, 8), 256, 0, stream>>>(xh, w1h + l * 131072,
                                                  b1 + l * 1024,
                                                  w2h + l * 131072, wpart);
    }
    // fc chain with fused FFN-merge + LN2 of layer 2
    fc_fused<<<256, 256, 0, stream>>>(wpart, x1, b2 + 256, ln2g + 256,
                                      ln2b + 256, fc1h, fc1b, fc2h, fc2b, aoh);
    gram_f16<<<dim3(32, 32), 256, 0, stream>>>(aoh, out);
}